// Round 1
// baseline (3057.086 us; speedup 1.0000x reference)
//
#include <hip/hip_runtime.h>
#include <cmath>

#define GRIDN 32
#define NPIX 1024
#define NEDGE 1984
#define NPAD 2048
#define KTOP 256
#define NITER 150

__device__ __forceinline__ void lse_comb(float& m, float& s, float m2, float s2) {
    float M = fmaxf(m, m2);
    s = s * exp2f(m - M) + s2 * exp2f(m2 - M);
    m = M;
}

// ---------------- pooling: softmax(x) and one-hot(y), adaptive-avg-pool 8x8 ----------------
__global__ __launch_bounds__(256) void pool_kernel(const float* __restrict__ x,
                                                   const int* __restrict__ y,
                                                   float* __restrict__ pooled) {
    int t = blockIdx.x;            // 0..23  (0..11: x images, 12..23: y images)
    float* out = pooled + t * NPIX;
    int tid = threadIdx.x;
    if (t < 12) {
        int b = t / 3, c = t % 3 + 1;
        const float* xb = x + (size_t)b * 4 * 65536;
        for (int cell = tid; cell < NPIX; cell += 256) {
            int gi = cell >> 5, gj = cell & 31;
            float acc = 0.f;
            for (int pi = 0; pi < 8; ++pi) {
                int row = gi * 8 + pi;
                const float* xr = xb + row * 256 + gj * 8;
                for (int pj = 0; pj < 8; ++pj) {
                    float x0 = xr[pj];
                    float x1 = xr[pj + 65536];
                    float x2 = xr[pj + 2 * 65536];
                    float x3 = xr[pj + 3 * 65536];
                    float mx = fmaxf(fmaxf(x0, x1), fmaxf(x2, x3));
                    float e0 = expf(x0 - mx), e1 = expf(x1 - mx);
                    float e2 = expf(x2 - mx), e3 = expf(x3 - mx);
                    float sden = e0 + e1 + e2 + e3;
                    float ec = (c == 1) ? e1 : (c == 2) ? e2 : e3;
                    acc += ec / sden;
                }
            }
            out[cell] = acc * (1.f / 64.f);
        }
    } else {
        int tt = t - 12;
        int b = tt / 3, c = tt % 3 + 1;
        const int* yb = y + (size_t)b * 65536;
        for (int cell = tid; cell < NPIX; cell += 256) {
            int gi = cell >> 5, gj = cell & 31;
            int cnt = 0;
            for (int pi = 0; pi < 8; ++pi) {
                const int* yr = yb + (gi * 8 + pi) * 256 + gj * 8;
                for (int pj = 0; pj < 8; ++pj) cnt += (yr[pj] == c) ? 1 : 0;
            }
            out[cell] = (float)cnt * (1.f / 64.f);
        }
    }
}

// ---------------- bitonic sort of 2048 u64 keys in LDS, 256 threads ----------------
__device__ void bitonic2048(unsigned long long* keys, int tid, bool asc) {
    for (int k = 2; k <= NPAD; k <<= 1) {
        for (int j = k >> 1; j > 0; j >>= 1) {
            for (int ii = tid; ii < NPAD; ii += 256) {
                int l = ii ^ j;
                if (l > ii) {
                    unsigned long long a = keys[ii], b = keys[l];
                    bool up = (((ii & k) == 0) == asc);
                    if ((a > b) == up) { keys[ii] = b; keys[l] = a; }
                }
            }
            __syncthreads();
        }
    }
}

// ---------------- persistence diagrams (H0 sublevel / H1 via superlevel duality) ------------
__global__ __launch_bounds__(256) void diag_kernel(const float* __restrict__ pooled,
                                                   float* __restrict__ diag) {
    __shared__ float v_[NPIX];
    __shared__ unsigned long long keys[NPAD];
    __shared__ int par[NPIX];
    __shared__ float birth[NPIX];
    __shared__ float pbs[NEDGE];
    __shared__ float pds[NEDGE];
    __shared__ float redA[4], redB[4];
    __shared__ float svmin, svmax;

    int run = blockIdx.x;      // 0..47
    int img = run >> 1, filt = run & 1;
    int tid = threadIdx.x;
    const float* m = pooled + img * NPIX;

    for (int i = tid; i < NPIX; i += 256) {
        float val = m[i];
        v_[i] = filt ? -val : val;
    }
    __syncthreads();
    // min/max (for the essential H0 class)
    float mn = INFINITY, mx = -INFINITY;
    for (int i = tid; i < NPIX; i += 256) { float vv = v_[i]; mn = fminf(mn, vv); mx = fmaxf(mx, vv); }
    for (int o = 32; o; o >>= 1) { mn = fminf(mn, __shfl_xor(mn, o)); mx = fmaxf(mx, __shfl_xor(mx, o)); }
    if ((tid & 63) == 0) { redA[tid >> 6] = mn; redB[tid >> 6] = mx; }
    __syncthreads();
    if (tid == 0) {
        svmin = fminf(fminf(redA[0], redA[1]), fminf(redA[2], redA[3]));
        svmax = fmaxf(fmaxf(redB[0], redB[1]), fmaxf(redB[2], redB[3]));
    }
    // edge keys: stable sort by (weight, edge index) — replicates jnp.argsort (stable)
    for (int e = tid; e < NPAD; e += 256) {
        unsigned long long key;
        if (e < NEDGE) {
            int u, vv;
            if (e < 992) { int r = e / 31; u = e + r; vv = u + 1; }   // horizontal
            else         { u = e - 992;   vv = u + 32; }              // vertical
            float w = fmaxf(v_[u], v_[vv]);
            unsigned int bw = __float_as_uint(w);
            bw = (bw & 0x80000000u) ? ~bw : (bw | 0x80000000u);       // orderable float bits
            key = ((unsigned long long)bw << 11) | (unsigned int)e;
        } else key = ~0ULL;
        keys[e] = key;
    }
    for (int i = tid; i < NPIX; i += 256) { par[i] = i; birth[i] = v_[i]; }
    __syncthreads();
    bitonic2048(keys, tid, true);   // ascending; ends with a barrier

    // sequential Kruskal/union-find with elder rule (thread 0)
    if (tid == 0) {
        for (int kk = 0; kk < NEDGE; ++kk) {
            int e = (int)(keys[kk] & 2047ULL);
            int u, vv;
            if (e < 992) { int r = e / 31; u = e + r; vv = u + 1; }
            else         { u = e - 992;   vv = u + 32; }
            float w = fmaxf(v_[u], v_[vv]);
            int a = u;  while (par[a] != a) { par[a] = par[par[a]]; a = par[a]; }
            int b = vv; while (par[b] != b) { par[b] = par[par[b]]; b = par[b]; }
            float pb_, pd_;
            if (a != b) {
                float bu = birth[a], bv = birth[b];
                bool uo = (bu <= bv);                 // tie -> root of u (matches reference)
                int older = uo ? a : b;
                int younger = uo ? b : a;
                pb_ = fmaxf(bu, bv); pd_ = w;         // younger component dies
                par[younger] = older;                 // birth[older] already the min
            } else { pb_ = w; pd_ = w; }              // trivial edge -> diagonal pair
            pbs[kk] = pb_; pds[kk] = pd_;
        }
    }
    __syncthreads();

    // top-k by persistence, ties -> lower index (matches jax.lax.top_k)
    int count = filt ? NEDGE : (NEDGE + 1);
    for (int k = tid; k < NPAD; k += 256) {
        unsigned long long key = 0ULL;
        if (k < count) {
            float pers = (k < NEDGE) ? (pds[k] - pbs[k]) : (svmax - svmin);
            key = ((unsigned long long)__float_as_uint(pers) << 32) | (unsigned int)(2047 - k);
        }
        keys[k] = key;
    }
    __syncthreads();
    bitonic2048(keys, tid, false);  // descending

    {
        unsigned long long key = keys[tid];
        int k = 2047 - (int)(key & 0xffffffffULL);
        float b_, d_;
        if (k < NEDGE) { b_ = pbs[k]; d_ = pds[k]; }
        else           { b_ = svmin;  d_ = svmax; }
        float ob, od;
        if (!filt) { ob = b_;  od = d_;  }       // H0 pairs
        else       { ob = -d_; od = -b_; }       // H1 = negated superlevel H0
        diag[((img * 4) + filt * 2 + 0) * KTOP + tid] = ob;
        diag[((img * 4) + filt * 2 + 1) * KTOP + tid] = od;
    }
}

// ---------------- entropic Sinkhorn, reduced 256x256 + lumped-diagonal scalars ----------------
__global__ __launch_bounds__(1024) void sink_kernel(const float* __restrict__ diag,
                                                    float* __restrict__ wres) {
    __shared__ float2 sPA[KTOP], sPB[KTOP];
    __shared__ float sda[KTOP], sdb[KTOP], sf[KTOP], sg[KTOP];
    __shared__ float pm[1024], ps[1024];
    __shared__ float wm4[4], ws4[4];
    __shared__ float sF2, sG2, sSig, sInvSig;

    int p = blockIdx.x;            // 0..23
    int img = p % 12, dim = p / 12;
    int t = threadIdx.x;
    const float* ab  = diag + ((img * 4) + dim * 2) * KTOP;
    const float* ad  = ab + KTOP;
    const float* bbp = diag + (((12 + img) * 4) + dim * 2) * KTOP;
    const float* bdp = bbp + KTOP;

    if (t < KTOP) {
        float a0 = ab[t], a1 = ad[t];
        float b0 = bbp[t], b1 = bdp[t];
        sPA[t] = make_float2(a0, a1);
        sPB[t] = make_float2(b0, b1);
        sda[t] = 0.5f * (a1 - a0);
        sdb[t] = 0.5f * (b1 - b0);
    }
    __syncthreads();

    int r = t & 255, q = t >> 8;
    int jbase = q * 64;
    // maxC
    {
        float2 A = sPA[r];
        float lmax = 0.f;
        for (int jj = 0; jj < 64; ++jj) {
            float2 B = sPB[jbase + jj];
            lmax = fmaxf(lmax, fmaxf(fabsf(A.x - B.x), fabsf(A.y - B.y)));
        }
        if (t < KTOP) lmax = fmaxf(lmax, fmaxf(sda[t], sdb[t]));
        for (int o = 32; o; o >>= 1) lmax = fmaxf(lmax, __shfl_xor(lmax, o));
        if ((t & 63) == 0) pm[t >> 6] = lmax;
    }
    __syncthreads();
    if (t == 0) {
        float mc = 0.f;
        for (int i = 0; i < 16; ++i) mc = fmaxf(mc, pm[i]);
        float eps = 0.02f * fmaxf(mc, 1e-6f);
        sSig = 1.4426950408889634f / eps;        // log2(e)/eps
        sInvSig = eps * 0.6931471805599453f;     // eps*ln2
    }
    __syncthreads();
    {
        float sig = sSig;
        if (t < KTOP) {
            float2 a2 = sPA[t], b2 = sPB[t];
            sPA[t] = make_float2(a2.x * sig, a2.y * sig);
            sPB[t] = make_float2(b2.x * sig, b2.y * sig);
            sda[t] *= sig; sdb[t] *= sig;
            sf[t] = 0.f; sg[t] = 0.f;
        }
        if (t == 0) { sF2 = 0.f; sG2 = 0.f; }
    }
    __syncthreads();

    float2 Ar = sPA[r];     // scaled a-point for row r (f phase)
    float2 Br = sPB[r];     // scaled b-point for col r (g phase)
    float daR = sda[r], dbR = sdb[r];

    for (int it = 0; it < NITER; ++it) {
        // ---- f update (uses old g, G2) ----
        float mrun = -INFINITY, srun = 0.f;
        #pragma unroll 4
        for (int jj = 0; jj < 64; ++jj) {
            int j = jbase + jj;
            float2 B = sPB[j];
            float Mh = fmaxf(fabsf(Ar.x - B.x), fabsf(Ar.y - B.y));
            float term = sg[j] - Mh;
            float d = term - mrun;
            float e = exp2f(-fabsf(d));
            bool gt = d > 0.f;
            srun = gt ? fmaf(srun, e, 1.f) : (srun + e);
            mrun = gt ? term : mrun;
        }
        pm[t] = mrun; ps[t] = srun;
        __syncthreads();
        if (t < 256) {
            float M0 = pm[t], S0 = ps[t];
            lse_comb(M0, S0, pm[256 + t], ps[256 + t]);
            lse_comb(M0, S0, pm[512 + t], ps[512 + t]);
            lse_comb(M0, S0, pm[768 + t], ps[768 + t]);
            lse_comb(M0, S0, sG2 + 8.f - daR, 1.f);   // 256 lumped diagonal columns
            sf[t] = -(M0 + log2f(S0));
        } else if (t < 512) {
            int j = t - 256;
            float mv = sg[j] - sdb[j], sv = 1.f;
            for (int o = 32; o; o >>= 1) {
                float m2 = __shfl_xor(mv, o), s2 = __shfl_xor(sv, o);
                lse_comb(mv, sv, m2, s2);
            }
            if ((t & 63) == 0) { wm4[(t >> 6) - 4] = mv; ws4[(t >> 6) - 4] = sv; }
        }
        __syncthreads();
        if (t == 0) {
            float M0 = wm4[0], S0 = ws4[0];
            lse_comb(M0, S0, wm4[1], ws4[1]);
            lse_comb(M0, S0, wm4[2], ws4[2]);
            lse_comb(M0, S0, wm4[3], ws4[3]);
            lse_comb(M0, S0, sG2 + 8.f, 1.f);
            sF2 = -(M0 + log2f(S0));
        }
        __syncthreads();
        // ---- g update (uses new f, F2) ----
        mrun = -INFINITY; srun = 0.f;
        #pragma unroll 4
        for (int jj = 0; jj < 64; ++jj) {
            int i = jbase + jj;
            float2 A = sPA[i];
            float Mh = fmaxf(fabsf(A.x - Br.x), fabsf(A.y - Br.y));
            float term = sf[i] - Mh;
            float d = term - mrun;
            float e = exp2f(-fabsf(d));
            bool gt = d > 0.f;
            srun = gt ? fmaf(srun, e, 1.f) : (srun + e);
            mrun = gt ? term : mrun;
        }
        pm[t] = mrun; ps[t] = srun;
        __syncthreads();
        if (t < 256) {
            float M0 = pm[t], S0 = ps[t];
            lse_comb(M0, S0, pm[256 + t], ps[256 + t]);
            lse_comb(M0, S0, pm[512 + t], ps[512 + t]);
            lse_comb(M0, S0, pm[768 + t], ps[768 + t]);
            lse_comb(M0, S0, sF2 + 8.f - dbR, 1.f);
            sg[t] = -(M0 + log2f(S0));
        } else if (t < 512) {
            int i = t - 256;
            float mv = sf[i] - sda[i], sv = 1.f;
            for (int o = 32; o; o >>= 1) {
                float m2 = __shfl_xor(mv, o), s2 = __shfl_xor(sv, o);
                lse_comb(mv, sv, m2, s2);
            }
            if ((t & 63) == 0) { wm4[(t >> 6) - 4] = mv; ws4[(t >> 6) - 4] = sv; }
        }
        __syncthreads();
        if (t == 0) {
            float M0 = wm4[0], S0 = ws4[0];
            lse_comb(M0, S0, wm4[1], ws4[1]);
            lse_comb(M0, S0, wm4[2], ws4[2]);
            lse_comb(M0, S0, wm4[3], ws4[3]);
            lse_comb(M0, S0, sF2 + 8.f, 1.f);
            sG2 = -(M0 + log2f(S0));
        }
        __syncthreads();
    }

    // ---- final cost sum(P*C) ----
    float acc = 0.f;
    {
        float fr = sf[r];
        for (int jj = 0; jj < 64; ++jj) {
            int j = jbase + jj;
            float2 B = sPB[j];
            float Mh = fmaxf(fabsf(Ar.x - B.x), fabsf(Ar.y - B.y));
            acc += exp2f(fr + sg[j] - Mh) * Mh;
        }
    }
    if (t < KTOP) {
        acc += 256.f * exp2f(sf[t] + sG2 - sda[t]) * sda[t];
        acc += 256.f * exp2f(sF2 + sg[t] - sdb[t]) * sdb[t];
    }
    for (int o = 32; o; o >>= 1) acc += __shfl_xor(acc, o);
    if ((t & 63) == 0) pm[t >> 6] = acc;
    __syncthreads();
    if (t == 0) {
        float tot = 0.f;
        for (int i = 0; i < 16; ++i) tot += pm[i];
        wres[p] = tot * sInvSig;   // back to natural units
    }
}

__global__ void finalize_kernel(const float* __restrict__ wres, float* __restrict__ out) {
    if (threadIdx.x == 0) {
        float s = 0.f;
        for (int i = 0; i < 24; ++i) s += wres[i];
        out[0] = s * 0.25f;        // / B
    }
}

extern "C" void kernel_launch(void* const* d_in, const int* in_sizes, int n_in,
                              void* d_out, int out_size, void* d_ws, size_t ws_size,
                              hipStream_t stream) {
    const float* x = (const float*)d_in[0];   // [4,4,256,256] f32
    const int* y = (const int*)d_in[1];       // [4,1,256,256] i32
    float* ws = (float*)d_ws;
    float* pooled = ws;                        // 24*1024 floats
    float* diag = pooled + 24 * NPIX;          // 24*4*256 floats
    float* wres = diag + 24 * 4 * KTOP;        // 24 floats

    pool_kernel<<<24, 256, 0, stream>>>(x, y, pooled);
    diag_kernel<<<48, 256, 0, stream>>>(pooled, diag);
    sink_kernel<<<24, 1024, 0, stream>>>(diag, wres);
    finalize_kernel<<<1, 64, 0, stream>>>(wres, (float*)d_out);
}

// Round 2
// 1988.977 us; speedup vs baseline: 1.5370x; 1.5370x over previous
//
#include <hip/hip_runtime.h>
#include <cmath>

#define GRIDN 32
#define NPIX 1024
#define NEDGE 1984
#define NPAD 2048
#define KTOP 256
#define NITER 150

__device__ __forceinline__ unsigned bf_rne(float x) {
    unsigned b = __float_as_uint(x);
    return (b + 0x7fffu + ((b >> 16) & 1u)) >> 16;
}

// ---------------- pooling: softmax(x) and one-hot(y), adaptive-avg-pool 8x8 ----------------
__global__ __launch_bounds__(256) void pool_kernel(const float* __restrict__ x,
                                                   const int* __restrict__ y,
                                                   float* __restrict__ pooled) {
    int blk = blockIdx.x;              // 0..95
    int img = blk >> 2;                // 0..23
    int cell = ((blk & 3) << 8) | threadIdx.x;
    int gi = cell >> 5, gj = cell & 31;
    const float L2E = 1.4426950408889634f;
    float acc = 0.f;
    if (img < 12) {
        int b = img / 3, c = img % 3 + 1;
        const float* xb = x + (size_t)b * 262144 + (size_t)gi * 2048 + gj * 8;
        for (int pi = 0; pi < 8; ++pi) {
            const float* xr = xb + pi * 256;
            #pragma unroll
            for (int ph = 0; ph < 2; ++ph) {
                float4 c0 = *(const float4*)(xr + ph * 4);
                float4 c1 = *(const float4*)(xr + ph * 4 + 65536);
                float4 c2 = *(const float4*)(xr + ph * 4 + 131072);
                float4 c3 = *(const float4*)(xr + ph * 4 + 196608);
                const float* f0 = (const float*)&c0;
                const float* f1 = (const float*)&c1;
                const float* f2 = (const float*)&c2;
                const float* f3 = (const float*)&c3;
                #pragma unroll
                for (int k = 0; k < 4; ++k) {
                    float e0 = exp2f(f0[k] * L2E), e1 = exp2f(f1[k] * L2E);
                    float e2 = exp2f(f2[k] * L2E), e3 = exp2f(f3[k] * L2E);
                    float ec = (c == 1) ? e1 : (c == 2) ? e2 : e3;
                    acc += ec / (e0 + e1 + e2 + e3);
                }
            }
        }
    } else {
        int tt = img - 12;
        int b = tt / 3, c = tt % 3 + 1;
        const int* yb = y + (size_t)b * 65536 + (size_t)gi * 2048 + gj * 8;
        int cnt = 0;
        for (int pi = 0; pi < 8; ++pi) {
            const int* yr = yb + pi * 256;
            #pragma unroll
            for (int pj = 0; pj < 8; ++pj) cnt += (yr[pj] == c) ? 1 : 0;
        }
        acc = (float)cnt;
    }
    pooled[img * NPIX + cell] = acc * (1.f / 64.f);
}

// ---------------- bitonic sort of 2048 u64 keys in LDS, 256 threads ----------------
__device__ void bitonic2048(unsigned long long* keys, int tid, bool asc) {
    for (int k = 2; k <= NPAD; k <<= 1) {
        for (int j = k >> 1; j > 0; j >>= 1) {
            for (int ii = tid; ii < NPAD; ii += 256) {
                int l = ii ^ j;
                if (l > ii) {
                    unsigned long long a = keys[ii], b = keys[l];
                    bool up = (((ii & k) == 0) == asc);
                    if ((a > b) == up) { keys[ii] = b; keys[l] = a; }
                }
            }
            __syncthreads();
        }
    }
}

// ---------------- persistence diagrams (H0 sublevel / H1 via superlevel duality) ------------
__global__ __launch_bounds__(256) void diag_kernel(const float* __restrict__ pooled,
                                                   float* __restrict__ diag) {
    __shared__ float v_[NPIX];
    __shared__ unsigned long long keys[NPAD];
    __shared__ unsigned long long PB[NPIX];      // low 32: parent, high 32: birth (f32 bits)
    __shared__ float pbs[NEDGE];
    __shared__ float pds[NEDGE];
    __shared__ float redA[4], redB[4];
    __shared__ float svmin, svmax;

    int run = blockIdx.x;      // 0..47
    int img = run >> 1, filt = run & 1;
    int tid = threadIdx.x;
    const float* m = pooled + img * NPIX;

    for (int i = tid; i < NPIX; i += 256) {
        float val = m[i];
        v_[i] = filt ? -val : val;
    }
    __syncthreads();
    // min/max (for the essential H0 class)
    float mn = INFINITY, mx = -INFINITY;
    for (int i = tid; i < NPIX; i += 256) { float vv = v_[i]; mn = fminf(mn, vv); mx = fmaxf(mx, vv); }
    for (int o = 32; o; o >>= 1) { mn = fminf(mn, __shfl_xor(mn, o)); mx = fmaxf(mx, __shfl_xor(mx, o)); }
    if ((tid & 63) == 0) { redA[tid >> 6] = mn; redB[tid >> 6] = mx; }
    __syncthreads();
    if (tid == 0) {
        svmin = fminf(fminf(redA[0], redA[1]), fminf(redA[2], redA[3]));
        svmax = fmaxf(fmaxf(redB[0], redB[1]), fmaxf(redB[2], redB[3]));
    }
    // edge keys: stable sort by (weight, edge index) — replicates jnp.argsort (stable)
    for (int e = tid; e < NPAD; e += 256) {
        unsigned long long key;
        if (e < NEDGE) {
            int u, vv;
            if (e < 992) { int r = e / 31; u = e + r; vv = u + 1; }   // horizontal
            else         { u = e - 992;   vv = u + 32; }              // vertical
            float w = fmaxf(v_[u], v_[vv]);
            unsigned int bw = __float_as_uint(w);
            bw = (bw & 0x80000000u) ? ~bw : (bw | 0x80000000u);       // orderable float bits
            key = ((unsigned long long)bw << 11) | (unsigned int)e;
        } else key = ~0ULL;
        keys[e] = key;
    }
    for (int i = tid; i < NPIX; i += 256)
        PB[i] = ((unsigned long long)__float_as_uint(v_[i]) << 32) | (unsigned)i;
    __syncthreads();
    bitonic2048(keys, tid, true);   // ascending; ends with a barrier

    // sequential Kruskal/union-find with elder rule (thread 0)
    if (tid == 0) {
        unsigned* PBlo = (unsigned*)PB;
        for (int kk = 0; kk < NEDGE; ++kk) {
            unsigned long long key = keys[kk];
            int e = (int)(key & 2047ULL);
            unsigned ob = (unsigned)(key >> 11);
            float w = __uint_as_float((ob & 0x80000000u) ? (ob & 0x7fffffffu) : ~ob);
            int u, vv;
            if (e < 992) { int rr = e / 31; u = e + rr; vv = u + 1; }
            else         { u = e - 992;    vv = u + 32; }
            int a = u, b = vv;
            unsigned long long qa = PB[a], qb = PB[b];
            int pa = (int)(unsigned)qa, pb = (int)(unsigned)qb;
            while (pa != a || pb != b) {
                if (pa != a) {
                    unsigned long long na = PB[pa];
                    int ga = (int)(unsigned)na;
                    PBlo[2 * a] = (unsigned)ga;     // compress a -> grandparent
                    a = pa; pa = ga; qa = na;
                }
                if (pb != b) {
                    unsigned long long nb = PB[pb];
                    int gb = (int)(unsigned)nb;
                    PBlo[2 * b] = (unsigned)gb;
                    b = pb; pb = gb; qb = nb;
                }
            }
            float pb_, pd_;
            if (a != b) {
                float bu = __uint_as_float((unsigned)(qa >> 32));
                float bv = __uint_as_float((unsigned)(qb >> 32));
                bool uo = (bu <= bv);                 // tie -> root of u (matches reference)
                int older = uo ? a : b;
                int younger = uo ? b : a;
                pb_ = fmaxf(bu, bv); pd_ = w;         // younger component dies
                PBlo[2 * younger] = (unsigned)older;  // birth[older] already the min
            } else { pb_ = w; pd_ = w; }              // trivial edge -> diagonal pair
            pbs[kk] = pb_; pds[kk] = pd_;
        }
    }
    __syncthreads();

    // top-k by persistence, ties -> lower index (matches jax.lax.top_k)
    int count = filt ? NEDGE : (NEDGE + 1);
    for (int k = tid; k < NPAD; k += 256) {
        unsigned long long key = 0ULL;
        if (k < count) {
            float pers = (k < NEDGE) ? (pds[k] - pbs[k]) : (svmax - svmin);
            key = ((unsigned long long)__float_as_uint(pers) << 32) | (unsigned int)(2047 - k);
        }
        keys[k] = key;
    }
    __syncthreads();
    bitonic2048(keys, tid, false);  // descending

    {
        unsigned long long key = keys[tid];
        int k = 2047 - (int)(key & 0xffffffffULL);
        float b_, d_;
        if (k < NEDGE) { b_ = pbs[k]; d_ = pds[k]; }
        else           { b_ = svmin;  d_ = svmax; }
        float ob, od;
        if (!filt) { ob = b_;  od = d_;  }       // H0 pairs
        else       { ob = -d_; od = -b_; }       // H1 = negated superlevel H0
        diag[((img * 4) + filt * 2 + 0) * KTOP + tid] = ob;
        diag[((img * 4) + filt * 2 + 1) * KTOP + tid] = od;
    }
}

// ---------------- entropic Sinkhorn: register-cached bf16 kernel matrix, exp2-free matvec ----
// f_hat_i = -(mg + log2( sum_j K_ij * u_j + cG*wa_i )),  K_ij = 2^(-Mhat_ij) const,
// u_j = 2^(g_hat_j - mg), cG = 2^(G2 + 8 - mg), wa_i = 2^(-da_i).  All exp2 args <= 0.
__global__ __launch_bounds__(1024, 4) void sink_kernel(const float* __restrict__ diag,
                                                       float* __restrict__ wres) {
    __shared__ float2 sPA[KTOP], sPB[KTOP];
    __shared__ float sda[KTOP], sdb[KTOP];
    __shared__ float swa[KTOP], swb[KTOP];
    __shared__ __align__(16) float ug[KTOP];
    __shared__ __align__(16) float uf[KTOP];
    __shared__ float f_lds[KTOP], g_lds[KTOP];
    __shared__ float pm[1024];
    __shared__ float wred[4], tred[4];
    __shared__ float s_sig, s_invsig, s_mg, s_mf, s_cG, s_cF, s_F2, s_G2;

    int p = blockIdx.x;            // 0..23
    int img = p % 12, dim = p / 12;
    int t = threadIdx.x;
    int r = t & 255, q = t >> 8;
    int jbase = q * 64;

    const float* ab  = diag + ((img * 4) + dim * 2) * KTOP;
    const float* ad  = ab + KTOP;
    const float* bbp = diag + (((12 + img) * 4) + dim * 2) * KTOP;
    const float* bdp = bbp + KTOP;

    if (t < KTOP) {
        float a0 = ab[t], a1 = ad[t];
        float b0 = bbp[t], b1 = bdp[t];
        sPA[t] = make_float2(a0, a1);
        sPB[t] = make_float2(b0, b1);
        sda[t] = 0.5f * (a1 - a0);
        sdb[t] = 0.5f * (b1 - b0);
    }
    __syncthreads();

    // maxC
    {
        float2 A = sPA[r];
        float lmax = 0.f;
        for (int jj = 0; jj < 64; ++jj) {
            float2 B = sPB[jbase + jj];
            lmax = fmaxf(lmax, fmaxf(fabsf(A.x - B.x), fabsf(A.y - B.y)));
        }
        if (t < KTOP) lmax = fmaxf(lmax, fmaxf(sda[t], sdb[t]));
        for (int o = 32; o; o >>= 1) lmax = fmaxf(lmax, __shfl_xor(lmax, o));
        if ((t & 63) == 0) pm[t >> 6] = lmax;
    }
    __syncthreads();
    if (t == 0) {
        float mc = 0.f;
        for (int i = 0; i < 16; ++i) mc = fmaxf(mc, pm[i]);
        float eps = 0.02f * fmaxf(mc, 1e-6f);
        s_sig = 1.4426950408889634f / eps;        // log2(e)/eps
        s_invsig = eps * 0.6931471805599453f;     // eps*ln2
    }
    __syncthreads();
    {
        float sig = s_sig;
        if (t < KTOP) {
            float2 a2 = sPA[t], b2 = sPB[t];
            sPA[t] = make_float2(a2.x * sig, a2.y * sig);
            sPB[t] = make_float2(b2.x * sig, b2.y * sig);
            float da2 = sda[t] * sig, db2 = sdb[t] * sig;
            sda[t] = da2; sdb[t] = db2;
            swa[t] = exp2f(-da2); swb[t] = exp2f(-db2);
            ug[t] = 1.f;
        }
        if (t == 0) { s_mg = 0.f; s_cG = 256.f; }
    }
    __syncthreads();

    // build register-resident bf16-packed kernel slices (constant across iterations)
    unsigned Kf[32], Kg[32];
    {
        float2 Apt = sPA[r];
        float2 Bc  = sPB[r];
        #pragma unroll
        for (int p2 = 0; p2 < 32; ++p2) {
            int j0 = jbase + 2 * p2;
            float2 B0 = sPB[j0], B1 = sPB[j0 + 1];
            float m0 = fmaxf(fabsf(Apt.x - B0.x), fabsf(Apt.y - B0.y));
            float m1 = fmaxf(fabsf(Apt.x - B1.x), fabsf(Apt.y - B1.y));
            Kf[p2] = bf_rne(exp2f(-m0)) | (bf_rne(exp2f(-m1)) << 16);
            float2 A0 = sPA[j0], A1 = sPA[j0 + 1];
            float n0 = fmaxf(fabsf(A0.x - Bc.x), fabsf(A0.y - Bc.y));
            float n1 = fmaxf(fabsf(A1.x - Bc.x), fabsf(A1.y - Bc.y));
            Kg[p2] = bf_rne(exp2f(-n0)) | (bf_rne(exp2f(-n1)) << 16);
        }
    }
    __syncthreads();

    for (int it = 0; it < NITER; ++it) {
        // ---- f half: S = Kf . ug ----
        {
            float S0 = 0.f, S1 = 0.f, S2 = 0.f, S3 = 0.f;
            const float4* u4 = (const float4*)(ug + jbase);
            #pragma unroll
            for (int p4 = 0; p4 < 16; ++p4) {
                float4 uv = u4[p4];
                unsigned k0 = Kf[2 * p4], k1 = Kf[2 * p4 + 1];
                S0 = fmaf(__uint_as_float(k0 << 16),          uv.x, S0);
                S1 = fmaf(__uint_as_float(k0 & 0xffff0000u),  uv.y, S1);
                S2 = fmaf(__uint_as_float(k1 << 16),          uv.z, S2);
                S3 = fmaf(__uint_as_float(k1 & 0xffff0000u),  uv.w, S3);
            }
            pm[t] = (S0 + S1) + (S2 + S3);
        }
        float tv = 0.f;
        if (t >= 256 && t < 512) tv = ug[t - 256] * swb[t - 256];
        __syncthreads();
        float fh = 0.f;
        if (t < 256) {
            float Si = ((pm[t] + pm[t + 256]) + (pm[t + 512] + pm[t + 768])) + s_cG * swa[t];
            fh = -(s_mg + log2f(Si));
            f_lds[t] = fh;
            float wmx = fh;
            for (int o = 32; o; o >>= 1) wmx = fmaxf(wmx, __shfl_xor(wmx, o));
            if ((t & 63) == 0) wred[t >> 6] = wmx;
        } else if (t < 512) {
            for (int o = 32; o; o >>= 1) tv += __shfl_xor(tv, o);
            if ((t & 63) == 0) tred[(t >> 6) - 4] = tv;
        }
        __syncthreads();
        {
            float mf = fmaxf(fmaxf(wred[0], wred[1]), fmaxf(wred[2], wred[3]));
            if (t < 256) uf[t] = exp2f(fh - mf);
            if (t == 0) {
                float T = ((tred[0] + tred[1]) + (tred[2] + tred[3])) + s_cG;
                float F2 = -(s_mg + log2f(T));
                s_F2 = F2;
                s_cF = exp2f(F2 + 8.f - mf);
                s_mf = mf;
            }
        }
        __syncthreads();
        // ---- g half: S = Kg . uf ----
        {
            float S0 = 0.f, S1 = 0.f, S2 = 0.f, S3 = 0.f;
            const float4* u4 = (const float4*)(uf + jbase);
            #pragma unroll
            for (int p4 = 0; p4 < 16; ++p4) {
                float4 uv = u4[p4];
                unsigned k0 = Kg[2 * p4], k1 = Kg[2 * p4 + 1];
                S0 = fmaf(__uint_as_float(k0 << 16),          uv.x, S0);
                S1 = fmaf(__uint_as_float(k0 & 0xffff0000u),  uv.y, S1);
                S2 = fmaf(__uint_as_float(k1 << 16),          uv.z, S2);
                S3 = fmaf(__uint_as_float(k1 & 0xffff0000u),  uv.w, S3);
            }
            pm[t] = (S0 + S1) + (S2 + S3);
        }
        tv = 0.f;
        if (t >= 256 && t < 512) tv = uf[t - 256] * swa[t - 256];
        __syncthreads();
        float gh = 0.f;
        if (t < 256) {
            float Sj = ((pm[t] + pm[t + 256]) + (pm[t + 512] + pm[t + 768])) + s_cF * swb[t];
            gh = -(s_mf + log2f(Sj));
            g_lds[t] = gh;
            float wmx = gh;
            for (int o = 32; o; o >>= 1) wmx = fmaxf(wmx, __shfl_xor(wmx, o));
            if ((t & 63) == 0) wred[t >> 6] = wmx;
        } else if (t < 512) {
            for (int o = 32; o; o >>= 1) tv += __shfl_xor(tv, o);
            if ((t & 63) == 0) tred[(t >> 6) - 4] = tv;
        }
        __syncthreads();
        {
            float mg = fmaxf(fmaxf(wred[0], wred[1]), fmaxf(wred[2], wred[3]));
            if (t < 256) ug[t] = exp2f(gh - mg);
            if (t == 0) {
                float T = ((tred[0] + tred[1]) + (tred[2] + tred[3])) + s_cF;
                float G2 = -(s_mf + log2f(T));
                s_G2 = G2;
                s_cG = exp2f(G2 + 8.f - mg);
                s_mg = mg;
            }
        }
        __syncthreads();
    }

    // ---- final cost sum(P*C) (recompute Mhat; one-time exp2 per element) ----
    float acc = 0.f;
    {
        float2 Apt = sPA[r];
        float fr = f_lds[r];
        for (int jj = 0; jj < 64; ++jj) {
            int j = jbase + jj;
            float2 B = sPB[j];
            float Mh = fmaxf(fabsf(Apt.x - B.x), fabsf(Apt.y - B.y));
            acc += exp2f(fr + g_lds[j] - Mh) * Mh;
        }
    }
    if (t < KTOP) {
        acc += 256.f * exp2f(f_lds[t] + s_G2 - sda[t]) * sda[t];
        acc += 256.f * exp2f(s_F2 + g_lds[t] - sdb[t]) * sdb[t];
    }
    for (int o = 32; o; o >>= 1) acc += __shfl_xor(acc, o);
    if ((t & 63) == 0) pm[t >> 6] = acc;
    __syncthreads();
    if (t == 0) {
        float tot = 0.f;
        for (int i = 0; i < 16; ++i) tot += pm[i];
        wres[p] = tot * s_invsig;   // back to natural units
    }
}

__global__ void finalize_kernel(const float* __restrict__ wres, float* __restrict__ out) {
    if (threadIdx.x == 0) {
        float s = 0.f;
        for (int i = 0; i < 24; ++i) s += wres[i];
        out[0] = s * 0.25f;        // / B
    }
}

extern "C" void kernel_launch(void* const* d_in, const int* in_sizes, int n_in,
                              void* d_out, int out_size, void* d_ws, size_t ws_size,
                              hipStream_t stream) {
    const float* x = (const float*)d_in[0];   // [4,4,256,256] f32
    const int* y = (const int*)d_in[1];       // [4,1,256,256] i32
    float* ws = (float*)d_ws;
    float* pooled = ws;                        // 24*1024 floats
    float* diag = pooled + 24 * NPIX;          // 24*4*256 floats
    float* wres = diag + 24 * 4 * KTOP;        // 24 floats

    pool_kernel<<<96, 256, 0, stream>>>(x, y, pooled);
    diag_kernel<<<48, 256, 0, stream>>>(pooled, diag);
    sink_kernel<<<24, 1024, 0, stream>>>(diag, wres);
    finalize_kernel<<<1, 64, 0, stream>>>(wres, (float*)d_out);
}

// Round 5
// 1662.839 us; speedup vs baseline: 1.8385x; 1.1961x over previous
//
#include <hip/hip_runtime.h>
#include <cmath>

#define NPIX 1024
#define NEDGE 1984
#define NPAD 2048
#define KTOP 256
#define NITER 150

__device__ __forceinline__ unsigned bf_rne(float x) {
    unsigned b = __float_as_uint(x);
    return (b + 0x7fffu + ((b >> 16) & 1u)) >> 16;
}
__device__ __forceinline__ int uw(int j) { return j + ((j >> 6) << 2); }  // staggered u index

__device__ __forceinline__ float min16(const float* a) {
    float4 x0 = *(const float4*)a,       x1 = *(const float4*)(a + 4);
    float4 x2 = *(const float4*)(a + 8), x3 = *(const float4*)(a + 12);
    float m0 = fminf(fminf(x0.x, x0.y), fminf(x0.z, x0.w));
    float m1 = fminf(fminf(x1.x, x1.y), fminf(x1.z, x1.w));
    float m2 = fminf(fminf(x2.x, x2.y), fminf(x2.z, x2.w));
    float m3 = fminf(fminf(x3.x, x3.y), fminf(x3.z, x3.w));
    return fminf(fminf(m0, m1), fminf(m2, m3));
}
__device__ __forceinline__ float sum16(const float* a) {
    float4 x0 = *(const float4*)a,       x1 = *(const float4*)(a + 4);
    float4 x2 = *(const float4*)(a + 8), x3 = *(const float4*)(a + 12);
    float s0 = (x0.x + x0.y) + (x0.z + x0.w);
    float s1 = (x1.x + x1.y) + (x1.z + x1.w);
    float s2 = (x2.x + x2.y) + (x2.z + x2.w);
    float s3 = (x3.x + x3.y) + (x3.z + x3.w);
    return (s0 + s1) + (s2 + s3);
}

// ---------------- pooling: softmax(x) and one-hot(y), adaptive-avg-pool 8x8 ----------------
__global__ __launch_bounds__(256) void pool_kernel(const float* __restrict__ x,
                                                   const int* __restrict__ y,
                                                   float* __restrict__ pooled) {
    int blk = blockIdx.x;              // 0..95
    int img = blk >> 2;                // 0..23
    int cell = ((blk & 3) << 8) | threadIdx.x;
    int gi = cell >> 5, gj = cell & 31;
    const float L2E = 1.4426950408889634f;
    float acc = 0.f;
    if (img < 12) {
        int b = img / 3, c = img % 3 + 1;
        const float* xb = x + (size_t)b * 262144 + (size_t)gi * 2048 + gj * 8;
        for (int pi = 0; pi < 8; ++pi) {
            const float* xr = xb + pi * 256;
            #pragma unroll
            for (int ph = 0; ph < 2; ++ph) {
                float4 c0 = *(const float4*)(xr + ph * 4);
                float4 c1 = *(const float4*)(xr + ph * 4 + 65536);
                float4 c2 = *(const float4*)(xr + ph * 4 + 131072);
                float4 c3 = *(const float4*)(xr + ph * 4 + 196608);
                const float* f0 = (const float*)&c0;
                const float* f1 = (const float*)&c1;
                const float* f2 = (const float*)&c2;
                const float* f3 = (const float*)&c3;
                #pragma unroll
                for (int k = 0; k < 4; ++k) {
                    float e0 = exp2f(f0[k] * L2E), e1 = exp2f(f1[k] * L2E);
                    float e2 = exp2f(f2[k] * L2E), e3 = exp2f(f3[k] * L2E);
                    float ec = (c == 1) ? e1 : (c == 2) ? e2 : e3;
                    acc += ec / (e0 + e1 + e2 + e3);
                }
            }
        }
    } else {
        int tt = img - 12;
        int b = tt / 3, c = tt % 3 + 1;
        const int* yb = y + (size_t)b * 65536 + (size_t)gi * 2048 + gj * 8;
        int cnt = 0;
        for (int pi = 0; pi < 8; ++pi) {
            const int* yr = yb + pi * 256;
            #pragma unroll
            for (int pj = 0; pj < 8; ++pj) cnt += (yr[pj] == c) ? 1 : 0;
        }
        acc = (float)cnt;
    }
    pooled[img * NPIX + cell] = acc * (1.f / 64.f);
}

// ---------------- bitonic sort of 2048 u64 keys in LDS, 512 threads ----------------
__device__ void bitonic2048(unsigned long long* keys, int tid, bool asc) {
    for (int k = 2; k <= NPAD; k <<= 1) {
        for (int j = k >> 1; j > 0; j >>= 1) {
            for (int ii = tid; ii < NPAD; ii += 512) {
                int l = ii ^ j;
                if (l > ii) {
                    unsigned long long a = keys[ii], b = keys[l];
                    bool up = (((ii & k) == 0) == asc);
                    if ((a > b) == up) { keys[ii] = b; keys[l] = a; }
                }
            }
            __syncthreads();
        }
    }
}

// ---------------- persistence diagrams (H0 sublevel / H1 via superlevel duality) ------------
// Serial union-find section is byte-identical to the round-2 version (verified absmax 0.0).
__global__ __launch_bounds__(512) void diag_kernel(const float* __restrict__ pooled,
                                                   float* __restrict__ diag) {
    __shared__ float v_[NPIX];
    __shared__ unsigned long long keys[NPAD];
    __shared__ unsigned long long PB[NPIX];      // low 32: parent, high 32: birth (f32 bits)
    __shared__ float pbs[NEDGE];
    __shared__ float pds[NEDGE];
    __shared__ float redA[8], redB[8];
    __shared__ float svmin, svmax;

    int run = blockIdx.x;      // 0..47
    int img = run >> 1, filt = run & 1;
    int tid = threadIdx.x;
    const float* m = pooled + img * NPIX;

    for (int i = tid; i < NPIX; i += 512) {
        float val = m[i];
        v_[i] = filt ? -val : val;
    }
    __syncthreads();
    // min/max (for the essential H0 class)
    float mn = INFINITY, mx = -INFINITY;
    for (int i = tid; i < NPIX; i += 512) { float vv = v_[i]; mn = fminf(mn, vv); mx = fmaxf(mx, vv); }
    for (int o = 32; o; o >>= 1) { mn = fminf(mn, __shfl_xor(mn, o)); mx = fmaxf(mx, __shfl_xor(mx, o)); }
    if ((tid & 63) == 0) { redA[tid >> 6] = mn; redB[tid >> 6] = mx; }
    __syncthreads();
    if (tid == 0) {
        float a = INFINITY, b = -INFINITY;
        for (int i2 = 0; i2 < 8; ++i2) { a = fminf(a, redA[i2]); b = fmaxf(b, redB[i2]); }
        svmin = a; svmax = b;
    }
    // edge keys: stable sort by (weight, edge index) — replicates jnp.argsort (stable)
    for (int e = tid; e < NPAD; e += 512) {
        unsigned long long key;
        if (e < NEDGE) {
            int u, vv;
            if (e < 992) { int r = e / 31; u = e + r; vv = u + 1; }   // horizontal
            else         { u = e - 992;   vv = u + 32; }              // vertical
            float w = fmaxf(v_[u], v_[vv]);
            unsigned int bw = __float_as_uint(w);
            bw = (bw & 0x80000000u) ? ~bw : (bw | 0x80000000u);       // orderable float bits
            key = ((unsigned long long)bw << 11) | (unsigned int)e;
        } else key = ~0ULL;
        keys[e] = key;
    }
    for (int i = tid; i < NPIX; i += 512)
        PB[i] = ((unsigned long long)__float_as_uint(v_[i]) << 32) | (unsigned)i;
    __syncthreads();
    bitonic2048(keys, tid, true);   // ascending; ends with a barrier

    // sequential Kruskal/union-find with elder rule (thread 0) — round-2 exact
    if (tid == 0) {
        unsigned* PBlo = (unsigned*)PB;
        for (int kk = 0; kk < NEDGE; ++kk) {
            unsigned long long key = keys[kk];
            int e = (int)(key & 2047ULL);
            unsigned ob = (unsigned)(key >> 11);
            float w = __uint_as_float((ob & 0x80000000u) ? (ob & 0x7fffffffu) : ~ob);
            int u, vv;
            if (e < 992) { int rr = e / 31; u = e + rr; vv = u + 1; }
            else         { u = e - 992;    vv = u + 32; }
            int a = u, b = vv;
            unsigned long long qa = PB[a], qb = PB[b];
            int pa = (int)(unsigned)qa, pb = (int)(unsigned)qb;
            while (pa != a || pb != b) {
                if (pa != a) {
                    unsigned long long na = PB[pa];
                    int ga = (int)(unsigned)na;
                    PBlo[2 * a] = (unsigned)ga;     // compress a -> grandparent
                    a = pa; pa = ga; qa = na;
                }
                if (pb != b) {
                    unsigned long long nb = PB[pb];
                    int gb = (int)(unsigned)nb;
                    PBlo[2 * b] = (unsigned)gb;
                    b = pb; pb = gb; qb = nb;
                }
            }
            float pb_, pd_;
            if (a != b) {
                float bu = __uint_as_float((unsigned)(qa >> 32));
                float bv = __uint_as_float((unsigned)(qb >> 32));
                bool uo = (bu <= bv);                 // tie -> root of u (matches reference)
                int older = uo ? a : b;
                int younger = uo ? b : a;
                pb_ = fmaxf(bu, bv); pd_ = w;         // younger component dies
                PBlo[2 * younger] = (unsigned)older;  // birth[older] already the min
            } else { pb_ = w; pd_ = w; }              // trivial edge -> diagonal pair
            pbs[kk] = pb_; pds[kk] = pd_;
        }
    }
    __syncthreads();

    // top-k by persistence, ties -> lower index (matches jax.lax.top_k)
    int count = filt ? NEDGE : (NEDGE + 1);
    for (int k = tid; k < NPAD; k += 512) {
        unsigned long long key = 0ULL;
        if (k < count) {
            float pers = (k < NEDGE) ? (pds[k] - pbs[k]) : (svmax - svmin);
            key = ((unsigned long long)__float_as_uint(pers) << 32) | (unsigned int)(2047 - k);
        }
        keys[k] = key;
    }
    __syncthreads();
    bitonic2048(keys, tid, false);  // descending

    if (tid < KTOP) {
        unsigned long long key = keys[tid];
        int k = 2047 - (int)(key & 0xffffffffULL);
        float b_, d_;
        if (k < NEDGE) { b_ = pbs[k]; d_ = pds[k]; }
        else           { b_ = svmin;  d_ = svmax; }
        float ob, od;
        if (!filt) { ob = b_;  od = d_;  }       // H0 pairs
        else       { ob = -d_; od = -b_; }       // H1 = negated superlevel H0
        diag[((img * 4) + filt * 2 + 0) * KTOP + tid] = ob;
        diag[((img * 4) + filt * 2 + 1) * KTOP + tid] = od;
    }
}

// ---------------- entropic Sinkhorn: multiplicative + per-phase fold normalization ----------
// Folded sums: Rf = cg*(Kf.ugs + 256*uG2s*wa)  with cg = min_j(prev folded Qf).
// Guarantees Rf >= 2^-73 and bounded above -> f32-safe.
// lambda-algebra telescopes: final P_ij = cf_last * ufs_i * K_ij * ugs_j.
__global__ __launch_bounds__(1024) void sink_kernel(const float* __restrict__ diag,
                                                    float* __restrict__ wres) {
    __shared__ float2 sPA[KTOP], sPB[KTOP];
    __shared__ float sda[KTOP], sdb[KTOP];
    __shared__ float swa[KTOP], swb[KTOP];
    __shared__ __align__(16) float ug_l[272];
    __shared__ __align__(16) float uf_l[272];
    __shared__ __align__(16) float minF[16], accTF[16], minG[16], accTG[16];
    __shared__ __align__(16) float pm[16];
    __shared__ float s_sig, s_invsig;

    int p = blockIdx.x;            // 0..23
    int img = p % 12, dim = p / 12;
    int t = threadIdx.x;
    int r = t >> 2, q = t & 3;     // 4 q-lanes per row, adjacent lanes -> shfl combine
    int jbase = q * 64;

    const float* ab  = diag + ((img * 4) + dim * 2) * KTOP;
    const float* ad  = ab + KTOP;
    const float* bbp = diag + (((12 + img) * 4) + dim * 2) * KTOP;
    const float* bdp = bbp + KTOP;

    if (t < KTOP) {
        float a0 = ab[t], a1 = ad[t];
        float b0 = bbp[t], b1 = bdp[t];
        sPA[t] = make_float2(a0, a1);
        sPB[t] = make_float2(b0, b1);
        sda[t] = 0.5f * (a1 - a0);
        sdb[t] = 0.5f * (b1 - b0);
    }
    __syncthreads();

    // maxC (unscaled)
    {
        float2 A = sPA[r];
        float lmax = 0.f;
        for (int jj = 0; jj < 64; ++jj) {
            float2 B = sPB[jbase + jj];
            lmax = fmaxf(lmax, fmaxf(fabsf(A.x - B.x), fabsf(A.y - B.y)));
        }
        if (t < KTOP) lmax = fmaxf(lmax, fmaxf(sda[t], sdb[t]));
        for (int o = 32; o; o >>= 1) lmax = fmaxf(lmax, __shfl_xor(lmax, o));
        if ((t & 63) == 0) pm[t >> 6] = lmax;
    }
    __syncthreads();
    if (t == 0) {
        float mc = 0.f;
        for (int i = 0; i < 16; ++i) mc = fmaxf(mc, pm[i]);
        float eps = 0.02f * fmaxf(mc, 1e-6f);
        s_sig = 1.4426950408889634f / eps;        // log2(e)/eps
        s_invsig = eps * 0.6931471805599453f;     // eps*ln2
    }
    __syncthreads();
    {
        float sig = s_sig;
        if (t < KTOP) {
            float2 a2 = sPA[t], b2 = sPB[t];
            sPA[t] = make_float2(a2.x * sig, a2.y * sig);
            sPB[t] = make_float2(b2.x * sig, b2.y * sig);
            float da2 = sda[t] * sig, db2 = sdb[t] * sig;
            sda[t] = da2; sdb[t] = db2;
            swa[t] = exp2f(-da2); swb[t] = exp2f(-db2);
            ug_l[uw(t)] = 1.f;
        }
    }
    __syncthreads();

    // register-resident bf16-packed kernel slices (constant across iterations)
    unsigned Kf[32], Kg[32];
    {
        float2 Apt = sPA[r];
        float2 Bc  = sPB[r];
        #pragma unroll
        for (int p2 = 0; p2 < 32; ++p2) {
            int j0 = jbase + 2 * p2;
            float2 B0 = sPB[j0], B1 = sPB[j0 + 1];
            float m0 = fmaxf(fabsf(Apt.x - B0.x), fabsf(Apt.y - B0.y));
            float m1 = fmaxf(fabsf(Apt.x - B1.x), fabsf(Apt.y - B1.y));
            Kf[p2] = bf_rne(exp2f(-m0)) | (bf_rne(exp2f(-m1)) << 16);
            float2 A0 = sPA[j0], A1 = sPA[j0 + 1];
            float n0 = fmaxf(fabsf(A0.x - Bc.x), fabsf(A0.y - Bc.y));
            float n1 = fmaxf(fabsf(A1.x - Bc.x), fabsf(A1.y - Bc.y));
            Kg[p2] = bf_rne(exp2f(-n0)) | (bf_rne(exp2f(-n1)) << 16);
        }
    }
    float wa_r = swa[r], wb_r = swb[r], da_r = sda[r], db_r = sdb[r];

    float ugs = 1.f, ufs = 1.f, uG2s = 1.f, uF2s = 1.f;
    float cg = 1.f, cf = 1.f;
    for (int it = 0; it < NITER; ++it) {
        // ---- f phase ----
        if (it) {
            cg = min16(minG);
            uG2s = 1.f / (cf * (sum16(accTG) + 256.f * uF2s));
        }
        {
            float S0 = 0.f, S1 = 0.f, S2 = 0.f, S3 = 0.f;
            const float4* u4 = (const float4*)(ug_l + q * 68);
            #pragma unroll
            for (int p4 = 0; p4 < 16; ++p4) {
                float4 uv = u4[p4];
                unsigned k0 = Kf[2 * p4], k1 = Kf[2 * p4 + 1];
                S0 = fmaf(__uint_as_float(k0 << 16),          uv.x, S0);
                S1 = fmaf(__uint_as_float(k0 & 0xffff0000u),  uv.y, S1);
                S2 = fmaf(__uint_as_float(k1 << 16),          uv.z, S2);
                S3 = fmaf(__uint_as_float(k1 & 0xffff0000u),  uv.w, S3);
            }
            float S = (S0 + S1) + (S2 + S3);
            S += __shfl_xor(S, 1); S += __shfl_xor(S, 2);       // full row sum, all 4 lanes
            float Rf = cg * (S + 256.f * uG2s * wa_r);
            ufs = 1.f / Rf;
            if (q == 0) uf_l[uw(r)] = ufs;
            float tv = (q == 1) ? ugs * wb_r : 0.f;             // T_f partial (old ug)
            float mv = Rf;
            tv += __shfl_xor(tv, 4);  mv = fminf(mv, __shfl_xor(mv, 4));
            tv += __shfl_xor(tv, 8);  mv = fminf(mv, __shfl_xor(mv, 8));
            tv += __shfl_xor(tv, 16); mv = fminf(mv, __shfl_xor(mv, 16));
            tv += __shfl_xor(tv, 32); mv = fminf(mv, __shfl_xor(mv, 32));
            if ((t & 63) == 1) accTF[t >> 6] = tv;
            if ((t & 63) == 2) minF[t >> 6] = mv;
        }
        __syncthreads();
        // ---- g phase ----
        cf = min16(minF);
        uF2s = 1.f / (cg * (sum16(accTF) + 256.f * uG2s));
        {
            float S0 = 0.f, S1 = 0.f, S2 = 0.f, S3 = 0.f;
            const float4* u4 = (const float4*)(uf_l + q * 68);
            #pragma unroll
            for (int p4 = 0; p4 < 16; ++p4) {
                float4 uv = u4[p4];
                unsigned k0 = Kg[2 * p4], k1 = Kg[2 * p4 + 1];
                S0 = fmaf(__uint_as_float(k0 << 16),          uv.x, S0);
                S1 = fmaf(__uint_as_float(k0 & 0xffff0000u),  uv.y, S1);
                S2 = fmaf(__uint_as_float(k1 << 16),          uv.z, S2);
                S3 = fmaf(__uint_as_float(k1 & 0xffff0000u),  uv.w, S3);
            }
            float S = (S0 + S1) + (S2 + S3);
            S += __shfl_xor(S, 1); S += __shfl_xor(S, 2);
            float Qf = cf * (S + 256.f * uF2s * wb_r);
            ugs = 1.f / Qf;
            if (q == 0) ug_l[uw(r)] = ugs;
            float tv = (q == 1) ? ufs * wa_r : 0.f;             // T_g partial (new uf)
            float mv = Qf;
            tv += __shfl_xor(tv, 4);  mv = fminf(mv, __shfl_xor(mv, 4));
            tv += __shfl_xor(tv, 8);  mv = fminf(mv, __shfl_xor(mv, 8));
            tv += __shfl_xor(tv, 16); mv = fminf(mv, __shfl_xor(mv, 16));
            tv += __shfl_xor(tv, 32); mv = fminf(mv, __shfl_xor(mv, 32));
            if ((t & 63) == 1) accTG[t >> 6] = tv;
            if ((t & 63) == 2) minG[t >> 6] = mv;
        }
        __syncthreads();
    }
    // final G2 (reference's G2 after last g update); overall plan scale = cf
    float uG2f = 1.f / (cf * (sum16(accTG) + 256.f * uF2s));

    // ---- final cost sum(P*C): P_ij = cf * ufs_i * K_ij * ugs_j,  C = Mhat*invsig ----
    float acc = 0.f;
    {
        float2 Apt = sPA[r];
        #pragma unroll
        for (int jj = 0; jj < 64; ++jj) {
            int j = jbase + jj;
            float2 B = sPB[j];
            float Mh = fmaxf(fabsf(Apt.x - B.x), fabsf(Apt.y - B.y));
            unsigned kb = Kf[jj >> 1];
            float kv = __uint_as_float((jj & 1) ? (kb & 0xffff0000u) : (kb << 16));
            acc += ((ufs * kv) * ug_l[uw(j)]) * Mh;
        }
    }
    if (q == 1) acc += 256.f * ((ufs * wa_r) * uG2f) * da_r;
    if (q == 2) acc += 256.f * ((uF2s * wb_r) * ugs) * db_r;
    acc *= cf;
    for (int o = 32; o; o >>= 1) acc += __shfl_xor(acc, o);
    if ((t & 63) == 0) pm[t >> 6] = acc;
    __syncthreads();
    if (t == 0) {
        float tot = 0.f;
        for (int i = 0; i < 16; ++i) tot += pm[i];
        wres[p] = tot * s_invsig;   // back to natural units
    }
}

__global__ void finalize_kernel(const float* __restrict__ wres, float* __restrict__ out) {
    if (threadIdx.x == 0) {
        float s = 0.f;
        for (int i = 0; i < 24; ++i) s += wres[i];
        out[0] = s * 0.25f;        // / B
    }
}

extern "C" void kernel_launch(void* const* d_in, const int* in_sizes, int n_in,
                              void* d_out, int out_size, void* d_ws, size_t ws_size,
                              hipStream_t stream) {
    const float* x = (const float*)d_in[0];   // [4,4,256,256] f32
    const int* y = (const int*)d_in[1];       // [4,1,256,256] i32
    float* ws = (float*)d_ws;
    float* pooled = ws;                        // 24*1024 floats
    float* diag = pooled + 24 * NPIX;          // 24*4*256 floats
    float* wres = diag + 24 * 4 * KTOP;        // 24 floats

    pool_kernel<<<96, 256, 0, stream>>>(x, y, pooled);
    diag_kernel<<<48, 512, 0, stream>>>(pooled, diag);
    sink_kernel<<<24, 1024, 0, stream>>>(diag, wres);
    finalize_kernel<<<1, 64, 0, stream>>>(wres, (float*)d_out);
}

// Round 6
// 1469.310 us; speedup vs baseline: 2.0806x; 1.1317x over previous
//
#include <hip/hip_runtime.h>
#include <cmath>

#define NPIX 1024
#define NEDGE 1984
#define NPAD 2048
#define KTOP 256
#define NITER 150

__device__ __forceinline__ unsigned bf_rne(float x) {
    unsigned b = __float_as_uint(x);
    return (b + 0x7fffu + ((b >> 16) & 1u)) >> 16;
}
__device__ __forceinline__ int uw2(int j) { return j + ((j >> 7) << 2); }  // +4 stagger per 128

__device__ __forceinline__ float min8v(const float* a) {
    float4 x0 = *(const float4*)a, x1 = *(const float4*)(a + 4);
    return fminf(fminf(fminf(x0.x, x0.y), fminf(x0.z, x0.w)),
                 fminf(fminf(x1.x, x1.y), fminf(x1.z, x1.w)));
}
__device__ __forceinline__ float sum8v(const float* a) {
    float4 x0 = *(const float4*)a, x1 = *(const float4*)(a + 4);
    return ((x0.x + x0.y) + (x0.z + x0.w)) + ((x1.x + x1.y) + (x1.z + x1.w));
}

// ---------------- pooling: softmax(x) and one-hot(y), adaptive-avg-pool 8x8 ----------------
__global__ __launch_bounds__(256) void pool_kernel(const float* __restrict__ x,
                                                   const int* __restrict__ y,
                                                   float* __restrict__ pooled) {
    int blk = blockIdx.x;              // 0..95
    int img = blk >> 2;                // 0..23
    int cell = ((blk & 3) << 8) | threadIdx.x;
    int gi = cell >> 5, gj = cell & 31;
    const float L2E = 1.4426950408889634f;
    float acc = 0.f;
    if (img < 12) {
        int b = img / 3, c = img % 3 + 1;
        const float* xb = x + (size_t)b * 262144 + (size_t)gi * 2048 + gj * 8;
        for (int pi = 0; pi < 8; ++pi) {
            const float* xr = xb + pi * 256;
            #pragma unroll
            for (int ph = 0; ph < 2; ++ph) {
                float4 c0 = *(const float4*)(xr + ph * 4);
                float4 c1 = *(const float4*)(xr + ph * 4 + 65536);
                float4 c2 = *(const float4*)(xr + ph * 4 + 131072);
                float4 c3 = *(const float4*)(xr + ph * 4 + 196608);
                const float* f0 = (const float*)&c0;
                const float* f1 = (const float*)&c1;
                const float* f2 = (const float*)&c2;
                const float* f3 = (const float*)&c3;
                #pragma unroll
                for (int k = 0; k < 4; ++k) {
                    float e0 = exp2f(f0[k] * L2E), e1 = exp2f(f1[k] * L2E);
                    float e2 = exp2f(f2[k] * L2E), e3 = exp2f(f3[k] * L2E);
                    float ec = (c == 1) ? e1 : (c == 2) ? e2 : e3;
                    acc += ec / (e0 + e1 + e2 + e3);
                }
            }
        }
    } else {
        int tt = img - 12;
        int b = tt / 3, c = tt % 3 + 1;
        const int* yb = y + (size_t)b * 65536 + (size_t)gi * 2048 + gj * 8;
        int cnt = 0;
        for (int pi = 0; pi < 8; ++pi) {
            const int* yr = yb + pi * 256;
            #pragma unroll
            for (int pj = 0; pj < 8; ++pj) cnt += (yr[pj] == c) ? 1 : 0;
        }
        acc = (float)cnt;
    }
    pooled[img * NPIX + cell] = acc * (1.f / 64.f);
}

// ---------------- bitonic sort of 2048 u64 keys in LDS, 512 threads ----------------
__device__ void bitonic2048(unsigned long long* keys, int tid, bool asc) {
    for (int k = 2; k <= NPAD; k <<= 1) {
        for (int j = k >> 1; j > 0; j >>= 1) {
            for (int ii = tid; ii < NPAD; ii += 512) {
                int l = ii ^ j;
                if (l > ii) {
                    unsigned long long a = keys[ii], b = keys[l];
                    bool up = (((ii & k) == 0) == asc);
                    if ((a > b) == up) { keys[ii] = b; keys[l] = a; }
                }
            }
            __syncthreads();
        }
    }
}

// ---------------- persistence diagrams (H0 sublevel / H1 via superlevel duality) ------------
// Serial union-find body byte-identical to round-2/5 (verified absmax 0.0); adds only the
// barrier-separated parallel pointer-jumping compression between 128-edge batches.
__global__ __launch_bounds__(512) void diag_kernel(const float* __restrict__ pooled,
                                                   float* __restrict__ diag) {
    __shared__ float v_[NPIX];
    __shared__ unsigned long long keys[NPAD];
    __shared__ unsigned long long PB[NPIX];      // low 32: parent, high 32: birth (f32 bits)
    __shared__ float pbs[NEDGE];
    __shared__ float pds[NEDGE];
    __shared__ float redA[8], redB[8];
    __shared__ float svmin, svmax;

    int run = blockIdx.x;      // 0..47
    int img = run >> 1, filt = run & 1;
    int tid = threadIdx.x;
    const float* m = pooled + img * NPIX;

    for (int i = tid; i < NPIX; i += 512) {
        float val = m[i];
        v_[i] = filt ? -val : val;
    }
    __syncthreads();
    // min/max (for the essential H0 class)
    float mn = INFINITY, mx = -INFINITY;
    for (int i = tid; i < NPIX; i += 512) { float vv = v_[i]; mn = fminf(mn, vv); mx = fmaxf(mx, vv); }
    for (int o = 32; o; o >>= 1) { mn = fminf(mn, __shfl_xor(mn, o)); mx = fmaxf(mx, __shfl_xor(mx, o)); }
    if ((tid & 63) == 0) { redA[tid >> 6] = mn; redB[tid >> 6] = mx; }
    __syncthreads();
    if (tid == 0) {
        float a = INFINITY, b = -INFINITY;
        for (int i2 = 0; i2 < 8; ++i2) { a = fminf(a, redA[i2]); b = fmaxf(b, redB[i2]); }
        svmin = a; svmax = b;
    }
    // edge keys: stable sort by (weight, edge index) — replicates jnp.argsort (stable)
    for (int e = tid; e < NPAD; e += 512) {
        unsigned long long key;
        if (e < NEDGE) {
            int u, vv;
            if (e < 992) { int r = e / 31; u = e + r; vv = u + 1; }   // horizontal
            else         { u = e - 992;   vv = u + 32; }              // vertical
            float w = fmaxf(v_[u], v_[vv]);
            unsigned int bw = __float_as_uint(w);
            bw = (bw & 0x80000000u) ? ~bw : (bw | 0x80000000u);       // orderable float bits
            key = ((unsigned long long)bw << 11) | (unsigned int)e;
        } else key = ~0ULL;
        keys[e] = key;
    }
    for (int i = tid; i < NPIX; i += 512)
        PB[i] = ((unsigned long long)__float_as_uint(v_[i]) << 32) | (unsigned)i;
    __syncthreads();
    bitonic2048(keys, tid, true);   // ascending; ends with a barrier

    // Kruskal/union-find with elder rule. Serial per-batch scan (thread 0) + parallel
    // pointer-jumping compression between batches (changes only parent pointers to
    // ancestors — roots and births untouched, so pair output is identical).
    unsigned* PBlo = (unsigned*)PB;
    for (int base = 0; base < NEDGE; base += 128) {
        if (base) {
            for (int rd = 0; rd < 4; ++rd) {
                for (int i = tid; i < NPIX; i += 512) {
                    unsigned pp = PBlo[2 * i];
                    unsigned gg = PBlo[2 * pp];
                    PBlo[2 * i] = gg;           // benign race: result is always an ancestor
                }
            }
        }
        __syncthreads();
        if (tid == 0) {
            int bend = (base + 128 < NEDGE) ? base + 128 : NEDGE;
            for (int kk = base; kk < bend; ++kk) {
                unsigned long long key = keys[kk];
                int e = (int)(key & 2047ULL);
                unsigned ob = (unsigned)(key >> 11);
                float w = __uint_as_float((ob & 0x80000000u) ? (ob & 0x7fffffffu) : ~ob);
                int u, vv;
                if (e < 992) { int rr = e / 31; u = e + rr; vv = u + 1; }
                else         { u = e - 992;    vv = u + 32; }
                int a = u, b = vv;
                unsigned long long qa = PB[a], qb = PB[b];
                int pa = (int)(unsigned)qa, pb = (int)(unsigned)qb;
                while (pa != a || pb != b) {
                    if (pa != a) {
                        unsigned long long na = PB[pa];
                        int ga = (int)(unsigned)na;
                        PBlo[2 * a] = (unsigned)ga;     // compress a -> grandparent
                        a = pa; pa = ga; qa = na;
                    }
                    if (pb != b) {
                        unsigned long long nb = PB[pb];
                        int gb = (int)(unsigned)nb;
                        PBlo[2 * b] = (unsigned)gb;
                        b = pb; pb = gb; qb = nb;
                    }
                }
                float pb_, pd_;
                if (a != b) {
                    float bu = __uint_as_float((unsigned)(qa >> 32));
                    float bv = __uint_as_float((unsigned)(qb >> 32));
                    bool uo = (bu <= bv);                 // tie -> root of u (matches reference)
                    int older = uo ? a : b;
                    int younger = uo ? b : a;
                    pb_ = fmaxf(bu, bv); pd_ = w;         // younger component dies
                    PBlo[2 * younger] = (unsigned)older;  // birth[older] already the min
                } else { pb_ = w; pd_ = w; }              // trivial edge -> diagonal pair
                pbs[kk] = pb_; pds[kk] = pd_;
            }
        }
        __syncthreads();
    }

    // top-k by persistence, ties -> lower index (matches jax.lax.top_k)
    int count = filt ? NEDGE : (NEDGE + 1);
    for (int k = tid; k < NPAD; k += 512) {
        unsigned long long key = 0ULL;
        if (k < count) {
            float pers = (k < NEDGE) ? (pds[k] - pbs[k]) : (svmax - svmin);
            key = ((unsigned long long)__float_as_uint(pers) << 32) | (unsigned int)(2047 - k);
        }
        keys[k] = key;
    }
    __syncthreads();
    bitonic2048(keys, tid, false);  // descending

    if (tid < KTOP) {
        unsigned long long key = keys[tid];
        int k = 2047 - (int)(key & 0xffffffffULL);
        float b_, d_;
        if (k < NEDGE) { b_ = pbs[k]; d_ = pds[k]; }
        else           { b_ = svmin;  d_ = svmax; }
        float ob, od;
        if (!filt) { ob = b_;  od = d_;  }       // H0 pairs
        else       { ob = -d_; od = -b_; }       // H1 = negated superlevel H0
        diag[((img * 4) + filt * 2 + 0) * KTOP + tid] = ob;
        diag[((img * 4) + filt * 2 + 1) * KTOP + tid] = od;
    }
}

// ---------------- entropic Sinkhorn: multiplicative + per-phase fold normalization ----------
// 512 threads, 2 lanes/row; full K row register-resident (Kf[64]+Kg[64] u32, bf16x2 packed).
// Folded sums: Rf = cg*(Kf.ugs + 256*uG2s*wa), cg = min(prev folded Qf) -> f32-safe.
// Algebra telescopes: final P_ij = cf_last * ufs_i * K_ij * ugs_j.
__global__ __launch_bounds__(512, 2) void sink_kernel(const float* __restrict__ diag,
                                                      float* __restrict__ wres) {
    __shared__ float2 sPA[KTOP], sPB[KTOP];
    __shared__ float sda[KTOP], sdb[KTOP];
    __shared__ float swa[KTOP], swb[KTOP];
    __shared__ __align__(16) float ug_l[264];
    __shared__ __align__(16) float uf_l[264];
    __shared__ __align__(16) float minF[8], accTF[8], minG[8], accTG[8];
    __shared__ __align__(16) float pm[8];
    __shared__ float s_sig, s_invsig;

    int p = blockIdx.x;            // 0..23
    int img = p % 12, dim = p / 12;
    int t = threadIdx.x;
    int r = t >> 1, q = t & 1;     // 2 q-lanes per row, adjacent lanes -> 1 shfl combine
    int jbase = q * 128;
    int w = t >> 6;                // wave id 0..7

    const float* ab  = diag + ((img * 4) + dim * 2) * KTOP;
    const float* ad  = ab + KTOP;
    const float* bbp = diag + (((12 + img) * 4) + dim * 2) * KTOP;
    const float* bdp = bbp + KTOP;

    if (t < KTOP) {
        float a0 = ab[t], a1 = ad[t];
        float b0 = bbp[t], b1 = bdp[t];
        sPA[t] = make_float2(a0, a1);
        sPB[t] = make_float2(b0, b1);
        sda[t] = 0.5f * (a1 - a0);
        sdb[t] = 0.5f * (b1 - b0);
    }
    __syncthreads();

    // maxC (unscaled)
    {
        float2 A = sPA[r];
        float lmax = 0.f;
        for (int jj = 0; jj < 128; ++jj) {
            float2 B = sPB[jbase + jj];
            lmax = fmaxf(lmax, fmaxf(fabsf(A.x - B.x), fabsf(A.y - B.y)));
        }
        if (t < KTOP) lmax = fmaxf(lmax, fmaxf(sda[t], sdb[t]));
        for (int o = 32; o; o >>= 1) lmax = fmaxf(lmax, __shfl_xor(lmax, o));
        if ((t & 63) == 0) pm[w] = lmax;
    }
    __syncthreads();
    if (t == 0) {
        float mc = 0.f;
        for (int i = 0; i < 8; ++i) mc = fmaxf(mc, pm[i]);
        float eps = 0.02f * fmaxf(mc, 1e-6f);
        s_sig = 1.4426950408889634f / eps;        // log2(e)/eps
        s_invsig = eps * 0.6931471805599453f;     // eps*ln2
    }
    __syncthreads();
    {
        float sig = s_sig;
        if (t < KTOP) {
            float2 a2 = sPA[t], b2 = sPB[t];
            sPA[t] = make_float2(a2.x * sig, a2.y * sig);
            sPB[t] = make_float2(b2.x * sig, b2.y * sig);
            float da2 = sda[t] * sig, db2 = sdb[t] * sig;
            sda[t] = da2; sdb[t] = db2;
            swa[t] = exp2f(-da2); swb[t] = exp2f(-db2);
            ug_l[uw2(t)] = 1.f;
        }
    }
    __syncthreads();

    // register-resident bf16-packed kernel row/col slices (constant across iterations)
    unsigned Kf[64], Kg[64];
    {
        float2 Apt = sPA[r];
        float2 Bc  = sPB[r];
        #pragma unroll
        for (int p2 = 0; p2 < 64; ++p2) {
            int j0 = jbase + 2 * p2;
            float2 B0 = sPB[j0], B1 = sPB[j0 + 1];
            float m0 = fmaxf(fabsf(Apt.x - B0.x), fabsf(Apt.y - B0.y));
            float m1 = fmaxf(fabsf(Apt.x - B1.x), fabsf(Apt.y - B1.y));
            Kf[p2] = bf_rne(exp2f(-m0)) | (bf_rne(exp2f(-m1)) << 16);
            float2 A0 = sPA[j0], A1 = sPA[j0 + 1];
            float n0 = fmaxf(fabsf(A0.x - Bc.x), fabsf(A0.y - Bc.y));
            float n1 = fmaxf(fabsf(A1.x - Bc.x), fabsf(A1.y - Bc.y));
            Kg[p2] = bf_rne(exp2f(-n0)) | (bf_rne(exp2f(-n1)) << 16);
        }
    }
    float wa_r = swa[r], wb_r = swb[r], da_r = sda[r], db_r = sdb[r];

    float ugs = 1.f, ufs = 1.f, uG2s = 1.f, uF2s = 1.f;
    float cg = 1.f, cf = 1.f;
    for (int it = 0; it < NITER; ++it) {
        // ---- f phase ----
        if (it) {
            cg = min8v(minG);
            uG2s = 1.f / (cf * (sum8v(accTG) + 256.f * uF2s));
        }
        {
            float S0 = 0.f, S1 = 0.f, S2 = 0.f, S3 = 0.f;
            const float4* u4 = (const float4*)ug_l + q * 33;
            #pragma unroll
            for (int p4 = 0; p4 < 32; ++p4) {
                float4 uv = u4[p4];
                unsigned k0 = Kf[2 * p4], k1 = Kf[2 * p4 + 1];
                S0 = fmaf(__uint_as_float(k0 << 16),          uv.x, S0);
                S1 = fmaf(__uint_as_float(k0 & 0xffff0000u),  uv.y, S1);
                S2 = fmaf(__uint_as_float(k1 << 16),          uv.z, S2);
                S3 = fmaf(__uint_as_float(k1 & 0xffff0000u),  uv.w, S3);
            }
            float S = (S0 + S1) + (S2 + S3);
            S += __shfl_xor(S, 1);                              // full row sum, both lanes
            float Rf = cg * (S + 256.f * uG2s * wa_r);
            ufs = 1.f / Rf;
            if (q == 0) uf_l[uw2(r)] = ufs;
            float tv = (q == 0) ? ugs * wb_r : 0.f;             // T_f partial (old ug)
            float mv = Rf;
            #pragma unroll
            for (int o = 1; o < 64; o <<= 1) {
                tv += __shfl_xor(tv, o);
                mv = fminf(mv, __shfl_xor(mv, o));
            }
            if ((t & 63) == 0) { accTF[w] = tv; minF[w] = mv; }
        }
        __syncthreads();
        // ---- g phase ----
        cf = min8v(minF);
        uF2s = 1.f / (cg * (sum8v(accTF) + 256.f * uG2s));
        {
            float S0 = 0.f, S1 = 0.f, S2 = 0.f, S3 = 0.f;
            const float4* u4 = (const float4*)uf_l + q * 33;
            #pragma unroll
            for (int p4 = 0; p4 < 32; ++p4) {
                float4 uv = u4[p4];
                unsigned k0 = Kg[2 * p4], k1 = Kg[2 * p4 + 1];
                S0 = fmaf(__uint_as_float(k0 << 16),          uv.x, S0);
                S1 = fmaf(__uint_as_float(k0 & 0xffff0000u),  uv.y, S1);
                S2 = fmaf(__uint_as_float(k1 << 16),          uv.z, S2);
                S3 = fmaf(__uint_as_float(k1 & 0xffff0000u),  uv.w, S3);
            }
            float S = (S0 + S1) + (S2 + S3);
            S += __shfl_xor(S, 1);
            float Qf = cf * (S + 256.f * uF2s * wb_r);
            ugs = 1.f / Qf;
            if (q == 0) ug_l[uw2(r)] = ugs;
            float tv = (q == 0) ? ufs * wa_r : 0.f;             // T_g partial (new uf)
            float mv = Qf;
            #pragma unroll
            for (int o = 1; o < 64; o <<= 1) {
                tv += __shfl_xor(tv, o);
                mv = fminf(mv, __shfl_xor(mv, o));
            }
            if ((t & 63) == 0) { accTG[w] = tv; minG[w] = mv; }
        }
        __syncthreads();
    }
    // final G2 (reference's G2 after last g update); overall plan scale = cf
    float uG2f = 1.f / (cf * (sum8v(accTG) + 256.f * uF2s));

    // ---- final cost sum(P*C): P_ij = cf * ufs_i * K_ij * ugs_j,  C = Mhat*invsig ----
    float acc = 0.f;
    {
        float2 Apt = sPA[r];
        #pragma unroll
        for (int jj = 0; jj < 128; ++jj) {
            int j = jbase + jj;
            float2 B = sPB[j];
            float Mh = fmaxf(fabsf(Apt.x - B.x), fabsf(Apt.y - B.y));
            unsigned kb = Kf[jj >> 1];
            float kv = __uint_as_float((jj & 1) ? (kb & 0xffff0000u) : (kb << 16));
            acc += ((ufs * kv) * ug_l[uw2(j)]) * Mh;
        }
    }
    if (q == 0) acc += 256.f * ((ufs * wa_r) * uG2f) * da_r;
    else        acc += 256.f * ((uF2s * wb_r) * ugs) * db_r;
    acc *= cf;
    for (int o = 32; o; o >>= 1) acc += __shfl_xor(acc, o);
    if ((t & 63) == 0) pm[w] = acc;
    __syncthreads();
    if (t == 0) {
        float tot = 0.f;
        for (int i = 0; i < 8; ++i) tot += pm[i];
        wres[p] = tot * s_invsig;   // back to natural units
    }
}

__global__ void finalize_kernel(const float* __restrict__ wres, float* __restrict__ out) {
    if (threadIdx.x == 0) {
        float s = 0.f;
        for (int i = 0; i < 24; ++i) s += wres[i];
        out[0] = s * 0.25f;        // / B
    }
}

extern "C" void kernel_launch(void* const* d_in, const int* in_sizes, int n_in,
                              void* d_out, int out_size, void* d_ws, size_t ws_size,
                              hipStream_t stream) {
    const float* x = (const float*)d_in[0];   // [4,4,256,256] f32
    const int* y = (const int*)d_in[1];       // [4,1,256,256] i32
    float* ws = (float*)d_ws;
    float* pooled = ws;                        // 24*1024 floats
    float* diag = pooled + 24 * NPIX;          // 24*4*256 floats
    float* wres = diag + 24 * 4 * KTOP;        // 24 floats

    pool_kernel<<<96, 256, 0, stream>>>(x, y, pooled);
    diag_kernel<<<48, 512, 0, stream>>>(pooled, diag);
    sink_kernel<<<24, 512, 0, stream>>>(diag, wres);
    finalize_kernel<<<1, 64, 0, stream>>>(wres, (float*)d_out);
}

// Round 7
// 1418.918 us; speedup vs baseline: 2.1545x; 1.0355x over previous
//
#include <hip/hip_runtime.h>
#include <cmath>

#define NPIX 1024
#define NEDGE 1984
#define NPAD 2048
#define KTOP 256
#define NITER 150

__device__ __forceinline__ unsigned bf_rne(float x) {
    unsigned b = __float_as_uint(x);
    return (b + 0x7fffu + ((b >> 16) & 1u)) >> 16;
}
__device__ __forceinline__ float rcpf(float x) { return __builtin_amdgcn_rcpf(x); }

template<int CTRL>
__device__ __forceinline__ float dppf(float x) {
    return __int_as_float(__builtin_amdgcn_update_dpp(
        __float_as_int(x), __float_as_int(x), CTRL, 0xF, 0xF, false));
}
// fused wave64 sum(s) + min(m): 4 DPP row_ror (VALU) + 1 ds_swizzle xor16 + readlanes
__device__ __forceinline__ void wave_red2(float& s, float& m) {
    s += dppf<0x121>(s); m = fminf(m, dppf<0x121>(m));
    s += dppf<0x122>(s); m = fminf(m, dppf<0x122>(m));
    s += dppf<0x124>(s); m = fminf(m, dppf<0x124>(m));
    s += dppf<0x128>(s); m = fminf(m, dppf<0x128>(m));
    s += __int_as_float(__builtin_amdgcn_ds_swizzle(__float_as_int(s), 0x401F));
    m = fminf(m, __int_as_float(__builtin_amdgcn_ds_swizzle(__float_as_int(m), 0x401F)));
    float s0 = __int_as_float(__builtin_amdgcn_readlane(__float_as_int(s), 0));
    float s1 = __int_as_float(__builtin_amdgcn_readlane(__float_as_int(s), 32));
    s = s0 + s1;
    float m0 = __int_as_float(__builtin_amdgcn_readlane(__float_as_int(m), 0));
    float m1 = __int_as_float(__builtin_amdgcn_readlane(__float_as_int(m), 32));
    m = fminf(m0, m1);
}

__device__ __forceinline__ float min8v(const float* a) {
    float4 x0 = *(const float4*)a, x1 = *(const float4*)(a + 4);
    return fminf(fminf(fminf(x0.x, x0.y), fminf(x0.z, x0.w)),
                 fminf(fminf(x1.x, x1.y), fminf(x1.z, x1.w)));
}
__device__ __forceinline__ float sum8v(const float* a) {
    float4 x0 = *(const float4*)a, x1 = *(const float4*)(a + 4);
    return ((x0.x + x0.y) + (x0.z + x0.w)) + ((x1.x + x1.y) + (x1.z + x1.w));
}

// ---------------- pooling: softmax(x) and one-hot(y), adaptive-avg-pool 8x8 ----------------
__global__ __launch_bounds__(256) void pool_kernel(const float* __restrict__ x,
                                                   const int* __restrict__ y,
                                                   float* __restrict__ pooled) {
    int blk = blockIdx.x;              // 0..95
    int img = blk >> 2;                // 0..23
    int cell = ((blk & 3) << 8) | threadIdx.x;
    int gi = cell >> 5, gj = cell & 31;
    const float L2E = 1.4426950408889634f;
    float acc = 0.f;
    if (img < 12) {
        int b = img / 3, c = img % 3 + 1;
        const float* xb = x + (size_t)b * 262144 + (size_t)gi * 2048 + gj * 8;
        for (int pi = 0; pi < 8; ++pi) {
            const float* xr = xb + pi * 256;
            #pragma unroll
            for (int ph = 0; ph < 2; ++ph) {
                float4 c0 = *(const float4*)(xr + ph * 4);
                float4 c1 = *(const float4*)(xr + ph * 4 + 65536);
                float4 c2 = *(const float4*)(xr + ph * 4 + 131072);
                float4 c3 = *(const float4*)(xr + ph * 4 + 196608);
                const float* f0 = (const float*)&c0;
                const float* f1 = (const float*)&c1;
                const float* f2 = (const float*)&c2;
                const float* f3 = (const float*)&c3;
                #pragma unroll
                for (int k = 0; k < 4; ++k) {
                    float e0 = exp2f(f0[k] * L2E), e1 = exp2f(f1[k] * L2E);
                    float e2 = exp2f(f2[k] * L2E), e3 = exp2f(f3[k] * L2E);
                    float ec = (c == 1) ? e1 : (c == 2) ? e2 : e3;
                    acc += ec / (e0 + e1 + e2 + e3);
                }
            }
        }
    } else {
        int tt = img - 12;
        int b = tt / 3, c = tt % 3 + 1;
        const int* yb = y + (size_t)b * 65536 + (size_t)gi * 2048 + gj * 8;
        int cnt = 0;
        for (int pi = 0; pi < 8; ++pi) {
            const int* yr = yb + pi * 256;
            #pragma unroll
            for (int pj = 0; pj < 8; ++pj) cnt += (yr[pj] == c) ? 1 : 0;
        }
        acc = (float)cnt;
    }
    pooled[img * NPIX + cell] = acc * (1.f / 64.f);
}

// ---------------- bitonic sort of 2048 u64 keys in LDS, 512 threads ----------------
__device__ void bitonic2048(unsigned long long* keys, int tid, bool asc) {
    for (int k = 2; k <= NPAD; k <<= 1) {
        for (int j = k >> 1; j > 0; j >>= 1) {
            for (int ii = tid; ii < NPAD; ii += 512) {
                int l = ii ^ j;
                if (l > ii) {
                    unsigned long long a = keys[ii], b = keys[l];
                    bool up = (((ii & k) == 0) == asc);
                    if ((a > b) == up) { keys[ii] = b; keys[l] = a; }
                }
            }
            __syncthreads();
        }
    }
}

// ---------------- persistence diagrams (H0 sublevel / H1 via superlevel duality) ------------
// Serial union-find body semantics byte-identical to round-2/5/6 (verified absmax 0.0).
// Added: read-only pipelining of keys (2 ahead) + euv LUT (1 ahead); PB reads stay
// strictly in-iteration (no speculative PB prefetch — that was the r3/r4 failure).
__global__ __launch_bounds__(512) void diag_kernel(const float* __restrict__ pooled,
                                                   float* __restrict__ diag) {
    __shared__ float v_[NPIX];
    __shared__ unsigned long long keys[NPAD];
    __shared__ unsigned long long PB[NPIX];      // low 32: parent, high 32: birth (f32 bits)
    __shared__ unsigned euv[NPAD];               // u | v<<16 per edge index
    __shared__ unsigned long long pbd[NEDGE];    // low: pb bits, high: pd bits
    __shared__ float redA[8], redB[8];
    __shared__ float svmin, svmax;

    int run = blockIdx.x;      // 0..47
    int img = run >> 1, filt = run & 1;
    int tid = threadIdx.x;
    const float* m = pooled + img * NPIX;

    for (int i = tid; i < NPIX; i += 512) {
        float val = m[i];
        v_[i] = filt ? -val : val;
    }
    __syncthreads();
    // min/max (for the essential H0 class)
    float mn = INFINITY, mx = -INFINITY;
    for (int i = tid; i < NPIX; i += 512) { float vv = v_[i]; mn = fminf(mn, vv); mx = fmaxf(mx, vv); }
    for (int o = 32; o; o >>= 1) { mn = fminf(mn, __shfl_xor(mn, o)); mx = fmaxf(mx, __shfl_xor(mx, o)); }
    if ((tid & 63) == 0) { redA[tid >> 6] = mn; redB[tid >> 6] = mx; }
    __syncthreads();
    if (tid == 0) {
        float a = INFINITY, b = -INFINITY;
        for (int i2 = 0; i2 < 8; ++i2) { a = fminf(a, redA[i2]); b = fmaxf(b, redB[i2]); }
        svmin = a; svmax = b;
    }
    // edge keys: stable sort by (weight, edge index) — replicates jnp.argsort (stable)
    for (int e = tid; e < NPAD; e += 512) {
        unsigned long long key;
        unsigned uv = 0;
        if (e < NEDGE) {
            int u, vv;
            if (e < 992) { int r = e / 31; u = e + r; vv = u + 1; }   // horizontal
            else         { u = e - 992;   vv = u + 32; }              // vertical
            float w = fmaxf(v_[u], v_[vv]);
            unsigned int bw = __float_as_uint(w);
            bw = (bw & 0x80000000u) ? ~bw : (bw | 0x80000000u);       // orderable float bits
            key = ((unsigned long long)bw << 11) | (unsigned int)e;
            uv = (unsigned)u | ((unsigned)vv << 16);
        } else key = ~0ULL;
        keys[e] = key;
        euv[e] = uv;
    }
    for (int i = tid; i < NPIX; i += 512)
        PB[i] = ((unsigned long long)__float_as_uint(v_[i]) << 32) | (unsigned)i;
    __syncthreads();
    bitonic2048(keys, tid, true);   // ascending; ends with a barrier

    // Kruskal/union-find with elder rule. Serial per-batch scan (thread 0) + parallel
    // pointer-jumping compression between batches (changes only parent pointers to
    // ancestors — roots and births untouched, so pair output is identical).
    unsigned* PBlo = (unsigned*)PB;
    for (int base = 0; base < NEDGE; base += 128) {
        if (base) {
            for (int rd = 0; rd < 4; ++rd) {
                for (int i = tid; i < NPIX; i += 512) {
                    unsigned pp = PBlo[2 * i];
                    unsigned gg = PBlo[2 * pp];
                    PBlo[2 * i] = gg;           // benign race: result is always an ancestor
                }
            }
        }
        __syncthreads();
        if (tid == 0) {
            int bend = (base + 128 < NEDGE) ? base + 128 : NEDGE;
            unsigned long long kc = keys[base];
            unsigned long long kn = keys[base + 1];
            unsigned uvc = euv[(int)(kc & 2047ULL)];
            for (int kk = base; kk < bend; ++kk) {
                unsigned long long k2 = keys[kk + 2];           // read-only prefetch (kk+2 <= 1985)
                unsigned uvn = euv[(int)(kn & 2047ULL)];        // read-only prefetch
                unsigned ob = (unsigned)(kc >> 11);
                float w = __uint_as_float((ob & 0x80000000u) ? (ob & 0x7fffffffu) : ~ob);
                int u = (int)(uvc & 0xffffu), vv = (int)(uvc >> 16);
                int a = u, b = vv;
                unsigned long long qa = PB[a], qb = PB[b];
                int pa = (int)(unsigned)qa, pb = (int)(unsigned)qb;
                while (pa != a || pb != b) {
                    if (pa != a) {
                        unsigned long long na = PB[pa];
                        int ga = (int)(unsigned)na;
                        PBlo[2 * a] = (unsigned)ga;     // compress a -> grandparent
                        a = pa; pa = ga; qa = na;
                    }
                    if (pb != b) {
                        unsigned long long nb = PB[pb];
                        int gb = (int)(unsigned)nb;
                        PBlo[2 * b] = (unsigned)gb;
                        b = pb; pb = gb; qb = nb;
                    }
                }
                float pb_, pd_;
                if (a != b) {
                    float bu = __uint_as_float((unsigned)(qa >> 32));
                    float bv = __uint_as_float((unsigned)(qb >> 32));
                    bool uo = (bu <= bv);                 // tie -> root of u (matches reference)
                    int older = uo ? a : b;
                    int younger = uo ? b : a;
                    pb_ = fmaxf(bu, bv); pd_ = w;         // younger component dies
                    PBlo[2 * younger] = (unsigned)older;  // birth[older] already the min
                } else { pb_ = w; pd_ = w; }              // trivial edge -> diagonal pair
                pbd[kk] = (unsigned long long)__float_as_uint(pb_)
                        | ((unsigned long long)__float_as_uint(pd_) << 32);
                kc = kn; kn = k2; uvc = uvn;
            }
        }
        __syncthreads();
    }

    // top-k by persistence, ties -> lower index (matches jax.lax.top_k)
    int count = filt ? NEDGE : (NEDGE + 1);
    for (int k = tid; k < NPAD; k += 512) {
        unsigned long long key = 0ULL;
        if (k < count) {
            float pers;
            if (k < NEDGE) {
                unsigned long long pd2 = pbd[k];
                pers = __uint_as_float((unsigned)(pd2 >> 32)) - __uint_as_float((unsigned)pd2);
            } else pers = svmax - svmin;
            key = ((unsigned long long)__float_as_uint(pers) << 32) | (unsigned int)(2047 - k);
        }
        keys[k] = key;
    }
    __syncthreads();
    bitonic2048(keys, tid, false);  // descending

    if (tid < KTOP) {
        unsigned long long key = keys[tid];
        int k = 2047 - (int)(key & 0xffffffffULL);
        float b_, d_;
        if (k < NEDGE) {
            unsigned long long pd2 = pbd[k];
            b_ = __uint_as_float((unsigned)pd2);
            d_ = __uint_as_float((unsigned)(pd2 >> 32));
        } else { b_ = svmin; d_ = svmax; }
        float ob, od;
        if (!filt) { ob = b_;  od = d_;  }       // H0 pairs
        else       { ob = -d_; od = -b_; }       // H1 = negated superlevel H0
        diag[((img * 4) + filt * 2 + 0) * KTOP + tid] = ob;
        diag[((img * 4) + filt * 2 + 1) * KTOP + tid] = od;
    }
}

// ---------------- entropic Sinkhorn: multiplicative + per-phase fold normalization ----------
// 512 threads, 2 lanes/row; K register-resident bf16x2; u vectors bf16x2-packed in LDS
// (halves LDS-pipe traffic); reduction trees on VALU via DPP row_ror + 1 ds_swizzle.
// Folded sums: Rf = cg*(Kf.ugs + 256*uG2s*wa), cg = min(prev folded Qf) -> f32-safe.
// Algebra telescopes: final P_ij = cf_last * ufs_i * K_ij * ugs_j.
#define BLO(x) __uint_as_float((x) << 16)
#define BHI(x) __uint_as_float((x) & 0xffff0000u)
__global__ __launch_bounds__(512, 2) void sink_kernel(const float* __restrict__ diag,
                                                      float* __restrict__ wres) {
    __shared__ float2 sPA[KTOP], sPB[KTOP];
    __shared__ float sda[KTOP], sdb[KTOP];
    __shared__ float swa[KTOP], swb[KTOP];
    __shared__ __align__(16) unsigned ug_l[136];   // bf16x2; half q at words [68q, 68q+63]
    __shared__ __align__(16) unsigned uf_l[136];
    __shared__ __align__(16) float minF[8], accTF[8], minG[8], accTG[8];
    __shared__ __align__(16) float pm[8];
    __shared__ float s_sig, s_invsig;

    int p = blockIdx.x;            // 0..23
    int img = p % 12, dim = p / 12;
    int t = threadIdx.x;
    int r = t >> 1, q = t & 1;     // 2 q-lanes per row (adjacent lanes)
    int jbase = q * 128;
    int w = t >> 6;                // wave id 0..7

    const float* ab  = diag + ((img * 4) + dim * 2) * KTOP;
    const float* ad  = ab + KTOP;
    const float* bbp = diag + (((12 + img) * 4) + dim * 2) * KTOP;
    const float* bdp = bbp + KTOP;

    if (t < KTOP) {
        float a0 = ab[t], a1 = ad[t];
        float b0 = bbp[t], b1 = bdp[t];
        sPA[t] = make_float2(a0, a1);
        sPB[t] = make_float2(b0, b1);
        sda[t] = 0.5f * (a1 - a0);
        sdb[t] = 0.5f * (b1 - b0);
    }
    if (t < 136) { ug_l[t] = 0x3F803F80u; }        // u = 1.0 (bf16 pair)
    __syncthreads();

    // maxC (unscaled)
    {
        float2 A = sPA[r];
        float lmax = 0.f;
        for (int jj = 0; jj < 128; ++jj) {
            float2 B = sPB[jbase + jj];
            lmax = fmaxf(lmax, fmaxf(fabsf(A.x - B.x), fabsf(A.y - B.y)));
        }
        if (t < KTOP) lmax = fmaxf(lmax, fmaxf(sda[t], sdb[t]));
        for (int o = 32; o; o >>= 1) lmax = fmaxf(lmax, __shfl_xor(lmax, o));
        if ((t & 63) == 0) pm[w] = lmax;
    }
    __syncthreads();
    if (t == 0) {
        float mc = 0.f;
        for (int i = 0; i < 8; ++i) mc = fmaxf(mc, pm[i]);
        float eps = 0.02f * fmaxf(mc, 1e-6f);
        s_sig = 1.4426950408889634f / eps;        // log2(e)/eps
        s_invsig = eps * 0.6931471805599453f;     // eps*ln2
    }
    __syncthreads();
    {
        float sig = s_sig;
        if (t < KTOP) {
            float2 a2 = sPA[t], b2 = sPB[t];
            sPA[t] = make_float2(a2.x * sig, a2.y * sig);
            sPB[t] = make_float2(b2.x * sig, b2.y * sig);
            float da2 = sda[t] * sig, db2 = sdb[t] * sig;
            sda[t] = da2; sdb[t] = db2;
            swa[t] = exp2f(-da2); swb[t] = exp2f(-db2);
        }
    }
    __syncthreads();

    // register-resident bf16-packed kernel row/col slices (constant across iterations)
    unsigned Kf[64], Kg[64];
    {
        float2 Apt = sPA[r];
        float2 Bc  = sPB[r];
        #pragma unroll
        for (int p2 = 0; p2 < 64; ++p2) {
            int j0 = jbase + 2 * p2;
            float2 B0 = sPB[j0], B1 = sPB[j0 + 1];
            float m0 = fmaxf(fabsf(Apt.x - B0.x), fabsf(Apt.y - B0.y));
            float m1 = fmaxf(fabsf(Apt.x - B1.x), fabsf(Apt.y - B1.y));
            Kf[p2] = bf_rne(exp2f(-m0)) | (bf_rne(exp2f(-m1)) << 16);
            float2 A0 = sPA[j0], A1 = sPA[j0 + 1];
            float n0 = fmaxf(fabsf(A0.x - Bc.x), fabsf(A0.y - Bc.y));
            float n1 = fmaxf(fabsf(A1.x - Bc.x), fabsf(A1.y - Bc.y));
            Kg[p2] = bf_rne(exp2f(-n0)) | (bf_rne(exp2f(-n1)) << 16);
        }
    }
    float wa_r = swa[r], wb_r = swb[r], da_r = sda[r], db_r = sdb[r];
    int uwr = 136 * (r >> 7) + (r & 127);          // ushort index of row r's slot

    float ugs = 1.f, ufs = 1.f, uG2s = 1.f, uF2s = 1.f;
    float cg = 1.f, cf = 1.f;
    for (int it = 0; it < NITER; ++it) {
        // ---- f phase ----
        if (it) {
            cg = min8v(minG);
            uG2s = rcpf(cf * (sum8v(accTG) + 256.f * uF2s));
        }
        {
            float S0 = 0.f, S1 = 0.f, S2 = 0.f, S3 = 0.f;
            const uint4* u4 = (const uint4*)ug_l + q * 17;
            #pragma unroll
            for (int p4 = 0; p4 < 16; ++p4) {
                uint4 uu = u4[p4];
                unsigned ka = Kf[4 * p4], kb = Kf[4 * p4 + 1];
                unsigned kc2 = Kf[4 * p4 + 2], kd = Kf[4 * p4 + 3];
                S0 = fmaf(BLO(ka),  BLO(uu.x), S0);
                S1 = fmaf(BHI(ka),  BHI(uu.x), S1);
                S2 = fmaf(BLO(kb),  BLO(uu.y), S2);
                S3 = fmaf(BHI(kb),  BHI(uu.y), S3);
                S0 = fmaf(BLO(kc2), BLO(uu.z), S0);
                S1 = fmaf(BHI(kc2), BHI(uu.z), S1);
                S2 = fmaf(BLO(kd),  BLO(uu.w), S2);
                S3 = fmaf(BHI(kd),  BHI(uu.w), S3);
            }
            float S = (S0 + S1) + (S2 + S3);
            S += dppf<0xB1>(S);                             // row-pair combine (xor 1)
            float Rf = cg * (S + 256.f * uG2s * wa_r);
            ufs = rcpf(Rf);
            if (q == 0) ((unsigned short*)uf_l)[uwr] = (unsigned short)bf_rne(ufs);
            float tv = (q == 0) ? ugs * wb_r : 0.f;         // T_f partial (old ug)
            float mv = Rf;
            wave_red2(tv, mv);
            if ((t & 63) == 0) { accTF[w] = tv; minF[w] = mv; }
        }
        __syncthreads();
        // ---- g phase ----
        cf = min8v(minF);
        uF2s = rcpf(cg * (sum8v(accTF) + 256.f * uG2s));
        {
            float S0 = 0.f, S1 = 0.f, S2 = 0.f, S3 = 0.f;
            const uint4* u4 = (const uint4*)uf_l + q * 17;
            #pragma unroll
            for (int p4 = 0; p4 < 16; ++p4) {
                uint4 uu = u4[p4];
                unsigned ka = Kg[4 * p4], kb = Kg[4 * p4 + 1];
                unsigned kc2 = Kg[4 * p4 + 2], kd = Kg[4 * p4 + 3];
                S0 = fmaf(BLO(ka),  BLO(uu.x), S0);
                S1 = fmaf(BHI(ka),  BHI(uu.x), S1);
                S2 = fmaf(BLO(kb),  BLO(uu.y), S2);
                S3 = fmaf(BHI(kb),  BHI(uu.y), S3);
                S0 = fmaf(BLO(kc2), BLO(uu.z), S0);
                S1 = fmaf(BHI(kc2), BHI(uu.z), S1);
                S2 = fmaf(BLO(kd),  BLO(uu.w), S2);
                S3 = fmaf(BHI(kd),  BHI(uu.w), S3);
            }
            float S = (S0 + S1) + (S2 + S3);
            S += dppf<0xB1>(S);
            float Qf = cf * (S + 256.f * uF2s * wb_r);
            ugs = rcpf(Qf);
            if (q == 0) ((unsigned short*)ug_l)[uwr] = (unsigned short)bf_rne(ugs);
            float tv = (q == 0) ? ufs * wa_r : 0.f;         // T_g partial (new uf)
            float mv = Qf;
            wave_red2(tv, mv);
            if ((t & 63) == 0) { accTG[w] = tv; minG[w] = mv; }
        }
        __syncthreads();
    }
    // final G2 (reference's G2 after last g update); overall plan scale = cf
    float uG2f = rcpf(cf * (sum8v(accTG) + 256.f * uF2s));

    // ---- final cost sum(P*C): P_ij = cf * ufs_i * K_ij * ugs_j,  C = Mhat*invsig ----
    float acc = 0.f;
    {
        float2 Apt = sPA[r];
        #pragma unroll
        for (int jj = 0; jj < 128; ++jj) {
            int j = jbase + jj;
            float2 B = sPB[j];
            float Mh = fmaxf(fabsf(Apt.x - B.x), fabsf(Apt.y - B.y));
            unsigned kb = Kf[jj >> 1];
            float kv = (jj & 1) ? BHI(kb) : BLO(kb);
            unsigned uu = ug_l[68 * q + (jj >> 1)];
            float ugv = (jj & 1) ? BHI(uu) : BLO(uu);
            acc += ((ufs * kv) * ugv) * Mh;
        }
    }
    if (q == 0) acc += 256.f * ((ufs * wa_r) * uG2f) * da_r;
    else        acc += 256.f * ((uF2s * wb_r) * ugs) * db_r;
    acc *= cf;
    for (int o = 32; o; o >>= 1) acc += __shfl_xor(acc, o);
    if ((t & 63) == 0) pm[w] = acc;
    __syncthreads();
    if (t == 0) {
        float tot = 0.f;
        for (int i = 0; i < 8; ++i) tot += pm[i];
        wres[p] = tot * s_invsig;   // back to natural units
    }
}

__global__ void finalize_kernel(const float* __restrict__ wres, float* __restrict__ out) {
    if (threadIdx.x == 0) {
        float s = 0.f;
        for (int i = 0; i < 24; ++i) s += wres[i];
        out[0] = s * 0.25f;        // / B
    }
}

extern "C" void kernel_launch(void* const* d_in, const int* in_sizes, int n_in,
                              void* d_out, int out_size, void* d_ws, size_t ws_size,
                              hipStream_t stream) {
    const float* x = (const float*)d_in[0];   // [4,4,256,256] f32
    const int* y = (const int*)d_in[1];       // [4,1,256,256] i32
    float* ws = (float*)d_ws;
    float* pooled = ws;                        // 24*1024 floats
    float* diag = pooled + 24 * NPIX;          // 24*4*256 floats
    float* wres = diag + 24 * 4 * KTOP;        // 24 floats

    pool_kernel<<<96, 256, 0, stream>>>(x, y, pooled);
    diag_kernel<<<48, 512, 0, stream>>>(pooled, diag);
    sink_kernel<<<24, 512, 0, stream>>>(diag, wres);
    finalize_kernel<<<1, 64, 0, stream>>>(wres, (float*)d_out);
}

// Round 8
// 909.960 us; speedup vs baseline: 3.3596x; 1.5593x over previous
//
#include <hip/hip_runtime.h>
#include <cmath>

#define NPIX 1024
#define NEDGE 1984
#define NPAD 2048
#define KTOP 256
#define NITER 150

typedef __attribute__((ext_vector_type(8))) short bf16x8_t;   // 8 bf16 = 4 VGPRs
typedef __attribute__((ext_vector_type(4))) float f32x4_t;

__device__ __forceinline__ unsigned bf_rne(float x) {
    unsigned b = __float_as_uint(x);
    return (b + 0x7fffu + ((b >> 16) & 1u)) >> 16;
}
__device__ __forceinline__ float rcpf(float x) { return __builtin_amdgcn_rcpf(x); }

template<int CTRL>
__device__ __forceinline__ float dppf(float x) {
    return __int_as_float(__builtin_amdgcn_update_dpp(
        __float_as_int(x), __float_as_int(x), CTRL, 0xF, 0xF, false));
}
// fused wave64 sum(s) + min(m)
__device__ __forceinline__ void wave_red2(float& s, float& m) {
    s += dppf<0x121>(s); m = fminf(m, dppf<0x121>(m));
    s += dppf<0x122>(s); m = fminf(m, dppf<0x122>(m));
    s += dppf<0x124>(s); m = fminf(m, dppf<0x124>(m));
    s += dppf<0x128>(s); m = fminf(m, dppf<0x128>(m));
    s += __int_as_float(__builtin_amdgcn_ds_swizzle(__float_as_int(s), 0x401F));
    m = fminf(m, __int_as_float(__builtin_amdgcn_ds_swizzle(__float_as_int(m), 0x401F)));
    float s0 = __int_as_float(__builtin_amdgcn_readlane(__float_as_int(s), 0));
    float s1 = __int_as_float(__builtin_amdgcn_readlane(__float_as_int(s), 32));
    s = s0 + s1;
    float m0 = __int_as_float(__builtin_amdgcn_readlane(__float_as_int(m), 0));
    float m1 = __int_as_float(__builtin_amdgcn_readlane(__float_as_int(m), 32));
    m = fminf(m0, m1);
}

__device__ __forceinline__ float min8v(const float* a) {
    float4 x0 = *(const float4*)a, x1 = *(const float4*)(a + 4);
    return fminf(fminf(fminf(x0.x, x0.y), fminf(x0.z, x0.w)),
                 fminf(fminf(x1.x, x1.y), fminf(x1.z, x1.w)));
}
__device__ __forceinline__ float sum8v(const float* a) {
    float4 x0 = *(const float4*)a, x1 = *(const float4*)(a + 4);
    return ((x0.x + x0.y) + (x0.z + x0.w)) + ((x1.x + x1.y) + (x1.z + x1.w));
}

// ---------------- pooling: softmax(x) and one-hot(y), adaptive-avg-pool 8x8 ----------------
__global__ __launch_bounds__(256) void pool_kernel(const float* __restrict__ x,
                                                   const int* __restrict__ y,
                                                   float* __restrict__ pooled) {
    int blk = blockIdx.x;              // 0..95
    int img = blk >> 2;                // 0..23
    int cell = ((blk & 3) << 8) | threadIdx.x;
    int gi = cell >> 5, gj = cell & 31;
    const float L2E = 1.4426950408889634f;
    float acc = 0.f;
    if (img < 12) {
        int b = img / 3, c = img % 3 + 1;
        const float* xb = x + (size_t)b * 262144 + (size_t)gi * 2048 + gj * 8;
        for (int pi = 0; pi < 8; ++pi) {
            const float* xr = xb + pi * 256;
            #pragma unroll
            for (int ph = 0; ph < 2; ++ph) {
                float4 c0 = *(const float4*)(xr + ph * 4);
                float4 c1 = *(const float4*)(xr + ph * 4 + 65536);
                float4 c2 = *(const float4*)(xr + ph * 4 + 131072);
                float4 c3 = *(const float4*)(xr + ph * 4 + 196608);
                const float* f0 = (const float*)&c0;
                const float* f1 = (const float*)&c1;
                const float* f2 = (const float*)&c2;
                const float* f3 = (const float*)&c3;
                #pragma unroll
                for (int k = 0; k < 4; ++k) {
                    float e0 = exp2f(f0[k] * L2E), e1 = exp2f(f1[k] * L2E);
                    float e2 = exp2f(f2[k] * L2E), e3 = exp2f(f3[k] * L2E);
                    float ec = (c == 1) ? e1 : (c == 2) ? e2 : e3;
                    acc += ec / (e0 + e1 + e2 + e3);
                }
            }
        }
    } else {
        int tt = img - 12;
        int b = tt / 3, c = tt % 3 + 1;
        const int* yb = y + (size_t)b * 65536 + (size_t)gi * 2048 + gj * 8;
        int cnt = 0;
        for (int pi = 0; pi < 8; ++pi) {
            const int* yr = yb + pi * 256;
            #pragma unroll
            for (int pj = 0; pj < 8; ++pj) cnt += (yr[pj] == c) ? 1 : 0;
        }
        acc = (float)cnt;
    }
    pooled[img * NPIX + cell] = acc * (1.f / 64.f);
}

// ---------------- bitonic sort of 2048 u64 keys in LDS, 512 threads ----------------
__device__ void bitonic2048(unsigned long long* keys, int tid, bool asc) {
    for (int k = 2; k <= NPAD; k <<= 1) {
        for (int j = k >> 1; j > 0; j >>= 1) {
            for (int ii = tid; ii < NPAD; ii += 512) {
                int l = ii ^ j;
                if (l > ii) {
                    unsigned long long a = keys[ii], b = keys[l];
                    bool up = (((ii & k) == 0) == asc);
                    if ((a > b) == up) { keys[ii] = b; keys[l] = a; }
                }
            }
            __syncthreads();
        }
    }
}

// ---------------- persistence diagrams (H0 sublevel / H1 via superlevel duality) ------------
// Byte-identical to the round-7 version (verified absmax 0.0).
__global__ __launch_bounds__(512) void diag_kernel(const float* __restrict__ pooled,
                                                   float* __restrict__ diag) {
    __shared__ float v_[NPIX];
    __shared__ unsigned long long keys[NPAD];
    __shared__ unsigned long long PB[NPIX];      // low 32: parent, high 32: birth (f32 bits)
    __shared__ unsigned euv[NPAD];               // u | v<<16 per edge index
    __shared__ unsigned long long pbd[NEDGE];    // low: pb bits, high: pd bits
    __shared__ float redA[8], redB[8];
    __shared__ float svmin, svmax;

    int run = blockIdx.x;      // 0..47
    int img = run >> 1, filt = run & 1;
    int tid = threadIdx.x;
    const float* m = pooled + img * NPIX;

    for (int i = tid; i < NPIX; i += 512) {
        float val = m[i];
        v_[i] = filt ? -val : val;
    }
    __syncthreads();
    // min/max (for the essential H0 class)
    float mn = INFINITY, mx = -INFINITY;
    for (int i = tid; i < NPIX; i += 512) { float vv = v_[i]; mn = fminf(mn, vv); mx = fmaxf(mx, vv); }
    for (int o = 32; o; o >>= 1) { mn = fminf(mn, __shfl_xor(mn, o)); mx = fmaxf(mx, __shfl_xor(mx, o)); }
    if ((tid & 63) == 0) { redA[tid >> 6] = mn; redB[tid >> 6] = mx; }
    __syncthreads();
    if (tid == 0) {
        float a = INFINITY, b = -INFINITY;
        for (int i2 = 0; i2 < 8; ++i2) { a = fminf(a, redA[i2]); b = fmaxf(b, redB[i2]); }
        svmin = a; svmax = b;
    }
    // edge keys: stable sort by (weight, edge index) — replicates jnp.argsort (stable)
    for (int e = tid; e < NPAD; e += 512) {
        unsigned long long key;
        unsigned uv = 0;
        if (e < NEDGE) {
            int u, vv;
            if (e < 992) { int r = e / 31; u = e + r; vv = u + 1; }   // horizontal
            else         { u = e - 992;   vv = u + 32; }              // vertical
            float w = fmaxf(v_[u], v_[vv]);
            unsigned int bw = __float_as_uint(w);
            bw = (bw & 0x80000000u) ? ~bw : (bw | 0x80000000u);       // orderable float bits
            key = ((unsigned long long)bw << 11) | (unsigned int)e;
            uv = (unsigned)u | ((unsigned)vv << 16);
        } else key = ~0ULL;
        keys[e] = key;
        euv[e] = uv;
    }
    for (int i = tid; i < NPIX; i += 512)
        PB[i] = ((unsigned long long)__float_as_uint(v_[i]) << 32) | (unsigned)i;
    __syncthreads();
    bitonic2048(keys, tid, true);   // ascending; ends with a barrier

    // Kruskal/union-find with elder rule. Serial per-batch scan (thread 0) + parallel
    // pointer-jumping compression between batches.
    unsigned* PBlo = (unsigned*)PB;
    for (int base = 0; base < NEDGE; base += 128) {
        if (base) {
            for (int rd = 0; rd < 4; ++rd) {
                for (int i = tid; i < NPIX; i += 512) {
                    unsigned pp = PBlo[2 * i];
                    unsigned gg = PBlo[2 * pp];
                    PBlo[2 * i] = gg;           // benign race: result is always an ancestor
                }
            }
        }
        __syncthreads();
        if (tid == 0) {
            int bend = (base + 128 < NEDGE) ? base + 128 : NEDGE;
            unsigned long long kc = keys[base];
            unsigned long long kn = keys[base + 1];
            unsigned uvc = euv[(int)(kc & 2047ULL)];
            for (int kk = base; kk < bend; ++kk) {
                unsigned long long k2 = keys[kk + 2];           // read-only prefetch
                unsigned uvn = euv[(int)(kn & 2047ULL)];        // read-only prefetch
                unsigned ob = (unsigned)(kc >> 11);
                float w = __uint_as_float((ob & 0x80000000u) ? (ob & 0x7fffffffu) : ~ob);
                int u = (int)(uvc & 0xffffu), vv = (int)(uvc >> 16);
                int a = u, b = vv;
                unsigned long long qa = PB[a], qb = PB[b];
                int pa = (int)(unsigned)qa, pb = (int)(unsigned)qb;
                while (pa != a || pb != b) {
                    if (pa != a) {
                        unsigned long long na = PB[pa];
                        int ga = (int)(unsigned)na;
                        PBlo[2 * a] = (unsigned)ga;     // compress a -> grandparent
                        a = pa; pa = ga; qa = na;
                    }
                    if (pb != b) {
                        unsigned long long nb = PB[pb];
                        int gb = (int)(unsigned)nb;
                        PBlo[2 * b] = (unsigned)gb;
                        b = pb; pb = gb; qb = nb;
                    }
                }
                float pb_, pd_;
                if (a != b) {
                    float bu = __uint_as_float((unsigned)(qa >> 32));
                    float bv = __uint_as_float((unsigned)(qb >> 32));
                    bool uo = (bu <= bv);                 // tie -> root of u (matches reference)
                    int older = uo ? a : b;
                    int younger = uo ? b : a;
                    pb_ = fmaxf(bu, bv); pd_ = w;         // younger component dies
                    PBlo[2 * younger] = (unsigned)older;  // birth[older] already the min
                } else { pb_ = w; pd_ = w; }              // trivial edge -> diagonal pair
                pbd[kk] = (unsigned long long)__float_as_uint(pb_)
                        | ((unsigned long long)__float_as_uint(pd_) << 32);
                kc = kn; kn = k2; uvc = uvn;
            }
        }
        __syncthreads();
    }

    // top-k by persistence, ties -> lower index (matches jax.lax.top_k)
    int count = filt ? NEDGE : (NEDGE + 1);
    for (int k = tid; k < NPAD; k += 512) {
        unsigned long long key = 0ULL;
        if (k < count) {
            float pers;
            if (k < NEDGE) {
                unsigned long long pd2 = pbd[k];
                pers = __uint_as_float((unsigned)(pd2 >> 32)) - __uint_as_float((unsigned)pd2);
            } else pers = svmax - svmin;
            key = ((unsigned long long)__float_as_uint(pers) << 32) | (unsigned int)(2047 - k);
        }
        keys[k] = key;
    }
    __syncthreads();
    bitonic2048(keys, tid, false);  // descending

    if (tid < KTOP) {
        unsigned long long key = keys[tid];
        int k = 2047 - (int)(key & 0xffffffffULL);
        float b_, d_;
        if (k < NEDGE) {
            unsigned long long pd2 = pbd[k];
            b_ = __uint_as_float((unsigned)pd2);
            d_ = __uint_as_float((unsigned)(pd2 >> 32));
        } else { b_ = svmin; d_ = svmax; }
        float ob, od;
        if (!filt) { ob = b_;  od = d_;  }       // H0 pairs
        else       { ob = -d_; od = -b_; }       // H1 = negated superlevel H0
        diag[((img * 4) + filt * 2 + 0) * KTOP + tid] = ob;
        diag[((img * 4) + filt * 2 + 1) * KTOP + tid] = od;
    }
}

// ---------------- entropic Sinkhorn: MFMA matvec + fold normalization ----------------------
// Per wave: rows [w*32, w*32+32). K as 16 A-frags (2 tiles x 8 k-slices) for f (K) and
// g (K^T). B operand = u broadcast into ALL 16 columns -> every lane's D regs hold S[row],
// row = w*32 + tt*16 + (lane>>4)*4 + reg (HW-verified C/D layout). Fold normalization as
// r5-r7 (verified): Rf = cg*(S + 256*uG2s*wa); final P_ij = cf * ufs_i * K_ij * ugs_j.
__global__ __launch_bounds__(512) void sink_kernel(const float* __restrict__ diag,
                                                   float* __restrict__ wres) {
    __shared__ float2 sPA[KTOP], sPB[KTOP];
    __shared__ float sda[KTOP], sdb[KTOP];
    __shared__ float swa[KTOP], swb[KTOP];
    __shared__ __align__(16) unsigned ug_bf[128];    // 256 bf16
    __shared__ __align__(16) unsigned uf_bf[128];
    __shared__ __align__(16) float uf32[KTOP], ug32[KTOP];
    __shared__ __align__(16) float minF[8], accTF[8], minG[8], accTG[8];
    __shared__ __align__(16) float pm[8];
    __shared__ float s_sig, s_invsig;

    int p = blockIdx.x;            // 0..23
    int img = p % 12, dim = p / 12;
    int t = threadIdx.x;
    int lane = t & 63, w = t >> 6;         // wave 0..7
    int lr = lane & 15, lg = lane >> 4;    // col-lane, k-group
    int r = t >> 1, q = t & 1, jb = q * 128;   // mapping for maxC / final cost

    const float* ab  = diag + ((img * 4) + dim * 2) * KTOP;
    const float* ad  = ab + KTOP;
    const float* bbp = diag + (((12 + img) * 4) + dim * 2) * KTOP;
    const float* bdp = bbp + KTOP;

    if (t < KTOP) {
        float a0 = ab[t], a1 = ad[t];
        float b0 = bbp[t], b1 = bdp[t];
        sPA[t] = make_float2(a0, a1);
        sPB[t] = make_float2(b0, b1);
        sda[t] = 0.5f * (a1 - a0);
        sdb[t] = 0.5f * (b1 - b0);
    }
    if (t < 128) ug_bf[t] = 0x3F803F80u;   // u = 1.0 (bf16 pair)
    __syncthreads();

    // maxC (unscaled)
    {
        float2 A = sPA[r];
        float lmax = 0.f;
        for (int jj = 0; jj < 128; ++jj) {
            float2 B = sPB[jb + jj];
            lmax = fmaxf(lmax, fmaxf(fabsf(A.x - B.x), fabsf(A.y - B.y)));
        }
        if (t < KTOP) lmax = fmaxf(lmax, fmaxf(sda[t], sdb[t]));
        for (int o = 32; o; o >>= 1) lmax = fmaxf(lmax, __shfl_xor(lmax, o));
        if (lane == 0) pm[w] = lmax;
    }
    __syncthreads();
    if (t == 0) {
        float mc = 0.f;
        for (int i = 0; i < 8; ++i) mc = fmaxf(mc, pm[i]);
        float eps = 0.02f * fmaxf(mc, 1e-6f);
        s_sig = 1.4426950408889634f / eps;        // log2(e)/eps
        s_invsig = eps * 0.6931471805599453f;     // eps*ln2
    }
    __syncthreads();
    {
        float sig = s_sig;
        if (t < KTOP) {
            float2 a2 = sPA[t], b2 = sPB[t];
            sPA[t] = make_float2(a2.x * sig, a2.y * sig);
            sPB[t] = make_float2(b2.x * sig, b2.y * sig);
            float da2 = sda[t] * sig, db2 = sdb[t] * sig;
            sda[t] = da2; sdb[t] = db2;
            swa[t] = exp2f(-da2); swb[t] = exp2f(-db2);
        }
    }
    __syncthreads();

    // Build A-fragments: Kf (rows of K) and Kg (rows of K^T), bf16, constant across iters.
    bf16x8_t KfA0[8], KfA1[8], KgA0[8], KgA1[8];
    {
        float2 Af0 = sPA[w * 32 + lr];
        float2 Af1 = sPA[w * 32 + 16 + lr];
        float2 Bg0 = sPB[w * 32 + lr];
        float2 Bg1 = sPB[w * 32 + 16 + lr];
        #pragma unroll
        for (int ks = 0; ks < 8; ++ks) {
            #pragma unroll
            for (int jj = 0; jj < 8; ++jj) {
                int b = ks * 32 + lg * 8 + jj;
                float2 Pb = sPB[b];
                KfA0[ks][jj] = (short)bf_rne(exp2f(-fmaxf(fabsf(Af0.x - Pb.x), fabsf(Af0.y - Pb.y))));
                KfA1[ks][jj] = (short)bf_rne(exp2f(-fmaxf(fabsf(Af1.x - Pb.x), fabsf(Af1.y - Pb.y))));
                float2 Pa = sPA[b];
                KgA0[ks][jj] = (short)bf_rne(exp2f(-fmaxf(fabsf(Pa.x - Bg0.x), fabsf(Pa.y - Bg0.y))));
                KgA1[ks][jj] = (short)bf_rne(exp2f(-fmaxf(fabsf(Pa.x - Bg1.x), fabsf(Pa.y - Bg1.y))));
            }
        }
    }
    // Diagonal weights in D layout: row = w*32 + tt*16 + lg*4 + reg
    float wa0[4], wa1[4], wb0[4], wb1[4];
    #pragma unroll
    for (int g2 = 0; g2 < 4; ++g2) {
        wa0[g2] = swa[w * 32 + lg * 4 + g2];
        wa1[g2] = swa[w * 32 + 16 + lg * 4 + g2];
        wb0[g2] = swb[w * 32 + lg * 4 + g2];
        wb1[g2] = swb[w * 32 + 16 + lg * 4 + g2];
    }

    float cg = 1.f, cf = 1.f, uG2s = 1.f, uF2s = 1.f;
    f32x4_t ugs0 = {1.f, 1.f, 1.f, 1.f}, ugs1 = {1.f, 1.f, 1.f, 1.f};
    f32x4_t ufs0 = {0.f, 0.f, 0.f, 0.f}, ufs1 = {0.f, 0.f, 0.f, 0.f};

    for (int it = 0; it < NITER; ++it) {
        // ---- f phase ----
        if (it) {
            cg = min8v(minG);
            uG2s = rcpf(cf * (sum8v(accTG) + 256.f * uF2s));
        }
        {
            bf16x8_t Bf[8];
            #pragma unroll
            for (int ks = 0; ks < 8; ++ks) Bf[ks] = ((const bf16x8_t*)ug_bf)[ks * 4 + lg];
            f32x4_t a0 = {0.f, 0.f, 0.f, 0.f}, a1 = {0.f, 0.f, 0.f, 0.f};
            #pragma unroll
            for (int ks = 0; ks < 8; ++ks) {
                a0 = __builtin_amdgcn_mfma_f32_16x16x32_bf16(KfA0[ks], Bf[ks], a0, 0, 0, 0);
                a1 = __builtin_amdgcn_mfma_f32_16x16x32_bf16(KfA1[ks], Bf[ks], a1, 0, 0, 0);
            }
            float mv = INFINITY, tv = 0.f;
            #pragma unroll
            for (int g2 = 0; g2 < 4; ++g2) {
                float R0 = cg * (a0[g2] + 256.f * uG2s * wa0[g2]);
                float R1 = cg * (a1[g2] + 256.f * uG2s * wa1[g2]);
                ufs0[g2] = rcpf(R0); ufs1[g2] = rcpf(R1);
                mv = fminf(mv, fminf(R0, R1));
                tv += ugs0[g2] * wb0[g2] + ugs1[g2] * wb1[g2];   // T_f from OLD ug
            }
            if (lr == 0) {
                uint2 v0, v1;
                v0.x = bf_rne(ufs0[0]) | (bf_rne(ufs0[1]) << 16);
                v0.y = bf_rne(ufs0[2]) | (bf_rne(ufs0[3]) << 16);
                v1.x = bf_rne(ufs1[0]) | (bf_rne(ufs1[1]) << 16);
                v1.y = bf_rne(ufs1[2]) | (bf_rne(ufs1[3]) << 16);
                ((uint2*)uf_bf)[w * 8 + lg] = v0;
                ((uint2*)uf_bf)[w * 8 + 4 + lg] = v1;
            }
            wave_red2(tv, mv);
            if (lane == 0) { accTF[w] = tv * 0.0625f; minF[w] = mv; }   // rows duplicated x16
        }
        __syncthreads();
        // ---- g phase ----
        cf = min8v(minF);
        uF2s = rcpf(cg * (sum8v(accTF) + 256.f * uG2s));
        {
            bf16x8_t Bf[8];
            #pragma unroll
            for (int ks = 0; ks < 8; ++ks) Bf[ks] = ((const bf16x8_t*)uf_bf)[ks * 4 + lg];
            f32x4_t a0 = {0.f, 0.f, 0.f, 0.f}, a1 = {0.f, 0.f, 0.f, 0.f};
            #pragma unroll
            for (int ks = 0; ks < 8; ++ks) {
                a0 = __builtin_amdgcn_mfma_f32_16x16x32_bf16(KgA0[ks], Bf[ks], a0, 0, 0, 0);
                a1 = __builtin_amdgcn_mfma_f32_16x16x32_bf16(KgA1[ks], Bf[ks], a1, 0, 0, 0);
            }
            float mv = INFINITY, tv = 0.f;
            #pragma unroll
            for (int g2 = 0; g2 < 4; ++g2) {
                float Q0 = cf * (a0[g2] + 256.f * uF2s * wb0[g2]);
                float Q1 = cf * (a1[g2] + 256.f * uF2s * wb1[g2]);
                ugs0[g2] = rcpf(Q0); ugs1[g2] = rcpf(Q1);
                mv = fminf(mv, fminf(Q0, Q1));
                tv += ufs0[g2] * wa0[g2] + ufs1[g2] * wa1[g2];   // T_g from NEW uf
            }
            if (lr == 0) {
                uint2 v0, v1;
                v0.x = bf_rne(ugs0[0]) | (bf_rne(ugs0[1]) << 16);
                v0.y = bf_rne(ugs0[2]) | (bf_rne(ugs0[3]) << 16);
                v1.x = bf_rne(ugs1[0]) | (bf_rne(ugs1[1]) << 16);
                v1.y = bf_rne(ugs1[2]) | (bf_rne(ugs1[3]) << 16);
                ((uint2*)ug_bf)[w * 8 + lg] = v0;
                ((uint2*)ug_bf)[w * 8 + 4 + lg] = v1;
            }
            wave_red2(tv, mv);
            if (lane == 0) { accTG[w] = tv * 0.0625f; minG[w] = mv; }
        }
        __syncthreads();
    }
    // final G2 (after last g update); overall plan scale = cf
    float uG2f = rcpf(cf * (sum8v(accTG) + 256.f * uF2s));
    // publish exact f32 potentials for the cost epilogue
    if (lr == 0) {
        ((f32x4_t*)uf32)[w * 8 + lg] = ufs0;
        ((f32x4_t*)uf32)[w * 8 + 4 + lg] = ufs1;
        ((f32x4_t*)ug32)[w * 8 + lg] = ugs0;
        ((f32x4_t*)ug32)[w * 8 + 4 + lg] = ugs1;
    }
    __syncthreads();

    // ---- final cost sum(P*C): P_ij = cf * ufs_i * K_ij * ugs_j,  C = Mhat*invsig ----
    float accv = 0.f;
    {
        float2 Apt = sPA[r];
        float ufr = uf32[r];
        #pragma unroll 8
        for (int jj = 0; jj < 128; ++jj) {
            int j = jb + jj;
            float2 B = sPB[j];
            float Mh = fmaxf(fabsf(Apt.x - B.x), fabsf(Apt.y - B.y));
            float kv = __uint_as_float(bf_rne(exp2f(-Mh)) << 16);   // same bf16 K as iterations
            accv += ((ufr * kv) * ug32[j]) * Mh;
        }
        if (q == 0) accv += 256.f * ((ufr * swa[r]) * uG2f) * sda[r];
        else        accv += 256.f * ((uF2s * swb[r]) * ug32[r]) * sdb[r];
    }
    accv *= cf;
    for (int o = 32; o; o >>= 1) accv += __shfl_xor(accv, o);
    if (lane == 0) pm[w] = accv;
    __syncthreads();
    if (t == 0) {
        float tot = 0.f;
        for (int i = 0; i < 8; ++i) tot += pm[i];
        wres[p] = tot * s_invsig;   // back to natural units
    }
}

__global__ void finalize_kernel(const float* __restrict__ wres, float* __restrict__ out) {
    if (threadIdx.x == 0) {
        float s = 0.f;
        for (int i = 0; i < 24; ++i) s += wres[i];
        out[0] = s * 0.25f;        // / B
    }
}

extern "C" void kernel_launch(void* const* d_in, const int* in_sizes, int n_in,
                              void* d_out, int out_size, void* d_ws, size_t ws_size,
                              hipStream_t stream) {
    const float* x = (const float*)d_in[0];   // [4,4,256,256] f32
    const int* y = (const int*)d_in[1];       // [4,1,256,256] i32
    float* ws = (float*)d_ws;
    float* pooled = ws;                        // 24*1024 floats
    float* diag = pooled + 24 * NPIX;          // 24*4*256 floats
    float* wres = diag + 24 * 4 * KTOP;        // 24 floats

    pool_kernel<<<96, 256, 0, stream>>>(x, y, pooled);
    diag_kernel<<<48, 512, 0, stream>>>(pooled, diag);
    sink_kernel<<<24, 512, 0, stream>>>(diag, wres);
    finalize_kernel<<<1, 64, 0, stream>>>(wres, (float*)d_out);
}

// Round 9
// 892.941 us; speedup vs baseline: 3.4236x; 1.0191x over previous
//
#include <hip/hip_runtime.h>
#include <cmath>

#define NPIX 1024
#define NEDGE 1984
#define NPAD 2048
#define KTOP 256
#define NITER 150

typedef __attribute__((ext_vector_type(8))) short bf16x8_t;   // 8 bf16 = 4 VGPRs
typedef __attribute__((ext_vector_type(4))) float f32x4_t;

__device__ __forceinline__ unsigned bf_rne(float x) {
    unsigned b = __float_as_uint(x);
    return (b + 0x7fffu + ((b >> 16) & 1u)) >> 16;
}
__device__ __forceinline__ float rcpf(float x) { return __builtin_amdgcn_rcpf(x); }

template<int CTRL>
__device__ __forceinline__ float dppf(float x) {
    return __int_as_float(__builtin_amdgcn_update_dpp(
        __float_as_int(x), __float_as_int(x), CTRL, 0xF, 0xF, false));
}
// fused wave64 sum(s) + min(m)
__device__ __forceinline__ void wave_red2(float& s, float& m) {
    s += dppf<0x121>(s); m = fminf(m, dppf<0x121>(m));
    s += dppf<0x122>(s); m = fminf(m, dppf<0x122>(m));
    s += dppf<0x124>(s); m = fminf(m, dppf<0x124>(m));
    s += dppf<0x128>(s); m = fminf(m, dppf<0x128>(m));
    s += __int_as_float(__builtin_amdgcn_ds_swizzle(__float_as_int(s), 0x401F));
    m = fminf(m, __int_as_float(__builtin_amdgcn_ds_swizzle(__float_as_int(m), 0x401F)));
    float s0 = __int_as_float(__builtin_amdgcn_readlane(__float_as_int(s), 0));
    float s1 = __int_as_float(__builtin_amdgcn_readlane(__float_as_int(s), 32));
    s = s0 + s1;
    float m0 = __int_as_float(__builtin_amdgcn_readlane(__float_as_int(m), 0));
    float m1 = __int_as_float(__builtin_amdgcn_readlane(__float_as_int(m), 32));
    m = fminf(m0, m1);
}

__device__ __forceinline__ float min8v(const float* a) {
    float4 x0 = *(const float4*)a, x1 = *(const float4*)(a + 4);
    return fminf(fminf(fminf(x0.x, x0.y), fminf(x0.z, x0.w)),
                 fminf(fminf(x1.x, x1.y), fminf(x1.z, x1.w)));
}
__device__ __forceinline__ float sum8v(const float* a) {
    float4 x0 = *(const float4*)a, x1 = *(const float4*)(a + 4);
    return ((x0.x + x0.y) + (x0.z + x0.w)) + ((x1.x + x1.y) + (x1.z + x1.w));
}

// ---------------- pooling: softmax(x) and one-hot(y), adaptive-avg-pool 8x8 ----------------
__global__ __launch_bounds__(256) void pool_kernel(const float* __restrict__ x,
                                                   const int* __restrict__ y,
                                                   float* __restrict__ pooled) {
    int blk = blockIdx.x;              // 0..95
    int img = blk >> 2;                // 0..23
    int cell = ((blk & 3) << 8) | threadIdx.x;
    int gi = cell >> 5, gj = cell & 31;
    const float L2E = 1.4426950408889634f;
    float acc = 0.f;
    if (img < 12) {
        int b = img / 3, c = img % 3 + 1;
        const float* xb = x + (size_t)b * 262144 + (size_t)gi * 2048 + gj * 8;
        for (int pi = 0; pi < 8; ++pi) {
            const float* xr = xb + pi * 256;
            #pragma unroll
            for (int ph = 0; ph < 2; ++ph) {
                float4 c0 = *(const float4*)(xr + ph * 4);
                float4 c1 = *(const float4*)(xr + ph * 4 + 65536);
                float4 c2 = *(const float4*)(xr + ph * 4 + 131072);
                float4 c3 = *(const float4*)(xr + ph * 4 + 196608);
                const float* f0 = (const float*)&c0;
                const float* f1 = (const float*)&c1;
                const float* f2 = (const float*)&c2;
                const float* f3 = (const float*)&c3;
                #pragma unroll
                for (int k = 0; k < 4; ++k) {
                    float e0 = exp2f(f0[k] * L2E), e1 = exp2f(f1[k] * L2E);
                    float e2 = exp2f(f2[k] * L2E), e3 = exp2f(f3[k] * L2E);
                    float ec = (c == 1) ? e1 : (c == 2) ? e2 : e3;
                    acc += ec / (e0 + e1 + e2 + e3);
                }
            }
        }
    } else {
        int tt = img - 12;
        int b = tt / 3, c = tt % 3 + 1;
        const int* yb = y + (size_t)b * 65536 + (size_t)gi * 2048 + gj * 8;
        int cnt = 0;
        for (int pi = 0; pi < 8; ++pi) {
            const int* yr = yb + pi * 256;
            #pragma unroll
            for (int pj = 0; pj < 8; ++pj) cnt += (yr[pj] == c) ? 1 : 0;
        }
        acc = (float)cnt;
    }
    pooled[img * NPIX + cell] = acc * (1.f / 64.f);
}

// ---------------- bitonic sort of 2048 u64 keys in LDS, 512 threads ----------------
__device__ void bitonic2048(unsigned long long* keys, int tid, bool asc) {
    for (int k = 2; k <= NPAD; k <<= 1) {
        for (int j = k >> 1; j > 0; j >>= 1) {
            for (int ii = tid; ii < NPAD; ii += 512) {
                int l = ii ^ j;
                if (l > ii) {
                    unsigned long long a = keys[ii], b = keys[l];
                    bool up = (((ii & k) == 0) == asc);
                    if ((a > b) == up) { keys[ii] = b; keys[l] = a; }
                }
            }
            __syncthreads();
        }
    }
}

// ---------------- persistence diagrams (H0 sublevel / H1 via superlevel duality) ------------
// Batch-snapshot union-find: per 128-edge batch, a parallel precheck (read-only walks on the
// post-compression forest) resolves each edge's roots; already-connected edges emit (w,w)
// in parallel. The serial elder-rule scan (same verified loop body) starts finds at the
// snapshot roots and reads ONLY the read-only snap[] ahead (no PB speculation).
__global__ __launch_bounds__(512) void diag_kernel(const float* __restrict__ pooled,
                                                   float* __restrict__ diag) {
    __shared__ float v_[NPIX];
    __shared__ unsigned long long keys[NPAD];
    __shared__ unsigned long long PB[NPIX];      // low 32: parent, high 32: birth (f32 bits)
    __shared__ unsigned euv[NPAD];               // u | v<<16 per edge index
    __shared__ unsigned long long pbd[NEDGE];    // low: pb bits, high: pd bits
    __shared__ unsigned long long snap[132];     // wbits<<22 | (ra+1)<<11 | (rb+1); low22==0 -> trivial
    __shared__ float redA[8], redB[8];
    __shared__ float svmin, svmax;

    int run = blockIdx.x;      // 0..47
    int img = run >> 1, filt = run & 1;
    int tid = threadIdx.x;
    const float* m = pooled + img * NPIX;

    for (int i = tid; i < NPIX; i += 512) {
        float val = m[i];
        v_[i] = filt ? -val : val;
    }
    __syncthreads();
    // min/max (for the essential H0 class)
    float mn = INFINITY, mx = -INFINITY;
    for (int i = tid; i < NPIX; i += 512) { float vv = v_[i]; mn = fminf(mn, vv); mx = fmaxf(mx, vv); }
    for (int o = 32; o; o >>= 1) { mn = fminf(mn, __shfl_xor(mn, o)); mx = fmaxf(mx, __shfl_xor(mx, o)); }
    if ((tid & 63) == 0) { redA[tid >> 6] = mn; redB[tid >> 6] = mx; }
    __syncthreads();
    if (tid == 0) {
        float a = INFINITY, b = -INFINITY;
        for (int i2 = 0; i2 < 8; ++i2) { a = fminf(a, redA[i2]); b = fmaxf(b, redB[i2]); }
        svmin = a; svmax = b;
    }
    // edge keys: stable sort by (weight, edge index) — replicates jnp.argsort (stable)
    for (int e = tid; e < NPAD; e += 512) {
        unsigned long long key;
        unsigned uv = 0;
        if (e < NEDGE) {
            int u, vv;
            if (e < 992) { int r = e / 31; u = e + r; vv = u + 1; }   // horizontal
            else         { u = e - 992;   vv = u + 32; }              // vertical
            float w = fmaxf(v_[u], v_[vv]);
            unsigned int bw = __float_as_uint(w);
            bw = (bw & 0x80000000u) ? ~bw : (bw | 0x80000000u);       // orderable float bits
            key = ((unsigned long long)bw << 11) | (unsigned int)e;
            uv = (unsigned)u | ((unsigned)vv << 16);
        } else key = ~0ULL;
        keys[e] = key;
        euv[e] = uv;
    }
    for (int i = tid; i < NPIX; i += 512)
        PB[i] = ((unsigned long long)__float_as_uint(v_[i]) << 32) | (unsigned)i;
    __syncthreads();
    bitonic2048(keys, tid, true);   // ascending; ends with a barrier

    // Kruskal/union-find with elder rule, batch-snapshot structure.
    unsigned* PBlo = (unsigned*)PB;
    for (int base = 0; base < NEDGE; base += 128) {
        // parallel pointer-jumping compression (roots/births untouched)
        if (base) {
            for (int rd = 0; rd < 4; ++rd) {
                for (int i = tid; i < NPIX; i += 512) {
                    unsigned pp = PBlo[2 * i];
                    unsigned gg = PBlo[2 * pp];
                    PBlo[2 * i] = gg;           // benign race: result is always an ancestor
                }
            }
        }
        __syncthreads();
        int bend = (base + 128 < NEDGE) ? base + 128 : NEDGE;
        int bcnt = bend - base;
        // parallel precheck: resolve snapshot roots; emit trivial pairs in parallel
        if (tid < bcnt) {
            int kk = base + tid;
            unsigned long long key = keys[kk];
            int e = (int)(key & 2047ULL);
            unsigned bw = (unsigned)(key >> 11);
            unsigned uv = euv[e];
            int ra = (int)(uv & 0xffffu), rb = (int)(uv >> 16);
            unsigned pp = PBlo[2 * ra];
            while (pp != (unsigned)ra) { ra = (int)pp; pp = PBlo[2 * ra]; }
            unsigned p2 = PBlo[2 * rb];
            while (p2 != (unsigned)rb) { rb = (int)p2; p2 = PBlo[2 * rb]; }
            if (ra == rb) {
                unsigned wb = (bw & 0x80000000u) ? (bw & 0x7fffffffu) : ~bw;
                pbd[kk] = (unsigned long long)wb | ((unsigned long long)wb << 32);
                snap[tid] = (unsigned long long)bw << 22;        // trivial marker
            } else {
                snap[tid] = ((unsigned long long)bw << 22)
                          | ((unsigned)(ra + 1) << 11) | (unsigned)(rb + 1);
            }
        }
        __syncthreads();
        // serial elder-rule scan over merge candidates (snap[] is read-only here)
        if (tid == 0) {
            unsigned long long sc = snap[0];
            for (int i = 0; i < bcnt; ++i) {
                unsigned long long sn = snap[i + 1];             // read-only prefetch, no hazard
                if ((unsigned)(sc & 0x3FFFFFu)) {
                    unsigned ob = (unsigned)(sc >> 22);
                    float w = __uint_as_float((ob & 0x80000000u) ? (ob & 0x7fffffffu) : ~ob);
                    int a = (int)((sc >> 11) & 0x7FFu) - 1;
                    int b = (int)(sc & 0x7FFu) - 1;
                    unsigned long long qa = PB[a], qb = PB[b];
                    int pa = (int)(unsigned)qa, pb = (int)(unsigned)qb;
                    while (pa != a || pb != b) {
                        if (pa != a) {
                            unsigned long long na = PB[pa];
                            int ga = (int)(unsigned)na;
                            PBlo[2 * a] = (unsigned)ga;     // path-halving compression
                            a = pa; pa = ga; qa = na;
                        }
                        if (pb != b) {
                            unsigned long long nb = PB[pb];
                            int gb = (int)(unsigned)nb;
                            PBlo[2 * b] = (unsigned)gb;
                            b = pb; pb = gb; qb = nb;
                        }
                    }
                    float pb_, pd_;
                    if (a != b) {
                        float bu = __uint_as_float((unsigned)(qa >> 32));
                        float bv = __uint_as_float((unsigned)(qb >> 32));
                        bool uo = (bu <= bv);                 // tie -> root on u's side (values invariant)
                        int older = uo ? a : b;
                        int younger = uo ? b : a;
                        pb_ = fmaxf(bu, bv); pd_ = w;         // younger component dies
                        PBlo[2 * younger] = (unsigned)older;  // birth[older] already the min
                    } else { pb_ = w; pd_ = w; }              // became trivial within batch
                    pbd[base + i] = (unsigned long long)__float_as_uint(pb_)
                                  | ((unsigned long long)__float_as_uint(pd_) << 32);
                }
                sc = sn;
            }
        }
        __syncthreads();
    }

    // top-k by persistence, ties -> lower index (matches jax.lax.top_k)
    int count = filt ? NEDGE : (NEDGE + 1);
    for (int k = tid; k < NPAD; k += 512) {
        unsigned long long key = 0ULL;
        if (k < count) {
            float pers;
            if (k < NEDGE) {
                unsigned long long pd2 = pbd[k];
                pers = __uint_as_float((unsigned)(pd2 >> 32)) - __uint_as_float((unsigned)pd2);
            } else pers = svmax - svmin;
            key = ((unsigned long long)__float_as_uint(pers) << 32) | (unsigned int)(2047 - k);
        }
        keys[k] = key;
    }
    __syncthreads();
    bitonic2048(keys, tid, false);  // descending

    if (tid < KTOP) {
        unsigned long long key = keys[tid];
        int k = 2047 - (int)(key & 0xffffffffULL);
        float b_, d_;
        if (k < NEDGE) {
            unsigned long long pd2 = pbd[k];
            b_ = __uint_as_float((unsigned)pd2);
            d_ = __uint_as_float((unsigned)(pd2 >> 32));
        } else { b_ = svmin; d_ = svmax; }
        float ob, od;
        if (!filt) { ob = b_;  od = d_;  }       // H0 pairs
        else       { ob = -d_; od = -b_; }       // H1 = negated superlevel H0
        diag[((img * 4) + filt * 2 + 0) * KTOP + tid] = ob;
        diag[((img * 4) + filt * 2 + 1) * KTOP + tid] = od;
    }
}

// ---------------- entropic Sinkhorn: MFMA matvec + fold normalization ----------------------
// Byte-identical to the round-8 version (verified absmax 0.0).
__global__ __launch_bounds__(512) void sink_kernel(const float* __restrict__ diag,
                                                   float* __restrict__ wres) {
    __shared__ float2 sPA[KTOP], sPB[KTOP];
    __shared__ float sda[KTOP], sdb[KTOP];
    __shared__ float swa[KTOP], swb[KTOP];
    __shared__ __align__(16) unsigned ug_bf[128];    // 256 bf16
    __shared__ __align__(16) unsigned uf_bf[128];
    __shared__ __align__(16) float uf32[KTOP], ug32[KTOP];
    __shared__ __align__(16) float minF[8], accTF[8], minG[8], accTG[8];
    __shared__ __align__(16) float pm[8];
    __shared__ float s_sig, s_invsig;

    int p = blockIdx.x;            // 0..23
    int img = p % 12, dim = p / 12;
    int t = threadIdx.x;
    int lane = t & 63, w = t >> 6;         // wave 0..7
    int lr = lane & 15, lg = lane >> 4;    // col-lane, k-group
    int r = t >> 1, q = t & 1, jb = q * 128;   // mapping for maxC / final cost

    const float* ab  = diag + ((img * 4) + dim * 2) * KTOP;
    const float* ad  = ab + KTOP;
    const float* bbp = diag + (((12 + img) * 4) + dim * 2) * KTOP;
    const float* bdp = bbp + KTOP;

    if (t < KTOP) {
        float a0 = ab[t], a1 = ad[t];
        float b0 = bbp[t], b1 = bdp[t];
        sPA[t] = make_float2(a0, a1);
        sPB[t] = make_float2(b0, b1);
        sda[t] = 0.5f * (a1 - a0);
        sdb[t] = 0.5f * (b1 - b0);
    }
    if (t < 128) ug_bf[t] = 0x3F803F80u;   // u = 1.0 (bf16 pair)
    __syncthreads();

    // maxC (unscaled)
    {
        float2 A = sPA[r];
        float lmax = 0.f;
        for (int jj = 0; jj < 128; ++jj) {
            float2 B = sPB[jb + jj];
            lmax = fmaxf(lmax, fmaxf(fabsf(A.x - B.x), fabsf(A.y - B.y)));
        }
        if (t < KTOP) lmax = fmaxf(lmax, fmaxf(sda[t], sdb[t]));
        for (int o = 32; o; o >>= 1) lmax = fmaxf(lmax, __shfl_xor(lmax, o));
        if (lane == 0) pm[w] = lmax;
    }
    __syncthreads();
    if (t == 0) {
        float mc = 0.f;
        for (int i = 0; i < 8; ++i) mc = fmaxf(mc, pm[i]);
        float eps = 0.02f * fmaxf(mc, 1e-6f);
        s_sig = 1.4426950408889634f / eps;        // log2(e)/eps
        s_invsig = eps * 0.6931471805599453f;     // eps*ln2
    }
    __syncthreads();
    {
        float sig = s_sig;
        if (t < KTOP) {
            float2 a2 = sPA[t], b2 = sPB[t];
            sPA[t] = make_float2(a2.x * sig, a2.y * sig);
            sPB[t] = make_float2(b2.x * sig, b2.y * sig);
            float da2 = sda[t] * sig, db2 = sdb[t] * sig;
            sda[t] = da2; sdb[t] = db2;
            swa[t] = exp2f(-da2); swb[t] = exp2f(-db2);
        }
    }
    __syncthreads();

    // Build A-fragments: Kf (rows of K) and Kg (rows of K^T), bf16, constant across iters.
    bf16x8_t KfA0[8], KfA1[8], KgA0[8], KgA1[8];
    {
        float2 Af0 = sPA[w * 32 + lr];
        float2 Af1 = sPA[w * 32 + 16 + lr];
        float2 Bg0 = sPB[w * 32 + lr];
        float2 Bg1 = sPB[w * 32 + 16 + lr];
        #pragma unroll
        for (int ks = 0; ks < 8; ++ks) {
            #pragma unroll
            for (int jj = 0; jj < 8; ++jj) {
                int b = ks * 32 + lg * 8 + jj;
                float2 Pb = sPB[b];
                KfA0[ks][jj] = (short)bf_rne(exp2f(-fmaxf(fabsf(Af0.x - Pb.x), fabsf(Af0.y - Pb.y))));
                KfA1[ks][jj] = (short)bf_rne(exp2f(-fmaxf(fabsf(Af1.x - Pb.x), fabsf(Af1.y - Pb.y))));
                float2 Pa = sPA[b];
                KgA0[ks][jj] = (short)bf_rne(exp2f(-fmaxf(fabsf(Pa.x - Bg0.x), fabsf(Pa.y - Bg0.y))));
                KgA1[ks][jj] = (short)bf_rne(exp2f(-fmaxf(fabsf(Pa.x - Bg1.x), fabsf(Pa.y - Bg1.y))));
            }
        }
    }
    // Diagonal weights in D layout: row = w*32 + tt*16 + lg*4 + reg
    float wa0[4], wa1[4], wb0[4], wb1[4];
    #pragma unroll
    for (int g2 = 0; g2 < 4; ++g2) {
        wa0[g2] = swa[w * 32 + lg * 4 + g2];
        wa1[g2] = swa[w * 32 + 16 + lg * 4 + g2];
        wb0[g2] = swb[w * 32 + lg * 4 + g2];
        wb1[g2] = swb[w * 32 + 16 + lg * 4 + g2];
    }

    float cg = 1.f, cf = 1.f, uG2s = 1.f, uF2s = 1.f;
    f32x4_t ugs0 = {1.f, 1.f, 1.f, 1.f}, ugs1 = {1.f, 1.f, 1.f, 1.f};
    f32x4_t ufs0 = {0.f, 0.f, 0.f, 0.f}, ufs1 = {0.f, 0.f, 0.f, 0.f};

    for (int it = 0; it < NITER; ++it) {
        // ---- f phase ----
        if (it) {
            cg = min8v(minG);
            uG2s = rcpf(cf * (sum8v(accTG) + 256.f * uF2s));
        }
        {
            bf16x8_t Bf[8];
            #pragma unroll
            for (int ks = 0; ks < 8; ++ks) Bf[ks] = ((const bf16x8_t*)ug_bf)[ks * 4 + lg];
            f32x4_t a0 = {0.f, 0.f, 0.f, 0.f}, a1 = {0.f, 0.f, 0.f, 0.f};
            #pragma unroll
            for (int ks = 0; ks < 8; ++ks) {
                a0 = __builtin_amdgcn_mfma_f32_16x16x32_bf16(KfA0[ks], Bf[ks], a0, 0, 0, 0);
                a1 = __builtin_amdgcn_mfma_f32_16x16x32_bf16(KfA1[ks], Bf[ks], a1, 0, 0, 0);
            }
            float mv = INFINITY, tv = 0.f;
            #pragma unroll
            for (int g2 = 0; g2 < 4; ++g2) {
                float R0 = cg * (a0[g2] + 256.f * uG2s * wa0[g2]);
                float R1 = cg * (a1[g2] + 256.f * uG2s * wa1[g2]);
                ufs0[g2] = rcpf(R0); ufs1[g2] = rcpf(R1);
                mv = fminf(mv, fminf(R0, R1));
                tv += ugs0[g2] * wb0[g2] + ugs1[g2] * wb1[g2];   // T_f from OLD ug
            }
            if (lr == 0) {
                uint2 v0, v1;
                v0.x = bf_rne(ufs0[0]) | (bf_rne(ufs0[1]) << 16);
                v0.y = bf_rne(ufs0[2]) | (bf_rne(ufs0[3]) << 16);
                v1.x = bf_rne(ufs1[0]) | (bf_rne(ufs1[1]) << 16);
                v1.y = bf_rne(ufs1[2]) | (bf_rne(ufs1[3]) << 16);
                ((uint2*)uf_bf)[w * 8 + lg] = v0;
                ((uint2*)uf_bf)[w * 8 + 4 + lg] = v1;
            }
            wave_red2(tv, mv);
            if (lane == 0) { accTF[w] = tv * 0.0625f; minF[w] = mv; }   // rows duplicated x16
        }
        __syncthreads();
        // ---- g phase ----
        cf = min8v(minF);
        uF2s = rcpf(cg * (sum8v(accTF) + 256.f * uG2s));
        {
            bf16x8_t Bf[8];
            #pragma unroll
            for (int ks = 0; ks < 8; ++ks) Bf[ks] = ((const bf16x8_t*)uf_bf)[ks * 4 + lg];
            f32x4_t a0 = {0.f, 0.f, 0.f, 0.f}, a1 = {0.f, 0.f, 0.f, 0.f};
            #pragma unroll
            for (int ks = 0; ks < 8; ++ks) {
                a0 = __builtin_amdgcn_mfma_f32_16x16x32_bf16(KgA0[ks], Bf[ks], a0, 0, 0, 0);
                a1 = __builtin_amdgcn_mfma_f32_16x16x32_bf16(KgA1[ks], Bf[ks], a1, 0, 0, 0);
            }
            float mv = INFINITY, tv = 0.f;
            #pragma unroll
            for (int g2 = 0; g2 < 4; ++g2) {
                float Q0 = cf * (a0[g2] + 256.f * uF2s * wb0[g2]);
                float Q1 = cf * (a1[g2] + 256.f * uF2s * wb1[g2]);
                ugs0[g2] = rcpf(Q0); ugs1[g2] = rcpf(Q1);
                mv = fminf(mv, fminf(Q0, Q1));
                tv += ufs0[g2] * wa0[g2] + ufs1[g2] * wa1[g2];   // T_g from NEW uf
            }
            if (lr == 0) {
                uint2 v0, v1;
                v0.x = bf_rne(ugs0[0]) | (bf_rne(ugs0[1]) << 16);
                v0.y = bf_rne(ugs0[2]) | (bf_rne(ugs0[3]) << 16);
                v1.x = bf_rne(ugs1[0]) | (bf_rne(ugs1[1]) << 16);
                v1.y = bf_rne(ugs1[2]) | (bf_rne(ugs1[3]) << 16);
                ((uint2*)ug_bf)[w * 8 + lg] = v0;
                ((uint2*)ug_bf)[w * 8 + 4 + lg] = v1;
            }
            wave_red2(tv, mv);
            if (lane == 0) { accTG[w] = tv * 0.0625f; minG[w] = mv; }
        }
        __syncthreads();
    }
    // final G2 (after last g update); overall plan scale = cf
    float uG2f = rcpf(cf * (sum8v(accTG) + 256.f * uF2s));
    // publish exact f32 potentials for the cost epilogue
    if (lr == 0) {
        ((f32x4_t*)uf32)[w * 8 + lg] = ufs0;
        ((f32x4_t*)uf32)[w * 8 + 4 + lg] = ufs1;
        ((f32x4_t*)ug32)[w * 8 + lg] = ugs0;
        ((f32x4_t*)ug32)[w * 8 + 4 + lg] = ugs1;
    }
    __syncthreads();

    // ---- final cost sum(P*C): P_ij = cf * ufs_i * K_ij * ugs_j,  C = Mhat*invsig ----
    float accv = 0.f;
    {
        float2 Apt = sPA[r];
        float ufr = uf32[r];
        #pragma unroll 8
        for (int jj = 0; jj < 128; ++jj) {
            int j = jb + jj;
            float2 B = sPB[j];
            float Mh = fmaxf(fabsf(Apt.x - B.x), fabsf(Apt.y - B.y));
            float kv = __uint_as_float(bf_rne(exp2f(-Mh)) << 16);   // same bf16 K as iterations
            accv += ((ufr * kv) * ug32[j]) * Mh;
        }
        if (q == 0) accv += 256.f * ((ufr * swa[r]) * uG2f) * sda[r];
        else        accv += 256.f * ((uF2s * swb[r]) * ug32[r]) * sdb[r];
    }
    accv *= cf;
    for (int o = 32; o; o >>= 1) accv += __shfl_xor(accv, o);
    if (lane == 0) pm[w] = accv;
    __syncthreads();
    if (t == 0) {
        float tot = 0.f;
        for (int i = 0; i < 8; ++i) tot += pm[i];
        wres[p] = tot * s_invsig;   // back to natural units
    }
}

__global__ void finalize_kernel(const float* __restrict__ wres, float* __restrict__ out) {
    if (threadIdx.x == 0) {
        float s = 0.f;
        for (int i = 0; i < 24; ++i) s += wres[i];
        out[0] = s * 0.25f;        // / B
    }
}

extern "C" void kernel_launch(void* const* d_in, const int* in_sizes, int n_in,
                              void* d_out, int out_size, void* d_ws, size_t ws_size,
                              hipStream_t stream) {
    const float* x = (const float*)d_in[0];   // [4,4,256,256] f32
    const int* y = (const int*)d_in[1];       // [4,1,256,256] i32
    float* ws = (float*)d_ws;
    float* pooled = ws;                        // 24*1024 floats
    float* diag = pooled + 24 * NPIX;          // 24*4*256 floats
    float* wres = diag + 24 * 4 * KTOP;        // 24 floats

    pool_kernel<<<96, 256, 0, stream>>>(x, y, pooled);
    diag_kernel<<<48, 512, 0, stream>>>(pooled, diag);
    sink_kernel<<<24, 512, 0, stream>>>(diag, wres);
    finalize_kernel<<<1, 64, 0, stream>>>(wres, (float*)d_out);
}

// Round 10
// 834.889 us; speedup vs baseline: 3.6617x; 1.0695x over previous
//
#include <hip/hip_runtime.h>
#include <cmath>

#define NPIX 1024
#define NEDGE 1984
#define NPAD 2048
#define KTOP 256
#define NITER 150

typedef __attribute__((ext_vector_type(8))) short bf16x8_t;   // 8 bf16 = 4 VGPRs
typedef __attribute__((ext_vector_type(4))) float f32x4_t;

__device__ __forceinline__ unsigned bf_rne(float x) {
    unsigned b = __float_as_uint(x);
    return (b + 0x7fffu + ((b >> 16) & 1u)) >> 16;
}
__device__ __forceinline__ float rcpf(float x) { return __builtin_amdgcn_rcpf(x); }

template<int CTRL>
__device__ __forceinline__ float dppf(float x) {
    return __int_as_float(__builtin_amdgcn_update_dpp(
        __float_as_int(x), __float_as_int(x), CTRL, 0xF, 0xF, false));
}
// fused wave64 sum(s) + min(m)
__device__ __forceinline__ void wave_red2(float& s, float& m) {
    s += dppf<0x121>(s); m = fminf(m, dppf<0x121>(m));
    s += dppf<0x122>(s); m = fminf(m, dppf<0x122>(m));
    s += dppf<0x124>(s); m = fminf(m, dppf<0x124>(m));
    s += dppf<0x128>(s); m = fminf(m, dppf<0x128>(m));
    s += __int_as_float(__builtin_amdgcn_ds_swizzle(__float_as_int(s), 0x401F));
    m = fminf(m, __int_as_float(__builtin_amdgcn_ds_swizzle(__float_as_int(m), 0x401F)));
    float s0 = __int_as_float(__builtin_amdgcn_readlane(__float_as_int(s), 0));
    float s1 = __int_as_float(__builtin_amdgcn_readlane(__float_as_int(s), 32));
    s = s0 + s1;
    float m0 = __int_as_float(__builtin_amdgcn_readlane(__float_as_int(m), 0));
    float m1 = __int_as_float(__builtin_amdgcn_readlane(__float_as_int(m), 32));
    m = fminf(m0, m1);
}

__device__ __forceinline__ float min8v(const float* a) {
    float4 x0 = *(const float4*)a, x1 = *(const float4*)(a + 4);
    return fminf(fminf(fminf(x0.x, x0.y), fminf(x0.z, x0.w)),
                 fminf(fminf(x1.x, x1.y), fminf(x1.z, x1.w)));
}
__device__ __forceinline__ float sum8v(const float* a) {
    float4 x0 = *(const float4*)a, x1 = *(const float4*)(a + 4);
    return ((x0.x + x0.y) + (x0.z + x0.w)) + ((x1.x + x1.y) + (x1.z + x1.w));
}

// ---------------- pooling: softmax(x) and one-hot(y), adaptive-avg-pool 8x8 ----------------
__global__ __launch_bounds__(256) void pool_kernel(const float* __restrict__ x,
                                                   const int* __restrict__ y,
                                                   float* __restrict__ pooled) {
    int blk = blockIdx.x;              // 0..95
    int img = blk >> 2;                // 0..23
    int cell = ((blk & 3) << 8) | threadIdx.x;
    int gi = cell >> 5, gj = cell & 31;
    const float L2E = 1.4426950408889634f;
    float acc = 0.f;
    if (img < 12) {
        int b = img / 3, c = img % 3 + 1;
        const float* xb = x + (size_t)b * 262144 + (size_t)gi * 2048 + gj * 8;
        for (int pi = 0; pi < 8; ++pi) {
            const float* xr = xb + pi * 256;
            #pragma unroll
            for (int ph = 0; ph < 2; ++ph) {
                float4 c0 = *(const float4*)(xr + ph * 4);
                float4 c1 = *(const float4*)(xr + ph * 4 + 65536);
                float4 c2 = *(const float4*)(xr + ph * 4 + 131072);
                float4 c3 = *(const float4*)(xr + ph * 4 + 196608);
                const float* f0 = (const float*)&c0;
                const float* f1 = (const float*)&c1;
                const float* f2 = (const float*)&c2;
                const float* f3 = (const float*)&c3;
                #pragma unroll
                for (int k = 0; k < 4; ++k) {
                    float e0 = exp2f(f0[k] * L2E), e1 = exp2f(f1[k] * L2E);
                    float e2 = exp2f(f2[k] * L2E), e3 = exp2f(f3[k] * L2E);
                    float ec = (c == 1) ? e1 : (c == 2) ? e2 : e3;
                    acc += ec / (e0 + e1 + e2 + e3);
                }
            }
        }
    } else {
        int tt = img - 12;
        int b = tt / 3, c = tt % 3 + 1;
        const int* yb = y + (size_t)b * 65536 + (size_t)gi * 2048 + gj * 8;
        int cnt = 0;
        for (int pi = 0; pi < 8; ++pi) {
            const int* yr = yb + pi * 256;
            #pragma unroll
            for (int pj = 0; pj < 8; ++pj) cnt += (yr[pj] == c) ? 1 : 0;
        }
        acc = (float)cnt;
    }
    pooled[img * NPIX + cell] = acc * (1.f / 64.f);
}

// ---------------- bitonic sort of 2048 u64 keys, register phases for j<=2 ----------------
__device__ __forceinline__ void cex(unsigned long long& a, unsigned long long& b, bool up) {
    if ((a > b) == up) { unsigned long long t = a; a = b; b = t; }
}
__device__ void bitonic2048_reg(unsigned long long* keys, int tid, bool asc) {
    int i0 = tid << 2;   // thread owns elements i0..i0+3
    for (int k = 2; k <= NPAD; k <<= 1) {
        for (int j = k >> 1; j >= 4; j >>= 1) {
            #pragma unroll
            for (int rep = 0; rep < 4; ++rep) {
                int ii = tid + rep * 512;
                int l = ii ^ j;
                if (l > ii) {
                    unsigned long long a = keys[ii], b = keys[l];
                    bool up = (((ii & k) == 0) == asc);
                    if ((a > b) == up) { keys[ii] = b; keys[l] = a; }
                }
            }
            __syncthreads();
        }
        // j = 2 (k>=4) and j = 1 in registers; quad direction uniform for k>=4
        unsigned long long e0 = keys[i0], e1 = keys[i0 + 1], e2 = keys[i0 + 2], e3 = keys[i0 + 3];
        bool upq = (((i0 & k) == 0) == asc);
        if (k >= 4) {
            cex(e0, e2, upq); cex(e1, e3, upq);
            cex(e0, e1, upq); cex(e2, e3, upq);
        } else {   // k == 2: j=1 only, direction alternates within the quad
            cex(e0, e1, asc);
            cex(e2, e3, !asc);
        }
        keys[i0] = e0; keys[i0 + 1] = e1; keys[i0 + 2] = e2; keys[i0 + 3] = e3;
        __syncthreads();
    }
}

// ---------------- persistence diagrams (H0 sublevel / H1 via superlevel duality) ------------
// UF machinery (precheck + serial body + compression) byte-identical to round-9 (absmax 0.0).
// New: register-phase bitonic for sort1; top-k via radix-select (downstream is order-invariant).
__global__ __launch_bounds__(512) void diag_kernel(const float* __restrict__ pooled,
                                                   float* __restrict__ diag) {
    __shared__ float v_[NPIX];
    __shared__ unsigned long long keys[NPAD];
    __shared__ unsigned long long PB[NPIX];      // low 32: parent, high 32: birth (f32 bits)
    __shared__ unsigned euv[NPAD];               // u | v<<16 per edge index
    __shared__ unsigned long long pbd[NEDGE];    // low: pb bits, high: pd bits
    __shared__ unsigned long long snap[132];     // wbits<<22 | (ra+1)<<11 | (rb+1)
    __shared__ unsigned histAll[2048];           // 8 wave-copies x 256 bins
    __shared__ float redA[8], redB[8];
    __shared__ float svmin, svmax;
    __shared__ unsigned long long s_prefix, s_T;
    __shared__ unsigned s_need, s_done, s_outcnt;

    int run = blockIdx.x;      // 0..47
    int img = run >> 1, filt = run & 1;
    int tid = threadIdx.x;
    int wv = tid >> 6;
    const float* m = pooled + img * NPIX;

    for (int i = tid; i < NPIX; i += 512) {
        float val = m[i];
        v_[i] = filt ? -val : val;
    }
    __syncthreads();
    // min/max (for the essential H0 class)
    float mn = INFINITY, mx = -INFINITY;
    for (int i = tid; i < NPIX; i += 512) { float vv = v_[i]; mn = fminf(mn, vv); mx = fmaxf(mx, vv); }
    for (int o = 32; o; o >>= 1) { mn = fminf(mn, __shfl_xor(mn, o)); mx = fmaxf(mx, __shfl_xor(mx, o)); }
    if ((tid & 63) == 0) { redA[wv] = mn; redB[wv] = mx; }
    __syncthreads();
    if (tid == 0) {
        float a = INFINITY, b = -INFINITY;
        for (int i2 = 0; i2 < 8; ++i2) { a = fminf(a, redA[i2]); b = fmaxf(b, redB[i2]); }
        svmin = a; svmax = b;
    }
    // edge keys: stable sort by (weight, edge index) — replicates jnp.argsort (stable)
    for (int e = tid; e < NPAD; e += 512) {
        unsigned long long key;
        unsigned uv = 0;
        if (e < NEDGE) {
            int u, vv;
            if (e < 992) { int r = e / 31; u = e + r; vv = u + 1; }   // horizontal
            else         { u = e - 992;   vv = u + 32; }              // vertical
            float w = fmaxf(v_[u], v_[vv]);
            unsigned int bw = __float_as_uint(w);
            bw = (bw & 0x80000000u) ? ~bw : (bw | 0x80000000u);       // orderable float bits
            key = ((unsigned long long)bw << 11) | (unsigned int)e;
            uv = (unsigned)u | ((unsigned)vv << 16);
        } else key = ~0ULL;
        keys[e] = key;
        euv[e] = uv;
    }
    for (int i = tid; i < NPIX; i += 512)
        PB[i] = ((unsigned long long)__float_as_uint(v_[i]) << 32) | (unsigned)i;
    __syncthreads();
    bitonic2048_reg(keys, tid, true);   // ascending; ends with a barrier

    // Kruskal/union-find with elder rule, batch-snapshot structure (r9-exact).
    unsigned* PBlo = (unsigned*)PB;
    for (int base = 0; base < NEDGE; base += 128) {
        // parallel pointer-jumping compression (roots/births untouched)
        if (base) {
            for (int rd = 0; rd < 4; ++rd) {
                for (int i = tid; i < NPIX; i += 512) {
                    unsigned pp = PBlo[2 * i];
                    unsigned gg = PBlo[2 * pp];
                    PBlo[2 * i] = gg;           // benign race: result is always an ancestor
                }
            }
        }
        __syncthreads();
        int bend = (base + 128 < NEDGE) ? base + 128 : NEDGE;
        int bcnt = bend - base;
        // parallel precheck: resolve snapshot roots; emit trivial pairs in parallel
        if (tid < bcnt) {
            int kk = base + tid;
            unsigned long long key = keys[kk];
            int e = (int)(key & 2047ULL);
            unsigned bw = (unsigned)(key >> 11);
            unsigned uv = euv[e];
            int ra = (int)(uv & 0xffffu), rb = (int)(uv >> 16);
            unsigned pp = PBlo[2 * ra];
            while (pp != (unsigned)ra) { ra = (int)pp; pp = PBlo[2 * ra]; }
            unsigned p2 = PBlo[2 * rb];
            while (p2 != (unsigned)rb) { rb = (int)p2; p2 = PBlo[2 * rb]; }
            if (ra == rb) {
                unsigned wb = (bw & 0x80000000u) ? (bw & 0x7fffffffu) : ~bw;
                pbd[kk] = (unsigned long long)wb | ((unsigned long long)wb << 32);
                snap[tid] = (unsigned long long)bw << 22;        // trivial marker
            } else {
                snap[tid] = ((unsigned long long)bw << 22)
                          | ((unsigned)(ra + 1) << 11) | (unsigned)(rb + 1);
            }
        }
        __syncthreads();
        // serial elder-rule scan over merge candidates (snap[] is read-only here)
        if (tid == 0) {
            unsigned long long sc = snap[0];
            for (int i = 0; i < bcnt; ++i) {
                unsigned long long sn = snap[i + 1];             // read-only prefetch, no hazard
                if ((unsigned)(sc & 0x3FFFFFu)) {
                    unsigned ob = (unsigned)(sc >> 22);
                    float w = __uint_as_float((ob & 0x80000000u) ? (ob & 0x7fffffffu) : ~ob);
                    int a = (int)((sc >> 11) & 0x7FFu) - 1;
                    int b = (int)(sc & 0x7FFu) - 1;
                    unsigned long long qa = PB[a], qb = PB[b];
                    int pa = (int)(unsigned)qa, pb = (int)(unsigned)qb;
                    while (pa != a || pb != b) {
                        if (pa != a) {
                            unsigned long long na = PB[pa];
                            int ga = (int)(unsigned)na;
                            PBlo[2 * a] = (unsigned)ga;     // path-halving compression
                            a = pa; pa = ga; qa = na;
                        }
                        if (pb != b) {
                            unsigned long long nb = PB[pb];
                            int gb = (int)(unsigned)nb;
                            PBlo[2 * b] = (unsigned)gb;
                            b = pb; pb = gb; qb = nb;
                        }
                    }
                    float pb_, pd_;
                    if (a != b) {
                        float bu = __uint_as_float((unsigned)(qa >> 32));
                        float bv = __uint_as_float((unsigned)(qb >> 32));
                        bool uo = (bu <= bv);                 // tie -> root on u's side
                        int older = uo ? a : b;
                        int younger = uo ? b : a;
                        pb_ = fmaxf(bu, bv); pd_ = w;         // younger component dies
                        PBlo[2 * younger] = (unsigned)older;  // birth[older] already the min
                    } else { pb_ = w; pd_ = w; }              // became trivial within batch
                    pbd[base + i] = (unsigned long long)__float_as_uint(pb_)
                                  | ((unsigned long long)__float_as_uint(pd_) << 32);
                }
                sc = sn;
            }
        }
        __syncthreads();
    }

    // ---- top-k selection by (persistence, lower index) via radix-select ----
    // Downstream Sinkhorn is index-order-invariant, so only the selected SET matters.
    int count = filt ? NEDGE : (NEDGE + 1);
    for (int k = tid; k < NPAD; k += 512) {
        unsigned long long key = 0ULL;
        if (k < count) {
            float pers;
            if (k < NEDGE) {
                unsigned long long pd2 = pbd[k];
                pers = __uint_as_float((unsigned)(pd2 >> 32)) - __uint_as_float((unsigned)pd2);
            } else pers = svmax - svmin;
            key = ((unsigned long long)__float_as_uint(pers) << 32) | (unsigned int)(2047 - k);
        }
        keys[k] = key;
    }
    if (tid == 0) { s_prefix = 0ULL; s_T = 0ULL; s_need = KTOP; s_done = 0; s_outcnt = 0; }
    __syncthreads();

    for (int rnd = 0; rnd < 8; ++rnd) {
        for (int i = tid; i < 2048; i += 512) histAll[i] = 0;
        __syncthreads();
        if (!s_done) {
            int shift = 56 - 8 * rnd;
            unsigned long long pref = s_prefix;
            for (int k = tid; k < NPAD; k += 512) {
                unsigned long long key = keys[k];
                bool act = (rnd == 0) || ((key >> (shift + 8)) == (pref >> (shift + 8)));
                if (act) atomicAdd(&histAll[wv * 256 + (unsigned)((key >> shift) & 255ULL)], 1u);
            }
        }
        __syncthreads();
        if (wv == 0) {
            if (!s_done) {
                int l64 = tid;            // lane id within wave 0
                int shift = 56 - 8 * rnd;
                unsigned c0 = 0, c1 = 0, c2 = 0, c3 = 0;
                #pragma unroll
                for (int cp = 0; cp < 8; ++cp) {
                    const unsigned* h = histAll + cp * 256 + 4 * l64;
                    c0 += h[0]; c1 += h[1]; c2 += h[2]; c3 += h[3];
                }
                unsigned s3 = c3, s2 = c2 + s3, s1 = c1 + s2, s0 = c0 + s1;
                // wave-wide suffix sum of lane totals (s0)
                unsigned acc2 = s0;
                #pragma unroll
                for (int o = 1; o < 64; o <<= 1) {
                    unsigned v2 = __shfl_down(acc2, o);
                    if (l64 + o < 64) acc2 += v2;
                }
                unsigned above = acc2 - s0;                 // sum over lanes > l64
                unsigned Sn[5] = {above + s0, above + s1, above + s2, above + s3, above};
                unsigned need = s_need;
                #pragma unroll
                for (int q2 = 0; q2 < 4; ++q2) {
                    if (Sn[q2] >= need && Sn[q2 + 1] < need) {     // exactly one lane/bin fires
                        unsigned bstar = 4 * l64 + q2;
                        if (Sn[q2] == need) {
                            s_T = s_prefix | ((unsigned long long)bstar << shift);
                            s_done = 1;
                        } else {
                            s_prefix = s_prefix | ((unsigned long long)bstar << shift);
                            s_need = need - Sn[q2 + 1];
                        }
                    }
                }
            }
        }
        __syncthreads();
    }

    // compact selected (key >= T) and write output; order within diag is irrelevant downstream
    {
        unsigned long long T = s_T;
        for (int k = tid; k < NPAD; k += 512) {
            unsigned long long key = keys[k];
            if (key >= T && key != 0ULL) {
                int pos = (int)atomicAdd(&s_outcnt, 1u);
                int kk = 2047 - (int)(key & 0xffffffffULL);
                float b_, d_;
                if (kk < NEDGE) {
                    unsigned long long pd2 = pbd[kk];
                    b_ = __uint_as_float((unsigned)pd2);
                    d_ = __uint_as_float((unsigned)(pd2 >> 32));
                } else { b_ = svmin; d_ = svmax; }
                float ob, od;
                if (!filt) { ob = b_;  od = d_;  }       // H0 pairs
                else       { ob = -d_; od = -b_; }       // H1 = negated superlevel H0
                diag[((img * 4) + filt * 2 + 0) * KTOP + pos] = ob;
                diag[((img * 4) + filt * 2 + 1) * KTOP + pos] = od;
            }
        }
    }
}

// ---------------- entropic Sinkhorn: MFMA matvec + fold normalization ----------------------
// Byte-identical to the round-8/9 version (verified absmax 0.0).
__global__ __launch_bounds__(512) void sink_kernel(const float* __restrict__ diag,
                                                   float* __restrict__ wres) {
    __shared__ float2 sPA[KTOP], sPB[KTOP];
    __shared__ float sda[KTOP], sdb[KTOP];
    __shared__ float swa[KTOP], swb[KTOP];
    __shared__ __align__(16) unsigned ug_bf[128];    // 256 bf16
    __shared__ __align__(16) unsigned uf_bf[128];
    __shared__ __align__(16) float uf32[KTOP], ug32[KTOP];
    __shared__ __align__(16) float minF[8], accTF[8], minG[8], accTG[8];
    __shared__ __align__(16) float pm[8];
    __shared__ float s_sig, s_invsig;

    int p = blockIdx.x;            // 0..23
    int img = p % 12, dim = p / 12;
    int t = threadIdx.x;
    int lane = t & 63, w = t >> 6;         // wave 0..7
    int lr = lane & 15, lg = lane >> 4;    // col-lane, k-group
    int r = t >> 1, q = t & 1, jb = q * 128;   // mapping for maxC / final cost

    const float* ab  = diag + ((img * 4) + dim * 2) * KTOP;
    const float* ad  = ab + KTOP;
    const float* bbp = diag + (((12 + img) * 4) + dim * 2) * KTOP;
    const float* bdp = bbp + KTOP;

    if (t < KTOP) {
        float a0 = ab[t], a1 = ad[t];
        float b0 = bbp[t], b1 = bdp[t];
        sPA[t] = make_float2(a0, a1);
        sPB[t] = make_float2(b0, b1);
        sda[t] = 0.5f * (a1 - a0);
        sdb[t] = 0.5f * (b1 - b0);
    }
    if (t < 128) ug_bf[t] = 0x3F803F80u;   // u = 1.0 (bf16 pair)
    __syncthreads();

    // maxC (unscaled)
    {
        float2 A = sPA[r];
        float lmax = 0.f;
        for (int jj = 0; jj < 128; ++jj) {
            float2 B = sPB[jb + jj];
            lmax = fmaxf(lmax, fmaxf(fabsf(A.x - B.x), fabsf(A.y - B.y)));
        }
        if (t < KTOP) lmax = fmaxf(lmax, fmaxf(sda[t], sdb[t]));
        for (int o = 32; o; o >>= 1) lmax = fmaxf(lmax, __shfl_xor(lmax, o));
        if (lane == 0) pm[w] = lmax;
    }
    __syncthreads();
    if (t == 0) {
        float mc = 0.f;
        for (int i = 0; i < 8; ++i) mc = fmaxf(mc, pm[i]);
        float eps = 0.02f * fmaxf(mc, 1e-6f);
        s_sig = 1.4426950408889634f / eps;        // log2(e)/eps
        s_invsig = eps * 0.6931471805599453f;     // eps*ln2
    }
    __syncthreads();
    {
        float sig = s_sig;
        if (t < KTOP) {
            float2 a2 = sPA[t], b2 = sPB[t];
            sPA[t] = make_float2(a2.x * sig, a2.y * sig);
            sPB[t] = make_float2(b2.x * sig, b2.y * sig);
            float da2 = sda[t] * sig, db2 = sdb[t] * sig;
            sda[t] = da2; sdb[t] = db2;
            swa[t] = exp2f(-da2); swb[t] = exp2f(-db2);
        }
    }
    __syncthreads();

    // Build A-fragments: Kf (rows of K) and Kg (rows of K^T), bf16, constant across iters.
    bf16x8_t KfA0[8], KfA1[8], KgA0[8], KgA1[8];
    {
        float2 Af0 = sPA[w * 32 + lr];
        float2 Af1 = sPA[w * 32 + 16 + lr];
        float2 Bg0 = sPB[w * 32 + lr];
        float2 Bg1 = sPB[w * 32 + 16 + lr];
        #pragma unroll
        for (int ks = 0; ks < 8; ++ks) {
            #pragma unroll
            for (int jj = 0; jj < 8; ++jj) {
                int b = ks * 32 + lg * 8 + jj;
                float2 Pb = sPB[b];
                KfA0[ks][jj] = (short)bf_rne(exp2f(-fmaxf(fabsf(Af0.x - Pb.x), fabsf(Af0.y - Pb.y))));
                KfA1[ks][jj] = (short)bf_rne(exp2f(-fmaxf(fabsf(Af1.x - Pb.x), fabsf(Af1.y - Pb.y))));
                float2 Pa = sPA[b];
                KgA0[ks][jj] = (short)bf_rne(exp2f(-fmaxf(fabsf(Pa.x - Bg0.x), fabsf(Pa.y - Bg0.y))));
                KgA1[ks][jj] = (short)bf_rne(exp2f(-fmaxf(fabsf(Pa.x - Bg1.x), fabsf(Pa.y - Bg1.y))));
            }
        }
    }
    // Diagonal weights in D layout: row = w*32 + tt*16 + lg*4 + reg
    float wa0[4], wa1[4], wb0[4], wb1[4];
    #pragma unroll
    for (int g2 = 0; g2 < 4; ++g2) {
        wa0[g2] = swa[w * 32 + lg * 4 + g2];
        wa1[g2] = swa[w * 32 + 16 + lg * 4 + g2];
        wb0[g2] = swb[w * 32 + lg * 4 + g2];
        wb1[g2] = swb[w * 32 + 16 + lg * 4 + g2];
    }

    float cg = 1.f, cf = 1.f, uG2s = 1.f, uF2s = 1.f;
    f32x4_t ugs0 = {1.f, 1.f, 1.f, 1.f}, ugs1 = {1.f, 1.f, 1.f, 1.f};
    f32x4_t ufs0 = {0.f, 0.f, 0.f, 0.f}, ufs1 = {0.f, 0.f, 0.f, 0.f};

    for (int it = 0; it < NITER; ++it) {
        // ---- f phase ----
        if (it) {
            cg = min8v(minG);
            uG2s = rcpf(cf * (sum8v(accTG) + 256.f * uF2s));
        }
        {
            bf16x8_t Bf[8];
            #pragma unroll
            for (int ks = 0; ks < 8; ++ks) Bf[ks] = ((const bf16x8_t*)ug_bf)[ks * 4 + lg];
            f32x4_t a0 = {0.f, 0.f, 0.f, 0.f}, a1 = {0.f, 0.f, 0.f, 0.f};
            #pragma unroll
            for (int ks = 0; ks < 8; ++ks) {
                a0 = __builtin_amdgcn_mfma_f32_16x16x32_bf16(KfA0[ks], Bf[ks], a0, 0, 0, 0);
                a1 = __builtin_amdgcn_mfma_f32_16x16x32_bf16(KfA1[ks], Bf[ks], a1, 0, 0, 0);
            }
            float mv = INFINITY, tv = 0.f;
            #pragma unroll
            for (int g2 = 0; g2 < 4; ++g2) {
                float R0 = cg * (a0[g2] + 256.f * uG2s * wa0[g2]);
                float R1 = cg * (a1[g2] + 256.f * uG2s * wa1[g2]);
                ufs0[g2] = rcpf(R0); ufs1[g2] = rcpf(R1);
                mv = fminf(mv, fminf(R0, R1));
                tv += ugs0[g2] * wb0[g2] + ugs1[g2] * wb1[g2];   // T_f from OLD ug
            }
            if (lr == 0) {
                uint2 v0, v1;
                v0.x = bf_rne(ufs0[0]) | (bf_rne(ufs0[1]) << 16);
                v0.y = bf_rne(ufs0[2]) | (bf_rne(ufs0[3]) << 16);
                v1.x = bf_rne(ufs1[0]) | (bf_rne(ufs1[1]) << 16);
                v1.y = bf_rne(ufs1[2]) | (bf_rne(ufs1[3]) << 16);
                ((uint2*)uf_bf)[w * 8 + lg] = v0;
                ((uint2*)uf_bf)[w * 8 + 4 + lg] = v1;
            }
            wave_red2(tv, mv);
            if (lane == 0) { accTF[w] = tv * 0.0625f; minF[w] = mv; }   // rows duplicated x16
        }
        __syncthreads();
        // ---- g phase ----
        cf = min8v(minF);
        uF2s = rcpf(cg * (sum8v(accTF) + 256.f * uG2s));
        {
            bf16x8_t Bf[8];
            #pragma unroll
            for (int ks = 0; ks < 8; ++ks) Bf[ks] = ((const bf16x8_t*)uf_bf)[ks * 4 + lg];
            f32x4_t a0 = {0.f, 0.f, 0.f, 0.f}, a1 = {0.f, 0.f, 0.f, 0.f};
            #pragma unroll
            for (int ks = 0; ks < 8; ++ks) {
                a0 = __builtin_amdgcn_mfma_f32_16x16x32_bf16(KgA0[ks], Bf[ks], a0, 0, 0, 0);
                a1 = __builtin_amdgcn_mfma_f32_16x16x32_bf16(KgA1[ks], Bf[ks], a1, 0, 0, 0);
            }
            float mv = INFINITY, tv = 0.f;
            #pragma unroll
            for (int g2 = 0; g2 < 4; ++g2) {
                float Q0 = cf * (a0[g2] + 256.f * uF2s * wb0[g2]);
                float Q1 = cf * (a1[g2] + 256.f * uF2s * wb1[g2]);
                ugs0[g2] = rcpf(Q0); ugs1[g2] = rcpf(Q1);
                mv = fminf(mv, fminf(Q0, Q1));
                tv += ufs0[g2] * wa0[g2] + ufs1[g2] * wa1[g2];   // T_g from NEW uf
            }
            if (lr == 0) {
                uint2 v0, v1;
                v0.x = bf_rne(ugs0[0]) | (bf_rne(ugs0[1]) << 16);
                v0.y = bf_rne(ugs0[2]) | (bf_rne(ugs0[3]) << 16);
                v1.x = bf_rne(ugs1[0]) | (bf_rne(ugs1[1]) << 16);
                v1.y = bf_rne(ugs1[2]) | (bf_rne(ugs1[3]) << 16);
                ((uint2*)ug_bf)[w * 8 + lg] = v0;
                ((uint2*)ug_bf)[w * 8 + 4 + lg] = v1;
            }
            wave_red2(tv, mv);
            if (lane == 0) { accTG[w] = tv * 0.0625f; minG[w] = mv; }
        }
        __syncthreads();
    }
    // final G2 (after last g update); overall plan scale = cf
    float uG2f = rcpf(cf * (sum8v(accTG) + 256.f * uF2s));
    // publish exact f32 potentials for the cost epilogue
    if (lr == 0) {
        ((f32x4_t*)uf32)[w * 8 + lg] = ufs0;
        ((f32x4_t*)uf32)[w * 8 + 4 + lg] = ufs1;
        ((f32x4_t*)ug32)[w * 8 + lg] = ugs0;
        ((f32x4_t*)ug32)[w * 8 + 4 + lg] = ugs1;
    }
    __syncthreads();

    // ---- final cost sum(P*C): P_ij = cf * ufs_i * K_ij * ugs_j,  C = Mhat*invsig ----
    float accv = 0.f;
    {
        float2 Apt = sPA[r];
        float ufr = uf32[r];
        #pragma unroll 8
        for (int jj = 0; jj < 128; ++jj) {
            int j = jb + jj;
            float2 B = sPB[j];
            float Mh = fmaxf(fabsf(Apt.x - B.x), fabsf(Apt.y - B.y));
            float kv = __uint_as_float(bf_rne(exp2f(-Mh)) << 16);   // same bf16 K as iterations
            accv += ((ufr * kv) * ug32[j]) * Mh;
        }
        if (q == 0) accv += 256.f * ((ufr * swa[r]) * uG2f) * sda[r];
        else        accv += 256.f * ((uF2s * swb[r]) * ug32[r]) * sdb[r];
    }
    accv *= cf;
    for (int o = 32; o; o >>= 1) accv += __shfl_xor(accv, o);
    if (lane == 0) pm[w] = accv;
    __syncthreads();
    if (t == 0) {
        float tot = 0.f;
        for (int i = 0; i < 8; ++i) tot += pm[i];
        wres[p] = tot * s_invsig;   // back to natural units
    }
}

__global__ void finalize_kernel(const float* __restrict__ wres, float* __restrict__ out) {
    if (threadIdx.x == 0) {
        float s = 0.f;
        for (int i = 0; i < 24; ++i) s += wres[i];
        out[0] = s * 0.25f;        // / B
    }
}

extern "C" void kernel_launch(void* const* d_in, const int* in_sizes, int n_in,
                              void* d_out, int out_size, void* d_ws, size_t ws_size,
                              hipStream_t stream) {
    const float* x = (const float*)d_in[0];   // [4,4,256,256] f32
    const int* y = (const int*)d_in[1];       // [4,1,256,256] i32
    float* ws = (float*)d_ws;
    float* pooled = ws;                        // 24*1024 floats
    float* diag = pooled + 24 * NPIX;          // 24*4*256 floats
    float* wres = diag + 24 * 4 * KTOP;        // 24 floats

    pool_kernel<<<96, 256, 0, stream>>>(x, y, pooled);
    diag_kernel<<<48, 512, 0, stream>>>(pooled, diag);
    sink_kernel<<<24, 512, 0, stream>>>(diag, wres);
    finalize_kernel<<<1, 64, 0, stream>>>(wres, (float*)d_out);
}

// Round 11
// 815.726 us; speedup vs baseline: 3.7477x; 1.0235x over previous
//
#include <hip/hip_runtime.h>
#include <cmath>

#define NPIX 1024
#define NEDGE 1984
#define NPAD 2048
#define KTOP 256
#define NITER 150

typedef __attribute__((ext_vector_type(8))) short bf16x8_t;   // 8 bf16 = 4 VGPRs
typedef __attribute__((ext_vector_type(4))) float f32x4_t;

__device__ __forceinline__ unsigned bf_rne(float x) {
    unsigned b = __float_as_uint(x);
    return (b + 0x7fffu + ((b >> 16) & 1u)) >> 16;
}
__device__ __forceinline__ float rcpf(float x) { return __builtin_amdgcn_rcpf(x); }

template<int CTRL>
__device__ __forceinline__ float dppf(float x) {
    return __int_as_float(__builtin_amdgcn_update_dpp(
        __float_as_int(x), __float_as_int(x), CTRL, 0xF, 0xF, false));
}
// fused wave64 sum(s) + min(m)
__device__ __forceinline__ void wave_red2(float& s, float& m) {
    s += dppf<0x121>(s); m = fminf(m, dppf<0x121>(m));
    s += dppf<0x122>(s); m = fminf(m, dppf<0x122>(m));
    s += dppf<0x124>(s); m = fminf(m, dppf<0x124>(m));
    s += dppf<0x128>(s); m = fminf(m, dppf<0x128>(m));
    s += __int_as_float(__builtin_amdgcn_ds_swizzle(__float_as_int(s), 0x401F));
    m = fminf(m, __int_as_float(__builtin_amdgcn_ds_swizzle(__float_as_int(m), 0x401F)));
    float s0 = __int_as_float(__builtin_amdgcn_readlane(__float_as_int(s), 0));
    float s1 = __int_as_float(__builtin_amdgcn_readlane(__float_as_int(s), 32));
    s = s0 + s1;
    float m0 = __int_as_float(__builtin_amdgcn_readlane(__float_as_int(m), 0));
    float m1 = __int_as_float(__builtin_amdgcn_readlane(__float_as_int(m), 32));
    m = fminf(m0, m1);
}

__device__ __forceinline__ float min8v(const float* a) {
    float4 x0 = *(const float4*)a, x1 = *(const float4*)(a + 4);
    return fminf(fminf(fminf(x0.x, x0.y), fminf(x0.z, x0.w)),
                 fminf(fminf(x1.x, x1.y), fminf(x1.z, x1.w)));
}
__device__ __forceinline__ float sum8v(const float* a) {
    float4 x0 = *(const float4*)a, x1 = *(const float4*)(a + 4);
    return ((x0.x + x0.y) + (x0.z + x0.w)) + ((x1.x + x1.y) + (x1.z + x1.w));
}

// ---------------- pooling: softmax(x) and one-hot(y), adaptive-avg-pool 8x8 ----------------
__global__ __launch_bounds__(256) void pool_kernel(const float* __restrict__ x,
                                                   const int* __restrict__ y,
                                                   float* __restrict__ pooled) {
    int blk = blockIdx.x;              // 0..95
    int img = blk >> 2;                // 0..23
    int cell = ((blk & 3) << 8) | threadIdx.x;
    int gi = cell >> 5, gj = cell & 31;
    const float L2E = 1.4426950408889634f;
    float acc = 0.f;
    if (img < 12) {
        int b = img / 3, c = img % 3 + 1;
        const float* xb = x + (size_t)b * 262144 + (size_t)gi * 2048 + gj * 8;
        for (int pi = 0; pi < 8; ++pi) {
            const float* xr = xb + pi * 256;
            #pragma unroll
            for (int ph = 0; ph < 2; ++ph) {
                float4 c0 = *(const float4*)(xr + ph * 4);
                float4 c1 = *(const float4*)(xr + ph * 4 + 65536);
                float4 c2 = *(const float4*)(xr + ph * 4 + 131072);
                float4 c3 = *(const float4*)(xr + ph * 4 + 196608);
                const float* f0 = (const float*)&c0;
                const float* f1 = (const float*)&c1;
                const float* f2 = (const float*)&c2;
                const float* f3 = (const float*)&c3;
                #pragma unroll
                for (int k = 0; k < 4; ++k) {
                    float e0 = exp2f(f0[k] * L2E), e1 = exp2f(f1[k] * L2E);
                    float e2 = exp2f(f2[k] * L2E), e3 = exp2f(f3[k] * L2E);
                    float ec = (c == 1) ? e1 : (c == 2) ? e2 : e3;
                    acc += ec / (e0 + e1 + e2 + e3);
                }
            }
        }
    } else {
        int tt = img - 12;
        int b = tt / 3, c = tt % 3 + 1;
        const int* yb = y + (size_t)b * 65536 + (size_t)gi * 2048 + gj * 8;
        int cnt = 0;
        for (int pi = 0; pi < 8; ++pi) {
            const int* yr = yb + pi * 256;
            #pragma unroll
            for (int pj = 0; pj < 8; ++pj) cnt += (yr[pj] == c) ? 1 : 0;
        }
        acc = (float)cnt;
    }
    pooled[img * NPIX + cell] = acc * (1.f / 64.f);
}

// ---------------- bitonic sort of 2048 u64 keys, register phases for j<=2 ----------------
__device__ __forceinline__ void cex(unsigned long long& a, unsigned long long& b, bool up) {
    if ((a > b) == up) { unsigned long long t = a; a = b; b = t; }
}
__device__ void bitonic2048_reg(unsigned long long* keys, int tid, bool asc) {
    int i0 = tid << 2;   // thread owns elements i0..i0+3
    for (int k = 2; k <= NPAD; k <<= 1) {
        for (int j = k >> 1; j >= 4; j >>= 1) {
            #pragma unroll
            for (int rep = 0; rep < 4; ++rep) {
                int ii = tid + rep * 512;
                int l = ii ^ j;
                if (l > ii) {
                    unsigned long long a = keys[ii], b = keys[l];
                    bool up = (((ii & k) == 0) == asc);
                    if ((a > b) == up) { keys[ii] = b; keys[l] = a; }
                }
            }
            __syncthreads();
        }
        // j = 2 (k>=4) and j = 1 in registers; quad direction uniform for k>=4
        unsigned long long e0 = keys[i0], e1 = keys[i0 + 1], e2 = keys[i0 + 2], e3 = keys[i0 + 3];
        bool upq = (((i0 & k) == 0) == asc);
        if (k >= 4) {
            cex(e0, e2, upq); cex(e1, e3, upq);
            cex(e0, e1, upq); cex(e2, e3, upq);
        } else {   // k == 2: j=1 only, direction alternates within the quad
            cex(e0, e1, asc);
            cex(e2, e3, !asc);
        }
        keys[i0] = e0; keys[i0 + 1] = e1; keys[i0 + 2] = e2; keys[i0 + 3] = e3;
        __syncthreads();
    }
}

// ---------------- persistence diagrams (H0 sublevel / H1 via superlevel duality) ------------
// Serial UF body byte-identical to r9/r10 (absmax 0.0). New: claim-based parallel merge
// commit — merges whose snapshot root-pair is untouched by any other in-batch edge commit
// in parallel (pair values exact: births are init-only, birth[root]==v_[root]); conflicting
// edges fall through to the serial scan. pbd output is bit-identical.
__global__ __launch_bounds__(512) void diag_kernel(const float* __restrict__ pooled,
                                                   float* __restrict__ diag) {
    __shared__ float v_[NPIX];
    __shared__ unsigned long long keys[NPAD];
    __shared__ unsigned long long PB[NPIX];      // low 32: parent, high 32: birth (f32 bits)
    __shared__ unsigned euv[NPAD];               // u | v<<16 per edge index
    __shared__ unsigned long long pbd[NEDGE];    // low: pb bits, high: pd bits
    __shared__ unsigned long long snap[132];     // wbits<<22 | (ra+1)<<11 | (rb+1); 0 = done
    __shared__ unsigned claimA[NPIX];            // per-root earliest-claiming batch slot
    __shared__ unsigned histAll[2048];           // 8 wave-copies x 256 bins
    __shared__ float redA[8], redB[8];
    __shared__ float svmin, svmax;
    __shared__ unsigned long long s_prefix, s_T;
    __shared__ unsigned s_need, s_done, s_outcnt;

    int run = blockIdx.x;      // 0..47
    int img = run >> 1, filt = run & 1;
    int tid = threadIdx.x;
    int wv = tid >> 6;
    const float* m = pooled + img * NPIX;

    for (int i = tid; i < NPIX; i += 512) {
        float val = m[i];
        v_[i] = filt ? -val : val;
    }
    __syncthreads();
    // min/max (for the essential H0 class)
    float mn = INFINITY, mx = -INFINITY;
    for (int i = tid; i < NPIX; i += 512) { float vv = v_[i]; mn = fminf(mn, vv); mx = fmaxf(mx, vv); }
    for (int o = 32; o; o >>= 1) { mn = fminf(mn, __shfl_xor(mn, o)); mx = fmaxf(mx, __shfl_xor(mx, o)); }
    if ((tid & 63) == 0) { redA[wv] = mn; redB[wv] = mx; }
    __syncthreads();
    if (tid == 0) {
        float a = INFINITY, b = -INFINITY;
        for (int i2 = 0; i2 < 8; ++i2) { a = fminf(a, redA[i2]); b = fmaxf(b, redB[i2]); }
        svmin = a; svmax = b;
    }
    // edge keys: stable sort by (weight, edge index) — replicates jnp.argsort (stable)
    for (int e = tid; e < NPAD; e += 512) {
        unsigned long long key;
        unsigned uv = 0;
        if (e < NEDGE) {
            int u, vv;
            if (e < 992) { int r = e / 31; u = e + r; vv = u + 1; }   // horizontal
            else         { u = e - 992;   vv = u + 32; }              // vertical
            float w = fmaxf(v_[u], v_[vv]);
            unsigned int bw = __float_as_uint(w);
            bw = (bw & 0x80000000u) ? ~bw : (bw | 0x80000000u);       // orderable float bits
            key = ((unsigned long long)bw << 11) | (unsigned int)e;
            uv = (unsigned)u | ((unsigned)vv << 16);
        } else key = ~0ULL;
        keys[e] = key;
        euv[e] = uv;
    }
    for (int i = tid; i < NPIX; i += 512)
        PB[i] = ((unsigned long long)__float_as_uint(v_[i]) << 32) | (unsigned)i;
    __syncthreads();
    bitonic2048_reg(keys, tid, true);   // ascending; ends with a barrier

    // Kruskal/union-find with elder rule, batch-snapshot + parallel-commit structure.
    unsigned* PBlo = (unsigned*)PB;
    for (int base = 0; base < NEDGE; base += 128) {
        // reset claims + parallel pointer-jumping compression (roots/births untouched)
        for (int i = tid; i < NPIX; i += 512) claimA[i] = 0xFFFFFFFFu;
        if (base) {
            for (int rd = 0; rd < 4; ++rd) {
                for (int i = tid; i < NPIX; i += 512) {
                    unsigned pp = PBlo[2 * i];
                    unsigned gg = PBlo[2 * pp];
                    PBlo[2 * i] = gg;           // benign race: result is always an ancestor
                }
            }
        }
        __syncthreads();
        int bend = (base + 128 < NEDGE) ? base + 128 : NEDGE;
        int bcnt = bend - base;
        // parallel precheck: resolve snapshot roots; trivial pairs emitted; merges claim roots
        if (tid < bcnt) {
            int kk = base + tid;
            unsigned long long key = keys[kk];
            int e = (int)(key & 2047ULL);
            unsigned bw = (unsigned)(key >> 11);
            unsigned uv = euv[e];
            int ra = (int)(uv & 0xffffu), rb = (int)(uv >> 16);
            unsigned pp = PBlo[2 * ra];
            while (pp != (unsigned)ra) { ra = (int)pp; pp = PBlo[2 * ra]; }
            unsigned p2 = PBlo[2 * rb];
            while (p2 != (unsigned)rb) { rb = (int)p2; p2 = PBlo[2 * rb]; }
            if (ra == rb) {
                unsigned wb = (bw & 0x80000000u) ? (bw & 0x7fffffffu) : ~bw;
                pbd[kk] = (unsigned long long)wb | ((unsigned long long)wb << 32);
                snap[tid] = 0ULL;                                // done (trivial)
            } else {
                snap[tid] = ((unsigned long long)bw << 22)
                          | ((unsigned)(ra + 1) << 11) | (unsigned)(rb + 1);
                atomicMin(&claimA[ra], (unsigned)tid);
                atomicMin(&claimA[rb], (unsigned)tid);
            }
        }
        __syncthreads();
        // parallel commit: edges owning BOTH root claims are isolated -> exact to commit now
        if (tid < bcnt) {
            unsigned long long sc = snap[tid];
            if ((unsigned)(sc & 0x3FFFFFu)) {
                int ra = (int)((sc >> 11) & 0x7FFu) - 1;
                int rb = (int)(sc & 0x7FFu) - 1;
                if (claimA[ra] == (unsigned)tid && claimA[rb] == (unsigned)tid) {
                    unsigned ob = (unsigned)(sc >> 22);
                    float w = __uint_as_float((ob & 0x80000000u) ? (ob & 0x7fffffffu) : ~ob);
                    float bu = v_[ra], bv = v_[rb];      // birth[root] == v_[root] (init-only)
                    bool uo = (bu <= bv);                // tie -> root on u's side
                    int older = uo ? ra : rb;
                    int younger = uo ? rb : ra;
                    PBlo[2 * younger] = (unsigned)older;
                    float pb_ = fmaxf(bu, bv);
                    pbd[base + tid] = (unsigned long long)__float_as_uint(pb_)
                                    | ((unsigned long long)__float_as_uint(w) << 32);
                    snap[tid] = 0ULL;                    // done (parallel-committed)
                }
            }
        }
        __syncthreads();
        // serial elder-rule scan over remaining conflicting merges (r9-exact body)
        if (tid == 0) {
            unsigned long long sc = snap[0];
            for (int i = 0; i < bcnt; ++i) {
                unsigned long long sn = snap[i + 1];             // read-only prefetch, no hazard
                if ((unsigned)(sc & 0x3FFFFFu)) {
                    unsigned ob = (unsigned)(sc >> 22);
                    float w = __uint_as_float((ob & 0x80000000u) ? (ob & 0x7fffffffu) : ~ob);
                    int a = (int)((sc >> 11) & 0x7FFu) - 1;
                    int b = (int)(sc & 0x7FFu) - 1;
                    unsigned long long qa = PB[a], qb = PB[b];
                    int pa = (int)(unsigned)qa, pb = (int)(unsigned)qb;
                    while (pa != a || pb != b) {
                        if (pa != a) {
                            unsigned long long na = PB[pa];
                            int ga = (int)(unsigned)na;
                            PBlo[2 * a] = (unsigned)ga;     // path-halving compression
                            a = pa; pa = ga; qa = na;
                        }
                        if (pb != b) {
                            unsigned long long nb = PB[pb];
                            int gb = (int)(unsigned)nb;
                            PBlo[2 * b] = (unsigned)gb;
                            b = pb; pb = gb; qb = nb;
                        }
                    }
                    float pb_, pd_;
                    if (a != b) {
                        float bu = __uint_as_float((unsigned)(qa >> 32));
                        float bv = __uint_as_float((unsigned)(qb >> 32));
                        bool uo = (bu <= bv);                 // tie -> root on u's side
                        int older = uo ? a : b;
                        int younger = uo ? b : a;
                        pb_ = fmaxf(bu, bv); pd_ = w;         // younger component dies
                        PBlo[2 * younger] = (unsigned)older;  // birth[older] already the min
                    } else { pb_ = w; pd_ = w; }              // became trivial within batch
                    pbd[base + i] = (unsigned long long)__float_as_uint(pb_)
                                  | ((unsigned long long)__float_as_uint(pd_) << 32);
                }
                sc = sn;
            }
        }
        __syncthreads();
    }

    // ---- top-k selection by (persistence, lower index) via radix-select ----
    // Downstream Sinkhorn is index-order-invariant, so only the selected SET matters.
    int count = filt ? NEDGE : (NEDGE + 1);
    for (int k = tid; k < NPAD; k += 512) {
        unsigned long long key = 0ULL;
        if (k < count) {
            float pers;
            if (k < NEDGE) {
                unsigned long long pd2 = pbd[k];
                pers = __uint_as_float((unsigned)(pd2 >> 32)) - __uint_as_float((unsigned)pd2);
            } else pers = svmax - svmin;
            key = ((unsigned long long)__float_as_uint(pers) << 32) | (unsigned int)(2047 - k);
        }
        keys[k] = key;
    }
    if (tid == 0) { s_prefix = 0ULL; s_T = 0ULL; s_need = KTOP; s_done = 0; s_outcnt = 0; }
    __syncthreads();

    for (int rnd = 0; rnd < 8; ++rnd) {
        for (int i = tid; i < 2048; i += 512) histAll[i] = 0;
        __syncthreads();
        if (!s_done) {
            int shift = 56 - 8 * rnd;
            unsigned long long pref = s_prefix;
            for (int k = tid; k < NPAD; k += 512) {
                unsigned long long key = keys[k];
                bool act = (rnd == 0) || ((key >> (shift + 8)) == (pref >> (shift + 8)));
                if (act) atomicAdd(&histAll[wv * 256 + (unsigned)((key >> shift) & 255ULL)], 1u);
            }
        }
        __syncthreads();
        if (wv == 0) {
            if (!s_done) {
                int l64 = tid;            // lane id within wave 0
                int shift = 56 - 8 * rnd;
                unsigned c0 = 0, c1 = 0, c2 = 0, c3 = 0;
                #pragma unroll
                for (int cp = 0; cp < 8; ++cp) {
                    const unsigned* h = histAll + cp * 256 + 4 * l64;
                    c0 += h[0]; c1 += h[1]; c2 += h[2]; c3 += h[3];
                }
                unsigned s3 = c3, s2 = c2 + s3, s1 = c1 + s2, s0 = c0 + s1;
                // wave-wide suffix sum of lane totals (s0)
                unsigned acc2 = s0;
                #pragma unroll
                for (int o = 1; o < 64; o <<= 1) {
                    unsigned v2 = __shfl_down(acc2, o);
                    if (l64 + o < 64) acc2 += v2;
                }
                unsigned above = acc2 - s0;                 // sum over lanes > l64
                unsigned Sn[5] = {above + s0, above + s1, above + s2, above + s3, above};
                unsigned need = s_need;
                #pragma unroll
                for (int q2 = 0; q2 < 4; ++q2) {
                    if (Sn[q2] >= need && Sn[q2 + 1] < need) {     // exactly one lane/bin fires
                        unsigned bstar = 4 * l64 + q2;
                        if (Sn[q2] == need) {
                            s_T = s_prefix | ((unsigned long long)bstar << shift);
                            s_done = 1;
                        } else {
                            s_prefix = s_prefix | ((unsigned long long)bstar << shift);
                            s_need = need - Sn[q2 + 1];
                        }
                    }
                }
            }
        }
        __syncthreads();
    }

    // compact selected (key >= T) and write output; order within diag is irrelevant downstream
    {
        unsigned long long T = s_T;
        for (int k = tid; k < NPAD; k += 512) {
            unsigned long long key = keys[k];
            if (key >= T && key != 0ULL) {
                int pos = (int)atomicAdd(&s_outcnt, 1u);
                int kk = 2047 - (int)(key & 0xffffffffULL);
                float b_, d_;
                if (kk < NEDGE) {
                    unsigned long long pd2 = pbd[kk];
                    b_ = __uint_as_float((unsigned)pd2);
                    d_ = __uint_as_float((unsigned)(pd2 >> 32));
                } else { b_ = svmin; d_ = svmax; }
                float ob, od;
                if (!filt) { ob = b_;  od = d_;  }       // H0 pairs
                else       { ob = -d_; od = -b_; }       // H1 = negated superlevel H0
                diag[((img * 4) + filt * 2 + 0) * KTOP + pos] = ob;
                diag[((img * 4) + filt * 2 + 1) * KTOP + pos] = od;
            }
        }
    }
}

// ---------------- entropic Sinkhorn: MFMA matvec + fold normalization ----------------------
// Byte-identical to the round-8/9/10 version (verified absmax 0.0).
__global__ __launch_bounds__(512) void sink_kernel(const float* __restrict__ diag,
                                                   float* __restrict__ wres) {
    __shared__ float2 sPA[KTOP], sPB[KTOP];
    __shared__ float sda[KTOP], sdb[KTOP];
    __shared__ float swa[KTOP], swb[KTOP];
    __shared__ __align__(16) unsigned ug_bf[128];    // 256 bf16
    __shared__ __align__(16) unsigned uf_bf[128];
    __shared__ __align__(16) float uf32[KTOP], ug32[KTOP];
    __shared__ __align__(16) float minF[8], accTF[8], minG[8], accTG[8];
    __shared__ __align__(16) float pm[8];
    __shared__ float s_sig, s_invsig;

    int p = blockIdx.x;            // 0..23
    int img = p % 12, dim = p / 12;
    int t = threadIdx.x;
    int lane = t & 63, w = t >> 6;         // wave 0..7
    int lr = lane & 15, lg = lane >> 4;    // col-lane, k-group
    int r = t >> 1, q = t & 1, jb = q * 128;   // mapping for maxC / final cost

    const float* ab  = diag + ((img * 4) + dim * 2) * KTOP;
    const float* ad  = ab + KTOP;
    const float* bbp = diag + (((12 + img) * 4) + dim * 2) * KTOP;
    const float* bdp = bbp + KTOP;

    if (t < KTOP) {
        float a0 = ab[t], a1 = ad[t];
        float b0 = bbp[t], b1 = bdp[t];
        sPA[t] = make_float2(a0, a1);
        sPB[t] = make_float2(b0, b1);
        sda[t] = 0.5f * (a1 - a0);
        sdb[t] = 0.5f * (b1 - b0);
    }
    if (t < 128) ug_bf[t] = 0x3F803F80u;   // u = 1.0 (bf16 pair)
    __syncthreads();

    // maxC (unscaled)
    {
        float2 A = sPA[r];
        float lmax = 0.f;
        for (int jj = 0; jj < 128; ++jj) {
            float2 B = sPB[jb + jj];
            lmax = fmaxf(lmax, fmaxf(fabsf(A.x - B.x), fabsf(A.y - B.y)));
        }
        if (t < KTOP) lmax = fmaxf(lmax, fmaxf(sda[t], sdb[t]));
        for (int o = 32; o; o >>= 1) lmax = fmaxf(lmax, __shfl_xor(lmax, o));
        if (lane == 0) pm[w] = lmax;
    }
    __syncthreads();
    if (t == 0) {
        float mc = 0.f;
        for (int i = 0; i < 8; ++i) mc = fmaxf(mc, pm[i]);
        float eps = 0.02f * fmaxf(mc, 1e-6f);
        s_sig = 1.4426950408889634f / eps;        // log2(e)/eps
        s_invsig = eps * 0.6931471805599453f;     // eps*ln2
    }
    __syncthreads();
    {
        float sig = s_sig;
        if (t < KTOP) {
            float2 a2 = sPA[t], b2 = sPB[t];
            sPA[t] = make_float2(a2.x * sig, a2.y * sig);
            sPB[t] = make_float2(b2.x * sig, b2.y * sig);
            float da2 = sda[t] * sig, db2 = sdb[t] * sig;
            sda[t] = da2; sdb[t] = db2;
            swa[t] = exp2f(-da2); swb[t] = exp2f(-db2);
        }
    }
    __syncthreads();

    // Build A-fragments: Kf (rows of K) and Kg (rows of K^T), bf16, constant across iters.
    bf16x8_t KfA0[8], KfA1[8], KgA0[8], KgA1[8];
    {
        float2 Af0 = sPA[w * 32 + lr];
        float2 Af1 = sPA[w * 32 + 16 + lr];
        float2 Bg0 = sPB[w * 32 + lr];
        float2 Bg1 = sPB[w * 32 + 16 + lr];
        #pragma unroll
        for (int ks = 0; ks < 8; ++ks) {
            #pragma unroll
            for (int jj = 0; jj < 8; ++jj) {
                int b = ks * 32 + lg * 8 + jj;
                float2 Pb = sPB[b];
                KfA0[ks][jj] = (short)bf_rne(exp2f(-fmaxf(fabsf(Af0.x - Pb.x), fabsf(Af0.y - Pb.y))));
                KfA1[ks][jj] = (short)bf_rne(exp2f(-fmaxf(fabsf(Af1.x - Pb.x), fabsf(Af1.y - Pb.y))));
                float2 Pa = sPA[b];
                KgA0[ks][jj] = (short)bf_rne(exp2f(-fmaxf(fabsf(Pa.x - Bg0.x), fabsf(Pa.y - Bg0.y))));
                KgA1[ks][jj] = (short)bf_rne(exp2f(-fmaxf(fabsf(Pa.x - Bg1.x), fabsf(Pa.y - Bg1.y))));
            }
        }
    }
    // Diagonal weights in D layout: row = w*32 + tt*16 + lg*4 + reg
    float wa0[4], wa1[4], wb0[4], wb1[4];
    #pragma unroll
    for (int g2 = 0; g2 < 4; ++g2) {
        wa0[g2] = swa[w * 32 + lg * 4 + g2];
        wa1[g2] = swa[w * 32 + 16 + lg * 4 + g2];
        wb0[g2] = swb[w * 32 + lg * 4 + g2];
        wb1[g2] = swb[w * 32 + 16 + lg * 4 + g2];
    }

    float cg = 1.f, cf = 1.f, uG2s = 1.f, uF2s = 1.f;
    f32x4_t ugs0 = {1.f, 1.f, 1.f, 1.f}, ugs1 = {1.f, 1.f, 1.f, 1.f};
    f32x4_t ufs0 = {0.f, 0.f, 0.f, 0.f}, ufs1 = {0.f, 0.f, 0.f, 0.f};

    for (int it = 0; it < NITER; ++it) {
        // ---- f phase ----
        if (it) {
            cg = min8v(minG);
            uG2s = rcpf(cf * (sum8v(accTG) + 256.f * uF2s));
        }
        {
            bf16x8_t Bf[8];
            #pragma unroll
            for (int ks = 0; ks < 8; ++ks) Bf[ks] = ((const bf16x8_t*)ug_bf)[ks * 4 + lg];
            f32x4_t a0 = {0.f, 0.f, 0.f, 0.f}, a1 = {0.f, 0.f, 0.f, 0.f};
            #pragma unroll
            for (int ks = 0; ks < 8; ++ks) {
                a0 = __builtin_amdgcn_mfma_f32_16x16x32_bf16(KfA0[ks], Bf[ks], a0, 0, 0, 0);
                a1 = __builtin_amdgcn_mfma_f32_16x16x32_bf16(KfA1[ks], Bf[ks], a1, 0, 0, 0);
            }
            float mv = INFINITY, tv = 0.f;
            #pragma unroll
            for (int g2 = 0; g2 < 4; ++g2) {
                float R0 = cg * (a0[g2] + 256.f * uG2s * wa0[g2]);
                float R1 = cg * (a1[g2] + 256.f * uG2s * wa1[g2]);
                ufs0[g2] = rcpf(R0); ufs1[g2] = rcpf(R1);
                mv = fminf(mv, fminf(R0, R1));
                tv += ugs0[g2] * wb0[g2] + ugs1[g2] * wb1[g2];   // T_f from OLD ug
            }
            if (lr == 0) {
                uint2 v0, v1;
                v0.x = bf_rne(ufs0[0]) | (bf_rne(ufs0[1]) << 16);
                v0.y = bf_rne(ufs0[2]) | (bf_rne(ufs0[3]) << 16);
                v1.x = bf_rne(ufs1[0]) | (bf_rne(ufs1[1]) << 16);
                v1.y = bf_rne(ufs1[2]) | (bf_rne(ufs1[3]) << 16);
                ((uint2*)uf_bf)[w * 8 + lg] = v0;
                ((uint2*)uf_bf)[w * 8 + 4 + lg] = v1;
            }
            wave_red2(tv, mv);
            if (lane == 0) { accTF[w] = tv * 0.0625f; minF[w] = mv; }   // rows duplicated x16
        }
        __syncthreads();
        // ---- g phase ----
        cf = min8v(minF);
        uF2s = rcpf(cg * (sum8v(accTF) + 256.f * uG2s));
        {
            bf16x8_t Bf[8];
            #pragma unroll
            for (int ks = 0; ks < 8; ++ks) Bf[ks] = ((const bf16x8_t*)uf_bf)[ks * 4 + lg];
            f32x4_t a0 = {0.f, 0.f, 0.f, 0.f}, a1 = {0.f, 0.f, 0.f, 0.f};
            #pragma unroll
            for (int ks = 0; ks < 8; ++ks) {
                a0 = __builtin_amdgcn_mfma_f32_16x16x32_bf16(KgA0[ks], Bf[ks], a0, 0, 0, 0);
                a1 = __builtin_amdgcn_mfma_f32_16x16x32_bf16(KgA1[ks], Bf[ks], a1, 0, 0, 0);
            }
            float mv = INFINITY, tv = 0.f;
            #pragma unroll
            for (int g2 = 0; g2 < 4; ++g2) {
                float Q0 = cf * (a0[g2] + 256.f * uF2s * wb0[g2]);
                float Q1 = cf * (a1[g2] + 256.f * uF2s * wb1[g2]);
                ugs0[g2] = rcpf(Q0); ugs1[g2] = rcpf(Q1);
                mv = fminf(mv, fminf(Q0, Q1));
                tv += ufs0[g2] * wa0[g2] + ufs1[g2] * wa1[g2];   // T_g from NEW uf
            }
            if (lr == 0) {
                uint2 v0, v1;
                v0.x = bf_rne(ugs0[0]) | (bf_rne(ugs0[1]) << 16);
                v0.y = bf_rne(ugs0[2]) | (bf_rne(ugs0[3]) << 16);
                v1.x = bf_rne(ugs1[0]) | (bf_rne(ugs1[1]) << 16);
                v1.y = bf_rne(ugs1[2]) | (bf_rne(ugs1[3]) << 16);
                ((uint2*)ug_bf)[w * 8 + lg] = v0;
                ((uint2*)ug_bf)[w * 8 + 4 + lg] = v1;
            }
            wave_red2(tv, mv);
            if (lane == 0) { accTG[w] = tv * 0.0625f; minG[w] = mv; }
        }
        __syncthreads();
    }
    // final G2 (after last g update); overall plan scale = cf
    float uG2f = rcpf(cf * (sum8v(accTG) + 256.f * uF2s));
    // publish exact f32 potentials for the cost epilogue
    if (lr == 0) {
        ((f32x4_t*)uf32)[w * 8 + lg] = ufs0;
        ((f32x4_t*)uf32)[w * 8 + 4 + lg] = ufs1;
        ((f32x4_t*)ug32)[w * 8 + lg] = ugs0;
        ((f32x4_t*)ug32)[w * 8 + 4 + lg] = ugs1;
    }
    __syncthreads();

    // ---- final cost sum(P*C): P_ij = cf * ufs_i * K_ij * ugs_j,  C = Mhat*invsig ----
    float accv = 0.f;
    {
        float2 Apt = sPA[r];
        float ufr = uf32[r];
        #pragma unroll 8
        for (int jj = 0; jj < 128; ++jj) {
            int j = jb + jj;
            float2 B = sPB[j];
            float Mh = fmaxf(fabsf(Apt.x - B.x), fabsf(Apt.y - B.y));
            float kv = __uint_as_float(bf_rne(exp2f(-Mh)) << 16);   // same bf16 K as iterations
            accv += ((ufr * kv) * ug32[j]) * Mh;
        }
        if (q == 0) accv += 256.f * ((ufr * swa[r]) * uG2f) * sda[r];
        else        accv += 256.f * ((uF2s * swb[r]) * ug32[r]) * sdb[r];
    }
    accv *= cf;
    for (int o = 32; o; o >>= 1) accv += __shfl_xor(accv, o);
    if (lane == 0) pm[w] = accv;
    __syncthreads();
    if (t == 0) {
        float tot = 0.f;
        for (int i = 0; i < 8; ++i) tot += pm[i];
        wres[p] = tot * s_invsig;   // back to natural units
    }
}

__global__ void finalize_kernel(const float* __restrict__ wres, float* __restrict__ out) {
    if (threadIdx.x == 0) {
        float s = 0.f;
        for (int i = 0; i < 24; ++i) s += wres[i];
        out[0] = s * 0.25f;        // / B
    }
}

extern "C" void kernel_launch(void* const* d_in, const int* in_sizes, int n_in,
                              void* d_out, int out_size, void* d_ws, size_t ws_size,
                              hipStream_t stream) {
    const float* x = (const float*)d_in[0];   // [4,4,256,256] f32
    const int* y = (const int*)d_in[1];       // [4,1,256,256] i32
    float* ws = (float*)d_ws;
    float* pooled = ws;                        // 24*1024 floats
    float* diag = pooled + 24 * NPIX;          // 24*4*256 floats
    float* wres = diag + 24 * 4 * KTOP;        // 24 floats

    pool_kernel<<<96, 256, 0, stream>>>(x, y, pooled);
    diag_kernel<<<48, 512, 0, stream>>>(pooled, diag);
    sink_kernel<<<24, 512, 0, stream>>>(diag, wres);
    finalize_kernel<<<1, 64, 0, stream>>>(wres, (float*)d_out);
}